// Round 1
// baseline (4562.302 us; speedup 1.0000x reference)
//
#include <hip/hip_runtime.h>

#define NN 50000
#define EE 300000
#define DD 256
#define RR 3

constexpr int BM = 64, BN = 64, BK = 16, PAD = 4;

// ---------------------------------------------------------------------------
// Count per-relation in/out degrees and edge counts.
__global__ __launch_bounds__(256) void count_kernel(
    const int* __restrict__ erow, const int* __restrict__ ecol,
    const int* __restrict__ etype, int* __restrict__ c_in,
    int* __restrict__ c_out, int* __restrict__ nr)
{
    int g = blockIdx.x * blockDim.x + threadIdx.x;
    int stride = gridDim.x * blockDim.x;
    for (int e = g; e < EE; e += stride) {
        int t = etype[e];
        atomicAdd(&c_out[t * NN + erow[e]], 1);
        atomicAdd(&c_in[t * NN + ecol[e]], 1);
        atomicAdd(&nr[t], 1);
    }
}

// ---------------------------------------------------------------------------
// C = A[MxD] @ B[DxD]  (MODE 0, plain store)
// C += (cnt[n]/(qs[n]+Nr)) * (A@B)  (MODE 1, fused row-scaled accumulate)
template <int MODE>
__global__ __launch_bounds__(256) void gemm64(
    const float* __restrict__ A, const float* __restrict__ B,
    float* __restrict__ C, int M,
    const float* __restrict__ qs, const int* __restrict__ cnt,
    const int* __restrict__ nrp)
{
    __shared__ float As[BK][BM + PAD];
    __shared__ float Bs[BK][BN + PAD];
    const int tid = threadIdx.x;
    const int row0 = blockIdx.x * BM, col0 = blockIdx.y * BN;
    const int la_m = tid >> 2, la_k = (tid & 3) * 4;  // A: 64 rows x 16 k
    const int lb_k = tid >> 4, lb_n = (tid & 15) * 4; // B: 16 k x 64 cols
    const int ty = tid >> 4, tx = tid & 15;

    float acc[4][4] = {};
    for (int k0 = 0; k0 < DD; k0 += BK) {
        int arow = row0 + la_m;
        float4 a4 = make_float4(0.f, 0.f, 0.f, 0.f);
        if (arow < M) a4 = *(const float4*)(A + (size_t)arow * DD + k0 + la_k);
        As[la_k + 0][la_m] = a4.x;
        As[la_k + 1][la_m] = a4.y;
        As[la_k + 2][la_m] = a4.z;
        As[la_k + 3][la_m] = a4.w;
        *(float4*)&Bs[lb_k][lb_n] =
            *(const float4*)(B + (size_t)(k0 + lb_k) * DD + col0 + lb_n);
        __syncthreads();
#pragma unroll
        for (int k = 0; k < BK; k++) {
            float4 av = *(const float4*)&As[k][ty * 4];
            float4 bv = *(const float4*)&Bs[k][tx * 4];
            float a[4] = {av.x, av.y, av.z, av.w};
            float b[4] = {bv.x, bv.y, bv.z, bv.w};
#pragma unroll
            for (int i = 0; i < 4; i++)
#pragma unroll
                for (int j = 0; j < 4; j++) acc[i][j] += a[i] * b[j];
        }
        __syncthreads();
    }

#pragma unroll
    for (int i = 0; i < 4; i++) {
        int r = row0 + ty * 4 + i;
        if (r >= M) continue;
        float* cp = C + (size_t)r * DD + col0 + tx * 4;
        if (MODE == 0) {
            *(float4*)cp = make_float4(acc[i][0], acc[i][1], acc[i][2], acc[i][3]);
        } else {
            float nr = (float)nrp[0];
            float s = (float)cnt[r] / (qs[r] + nr);
            float4 o = *(const float4*)cp;
            o.x += s * acc[i][0];
            o.y += s * acc[i][1];
            o.z += s * acc[i][2];
            o.w += s * acc[i][3];
            *(float4*)cp = o;
        }
    }
}

// ---------------------------------------------------------------------------
// kvs[i][j] += sum_n c_in[n]*K[n][i]*V[n][j];  ks_sum[i] += sum_n c_in[n]*K[n][i]
// Split-K over node chunks (blockIdx.z), atomic accumulate into 256x256 output.
__global__ __launch_bounds__(256) void kvs_kernel(
    const float* __restrict__ K, const float* __restrict__ V,
    const int* __restrict__ c_in, float* __restrict__ kvs,
    float* __restrict__ ks_sum)
{
    __shared__ float Kt[16][BM + PAD];
    __shared__ float Vt[16][BM + PAD];
    const int i0 = blockIdx.x * 64, j0 = blockIdx.y * 64;
    const int cl = (NN + gridDim.z - 1) / gridDim.z;
    const int ns = blockIdx.z * cl;
    const int ne = min(NN, ns + cl);
    const int tid = threadIdx.x;
    const int lk = tid >> 4, ln = (tid & 15) * 4;
    const int ty = tid >> 4, tx = tid & 15;

    float acc[4][4] = {};
    float ksl = 0.f;
    for (int n0 = ns; n0 < ne; n0 += 16) {
        int n = n0 + lk;
        float4 kx = make_float4(0.f, 0.f, 0.f, 0.f);
        float4 vx = make_float4(0.f, 0.f, 0.f, 0.f);
        if (n < ne) {
            float w = (float)c_in[n];
            kx = *(const float4*)(K + (size_t)n * DD + i0 + ln);
            kx.x *= w; kx.y *= w; kx.z *= w; kx.w *= w;
            vx = *(const float4*)(V + (size_t)n * DD + j0 + ln);
        }
        *(float4*)&Kt[lk][ln] = kx;
        *(float4*)&Vt[lk][ln] = vx;
        __syncthreads();
        if (blockIdx.y == 0 && tid < 64) {
#pragma unroll
            for (int k = 0; k < 16; k++) ksl += Kt[k][tid];
        }
#pragma unroll
        for (int k = 0; k < 16; k++) {
            float4 av = *(const float4*)&Kt[k][ty * 4];
            float4 bv = *(const float4*)&Vt[k][tx * 4];
            float a[4] = {av.x, av.y, av.z, av.w};
            float b[4] = {bv.x, bv.y, bv.z, bv.w};
#pragma unroll
            for (int i = 0; i < 4; i++)
#pragma unroll
                for (int j = 0; j < 4; j++) acc[i][j] += a[i] * b[j];
        }
        __syncthreads();
    }
#pragma unroll
    for (int i = 0; i < 4; i++)
#pragma unroll
        for (int j = 0; j < 4; j++)
            atomicAdd(&kvs[(size_t)(i0 + ty * 4 + i) * DD + j0 + tx * 4 + j],
                      acc[i][j]);
    if (blockIdx.y == 0 && tid < 64) atomicAdd(&ks_sum[i0 + tid], ksl);
}

// ---------------------------------------------------------------------------
// qs[n] = Q[n] . ks_sum    (one wave per node)
__global__ __launch_bounds__(256) void qs_kernel(
    const float* __restrict__ Q, const float* __restrict__ ks,
    float* __restrict__ qs)
{
    __shared__ float kss[DD];
    const int tid = threadIdx.x;
    kss[tid] = ks[tid];
    __syncthreads();
    const int wid = tid >> 6, lane = tid & 63;
    const int n = blockIdx.x * 4 + wid;
    if (n < NN) {
        float4 qv = *(const float4*)(Q + (size_t)n * DD + lane * 4);
        float4 kv = *(const float4*)&kss[lane * 4];
        float s = qv.x * kv.x + qv.y * kv.y + qv.z * kv.z + qv.w * kv.w;
#pragma unroll
        for (int off = 32; off; off >>= 1) s += __shfl_down(s, off, 64);
        if (lane == 0) qs[n] = s;
    }
}

// ---------------------------------------------------------------------------
// Per-edge: x_out[row] += (Nr/(qs[row]+Nr)) * V[col]   (one wave per edge)
__global__ __launch_bounds__(256) void scatter_kernel(
    const int* __restrict__ erow, const int* __restrict__ ecol,
    const int* __restrict__ etype, int rsel,
    const float* __restrict__ V, const float* __restrict__ qs,
    const int* __restrict__ nrp, float* __restrict__ x_out)
{
    long long g = (long long)blockIdx.x * blockDim.x + threadIdx.x;
    int e = (int)(g >> 6);
    int lane = (int)(g & 63);
    if (e >= EE) return;
    if (etype[e] != rsel) return;
    float nr = (float)nrp[0];
    int rw = erow[e], cl = ecol[e];
    float s = nr / (qs[rw] + nr);
    float4 v = *(const float4*)(V + (size_t)cl * DD + lane * 4);
    float* xp = x_out + (size_t)rw * DD + lane * 4;
    atomicAdd(xp + 0, s * v.x);
    atomicAdd(xp + 1, s * v.y);
    atomicAdd(xp + 2, s * v.z);
    atomicAdd(xp + 3, s * v.w);
}

// ---------------------------------------------------------------------------
extern "C" void kernel_launch(void* const* d_in, const int* in_sizes, int n_in,
                              void* d_out, int out_size, void* d_ws, size_t ws_size,
                              hipStream_t stream)
{
    const float* x   = (const float*)d_in[0];
    const float* Wq  = (const float*)d_in[1];
    const float* Wk  = (const float*)d_in[2];
    const float* Wv  = (const float*)d_in[3];
    const float* Whp = (const float*)d_in[4];
    const int* eidx  = (const int*)d_in[5];
    const int* etyp  = (const int*)d_in[6];
    const int* erow = eidx;
    const int* ecol = eidx + EE;
    float* out = (float*)d_out;

    float* bufA  = (float*)d_ws;                 // K_r, then Q_r
    float* bufV  = bufA + (size_t)NN * DD;       // V_r
    float* x_out = bufV + (size_t)NN * DD;       // accumulator
    float* kvs   = x_out + (size_t)NN * DD;      // 256x256
    float* ks    = kvs + DD * DD;                // 256
    float* qs    = ks + DD;                      // N
    int* c_in    = (int*)(qs + NN);              // 3*N
    int* c_out   = c_in + 3 * NN;                // 3*N
    int* nr      = c_out + 3 * NN;               // 3

    hipMemsetAsync(x_out, 0, (size_t)NN * DD * sizeof(float), stream);
    hipMemsetAsync(c_in, 0, (size_t)(6 * NN + 3) * sizeof(int), stream);
    count_kernel<<<512, 256, 0, stream>>>(erow, ecol, etyp, c_in, c_out, nr);

    dim3 gg((NN + BM - 1) / BM, DD / BN);
    for (int r = 0; r < RR; r++) {
        const size_t wo = (size_t)r * DD * DD;
        gemm64<0><<<gg, 256, 0, stream>>>(x, Wk + wo, bufA, NN, nullptr, nullptr, nullptr);
        gemm64<0><<<gg, 256, 0, stream>>>(x, Wv + wo, bufV, NN, nullptr, nullptr, nullptr);
        hipMemsetAsync(kvs, 0, (size_t)(DD * DD + DD) * sizeof(float), stream);
        kvs_kernel<<<dim3(4, 4, 64), 256, 0, stream>>>(bufA, bufV, c_in + (size_t)r * NN, kvs, ks);
        gemm64<0><<<gg, 256, 0, stream>>>(x, Wq + wo, bufA, NN, nullptr, nullptr, nullptr);
        qs_kernel<<<(NN + 3) / 4, 256, 0, stream>>>(bufA, ks, qs);
        gemm64<1><<<gg, 256, 0, stream>>>(bufA, kvs, x_out, NN, qs, c_out + (size_t)r * NN, nr + r);
        scatter_kernel<<<(EE * 64) / 256, 256, 0, stream>>>(erow, ecol, etyp, r, bufV, qs, nr + r, x_out);
    }
    gemm64<0><<<gg, 256, 0, stream>>>(x_out, Whp, out, NN, nullptr, nullptr, nullptr);
}

// Round 2
// 2689.997 us; speedup vs baseline: 1.6960x; 1.6960x over previous
//
#include <hip/hip_runtime.h>

#define NN 50000
#define EE 300000
#define DD 256
#define RR 3

using bf16x8 = __attribute__((ext_vector_type(8))) short;
using f32x4  = __attribute__((ext_vector_type(4))) float;

__device__ __forceinline__ float bf2f(unsigned short u) {
    return __uint_as_float(((unsigned)u) << 16);
}
__device__ __forceinline__ unsigned short f2bf(float f) {
    unsigned u = __float_as_uint(f);
    return (unsigned short)((u + 0x7fffu + ((u >> 16) & 1u)) >> 16);
}
__device__ __forceinline__ void gload_lds16(const void* g, void* l) {
    __builtin_amdgcn_global_load_lds(
        (const __attribute__((address_space(1))) unsigned int*)g,
        (__attribute__((address_space(3))) unsigned int*)l, 16, 0, 0);
}

// ---------------------------------------------------------------------------
// Weight prep: WqkvT[r][m*256+n][k] = W_m[r][k][n] (bf16);  WhpT[n][k]=Whp[k][n]
__global__ __launch_bounds__(256) void prep_w(
    const float* __restrict__ Wq, const float* __restrict__ Wk,
    const float* __restrict__ Wv, const float* __restrict__ Whp,
    unsigned short* __restrict__ WqkvT, unsigned short* __restrict__ WhpT)
{
    int t = blockIdx.x * 256 + threadIdx.x;
    const int total = RR * 3 * DD * DD;
    if (t < total) {
        int k = t & 255, n = (t >> 8) & 255, mm = (t >> 16) % 3, r = (t >> 16) / 3;
        const float* W = (mm == 0) ? Wq : (mm == 1) ? Wk : Wv;
        float v = W[((size_t)r * DD + k) * DD + n];
        WqkvT[((size_t)r * 768 + mm * DD + n) * DD + k] = f2bf(v);
    } else if (t < total + DD * DD) {
        int o = t - total, k = o & 255, n = o >> 8;
        WhpT[n * DD + k] = f2bf(Whp[k * DD + n]);
    }
}

// fp32 -> bf16, 4 elems/thread
__global__ __launch_bounds__(256) void conv_bf16(
    const float* __restrict__ in, unsigned short* __restrict__ out, int n4)
{
    int t = blockIdx.x * 256 + threadIdx.x;
    if (t < n4) {
        float4 v = ((const float4*)in)[t];
        ushort4 o;
        o.x = f2bf(v.x); o.y = f2bf(v.y); o.z = f2bf(v.z); o.w = f2bf(v.w);
        ((ushort4*)out)[t] = o;
    }
}

// ---------------------------------------------------------------------------
// Degree counts; nr via LDS block counters (kills same-address contention).
__global__ __launch_bounds__(256) void count_kernel(
    const int* __restrict__ erow, const int* __restrict__ ecol,
    const int* __restrict__ etype, int* __restrict__ c_in,
    int* __restrict__ c_out, int* __restrict__ nr)
{
    __shared__ int lnr[RR];
    if (threadIdx.x < RR) lnr[threadIdx.x] = 0;
    __syncthreads();
    int g = blockIdx.x * blockDim.x + threadIdx.x;
    int stride = gridDim.x * blockDim.x;
    for (int e = g; e < EE; e += stride) {
        int t = etype[e];
        atomicAdd(&c_out[t * NN + erow[e]], 1);
        atomicAdd(&c_in[t * NN + ecol[e]], 1);
        atomicAdd(&lnr[t], 1);
    }
    __syncthreads();
    if (threadIdx.x < RR) atomicAdd(&nr[threadIdx.x], lnr[threadIdx.x]);
}

// ---------------------------------------------------------------------------
// MFMA NT GEMM: C[M,N] = A[M,K=256] @ BT[N,K=256]^T  (bf16 in, fp32 acc)
// MODE 0: store bf16 to C(ldc). MODE 1: store fp32. MODE 2: C += cnt[r]/(qs[r]+Nr)*acc
// 128x128 tile, BK=64, 4 waves (2x2 of 64x64), XOR-swizzled LDS (rule 21:
// linear LDS dest + inverse-swizzled global source + swizzled ds_read).
template <int MODE>
__global__ __launch_bounds__(256) void gemm_nt(
    const unsigned short* __restrict__ A, int lda,
    const unsigned short* __restrict__ B, int ldb,
    void* __restrict__ Cv, int ldc, int M,
    const float* __restrict__ qs, const int* __restrict__ cnt,
    const int* __restrict__ nrp)
{
    __shared__ __align__(16) char ldsA[16384];
    __shared__ __align__(16) char ldsB[16384];
    const int tid = threadIdx.x, lane = tid & 63, wid = tid >> 6;
    const int wr = wid >> 1, wc = wid & 1;
    const int row0 = blockIdx.x * 128, col0 = blockIdx.y * 128;

    f32x4 acc[4][4];
#pragma unroll
    for (int m = 0; m < 4; m++)
#pragma unroll
        for (int n = 0; n < 4; n++) acc[m][n] = (f32x4){0.f, 0.f, 0.f, 0.f};

    for (int k0 = 0; k0 < DD; k0 += 64) {
#pragma unroll
        for (int is = 0; is < 4; is++) {
            int lb = is * 4096 + wid * 1024;
            int d = lb + lane * 16;
            int row = d >> 7;
            int sc = (d & 127) ^ ((row & 7) << 4);
            int gr = row0 + row; gr = gr < M ? gr : M - 1;
            gload_lds16((const char*)(A + (size_t)gr * lda + k0) + sc, ldsA + lb);
            int rn = col0 + row;
            gload_lds16((const char*)(B + (size_t)rn * ldb + k0) + sc, ldsB + lb);
        }
        __syncthreads();
#pragma unroll
        for (int kk = 0; kk < 2; kk++) {
            bf16x8 af[4], bf_[4];
            const int cb = kk * 64 + ((lane >> 4) << 4);
#pragma unroll
            for (int m = 0; m < 4; m++) {
                int row = wr * 64 + m * 16 + (lane & 15);
                af[m] = *(const bf16x8*)(ldsA + row * 128 + (cb ^ ((row & 7) << 4)));
                int rn = wc * 64 + m * 16 + (lane & 15);
                bf_[m] = *(const bf16x8*)(ldsB + rn * 128 + (cb ^ ((rn & 7) << 4)));
            }
#pragma unroll
            for (int m = 0; m < 4; m++)
#pragma unroll
                for (int n = 0; n < 4; n++)
                    acc[m][n] = __builtin_amdgcn_mfma_f32_16x16x32_bf16(
                        af[m], bf_[n], acc[m][n], 0, 0, 0);
        }
        __syncthreads();
    }

    float nrf = 0.f;
    if (MODE == 2) nrf = (float)nrp[0];
#pragma unroll
    for (int m = 0; m < 4; m++) {
#pragma unroll
        for (int reg = 0; reg < 4; reg++) {
            int r = row0 + wr * 64 + m * 16 + ((lane >> 4) << 2) + reg;
            if (r >= M) continue;
            float s = 0.f;
            if (MODE == 2) s = (float)cnt[r] / (qs[r] + nrf);
#pragma unroll
            for (int n = 0; n < 4; n++) {
                int c = col0 + wc * 64 + n * 16 + (lane & 15);
                float v = acc[m][n][reg];
                if (MODE == 0)
                    ((unsigned short*)Cv)[(size_t)r * ldc + c] = f2bf(v);
                else if (MODE == 1)
                    ((float*)Cv)[(size_t)r * ldc + c] = v;
                else
                    ((float*)Cv)[(size_t)r * ldc + c] += s * v;
            }
        }
    }
}

// ---------------------------------------------------------------------------
// kvsT[j][i] += sum_n w[n]*K[n][i]*V[n][j]; ks[i] += sum_n w[n]*K[n][i]
// K=QKV cols 256..511, V=cols 512..767 (bf16, row stride 768). 128x128 tile,
// 8x8 microtile, split over node chunks (blockIdx.z), atomic fp32 accumulate.
__global__ __launch_bounds__(256) void kvs_kernel(
    const unsigned short* __restrict__ QKV, const int* __restrict__ c_in,
    float* __restrict__ kvsT, float* __restrict__ ks)
{
    __shared__ __align__(16) float Ks[16][132];
    __shared__ __align__(16) float Vs[16][132];
    const int tid = threadIdx.x;
    const int i0 = blockIdx.x * 128, j0 = blockIdx.y * 128;
    const int chunk = (NN + gridDim.z - 1) / gridDim.z;
    const int ns = blockIdx.z * chunk, ne = min(NN, ns + chunk);
    const int ln = tid >> 4, lc = (tid & 15) * 8;
    const int ty = tid >> 4, tx = tid & 15;

    float acc[8][8] = {};
    float ksacc = 0.f;
    for (int n0 = ns; n0 < ne; n0 += 16) {
        int n = n0 + ln;
        float kf[8], vf[8];
        if (n < ne) {
            float w = (float)c_in[n];
            uint4 kr = *(const uint4*)(QKV + (size_t)n * 768 + 256 + i0 + lc);
            uint4 vr = *(const uint4*)(QKV + (size_t)n * 768 + 512 + j0 + lc);
            unsigned kk[4] = {kr.x, kr.y, kr.z, kr.w};
            unsigned vv[4] = {vr.x, vr.y, vr.z, vr.w};
#pragma unroll
            for (int q = 0; q < 4; q++) {
                kf[2 * q]     = w * bf2f((unsigned short)(kk[q] & 0xffff));
                kf[2 * q + 1] = w * bf2f((unsigned short)(kk[q] >> 16));
                vf[2 * q]     = bf2f((unsigned short)(vv[q] & 0xffff));
                vf[2 * q + 1] = bf2f((unsigned short)(vv[q] >> 16));
            }
        } else {
#pragma unroll
            for (int q = 0; q < 8; q++) { kf[q] = 0.f; vf[q] = 0.f; }
        }
        *(float4*)&Ks[ln][lc]     = make_float4(kf[0], kf[1], kf[2], kf[3]);
        *(float4*)&Ks[ln][lc + 4] = make_float4(kf[4], kf[5], kf[6], kf[7]);
        *(float4*)&Vs[ln][lc]     = make_float4(vf[0], vf[1], vf[2], vf[3]);
        *(float4*)&Vs[ln][lc + 4] = make_float4(vf[4], vf[5], vf[6], vf[7]);
        __syncthreads();
        if (blockIdx.y == 0 && tid < 128) {
#pragma unroll
            for (int k = 0; k < 16; k++) ksacc += Ks[k][tid];
        }
#pragma unroll
        for (int k = 0; k < 16; k++) {
            float4 a0 = *(const float4*)&Ks[k][ty * 8];
            float4 a1 = *(const float4*)&Ks[k][ty * 8 + 4];
            float4 b0 = *(const float4*)&Vs[k][tx * 8];
            float4 b1 = *(const float4*)&Vs[k][tx * 8 + 4];
            float a[8] = {a0.x, a0.y, a0.z, a0.w, a1.x, a1.y, a1.z, a1.w};
            float b[8] = {b0.x, b0.y, b0.z, b0.w, b1.x, b1.y, b1.z, b1.w};
#pragma unroll
            for (int ii = 0; ii < 8; ii++)
#pragma unroll
                for (int jj = 0; jj < 8; jj++) acc[ii][jj] += a[ii] * b[jj];
        }
        __syncthreads();
    }
#pragma unroll
    for (int ii = 0; ii < 8; ii++)
#pragma unroll
        for (int jj = 0; jj < 8; jj++)
            atomicAdd(&kvsT[(size_t)(j0 + tx * 8 + jj) * DD + i0 + ty * 8 + ii],
                      acc[ii][jj]);
    if (blockIdx.y == 0 && tid < 128) atomicAdd(&ks[i0 + tid], ksacc);
}

// ---------------------------------------------------------------------------
// qs[n] = Q[n] . ks   (Q bf16 at QKV cols 0..255, one wave per node)
__global__ __launch_bounds__(256) void qs_kernel(
    const unsigned short* __restrict__ QKV, const float* __restrict__ ks,
    float* __restrict__ qs)
{
    __shared__ float kss[DD];
    const int tid = threadIdx.x;
    kss[tid] = ks[tid];
    __syncthreads();
    const int wid = tid >> 6, lane = tid & 63;
    const int n = blockIdx.x * 4 + wid;
    if (n < NN) {
        ushort4 q4 = *(const ushort4*)(QKV + (size_t)n * 768 + lane * 4);
        float s = bf2f(q4.x) * kss[lane * 4] + bf2f(q4.y) * kss[lane * 4 + 1] +
                  bf2f(q4.z) * kss[lane * 4 + 2] + bf2f(q4.w) * kss[lane * 4 + 3];
#pragma unroll
        for (int off = 32; off; off >>= 1) s += __shfl_down(s, off, 64);
        if (lane == 0) qs[n] = s;
    }
}

// ---------------------------------------------------------------------------
// x_out[row] += (Nr/(qs[row]+Nr)) * V[col]  (V bf16 at QKV cols 512..767)
__global__ __launch_bounds__(256) void scatter_kernel(
    const int* __restrict__ erow, const int* __restrict__ ecol,
    const int* __restrict__ etype, int rsel,
    const unsigned short* __restrict__ QKV, const float* __restrict__ qs,
    const int* __restrict__ nrp, float* __restrict__ x_out)
{
    long long g = (long long)blockIdx.x * blockDim.x + threadIdx.x;
    int e = (int)(g >> 6);
    int lane = (int)(g & 63);
    if (e >= EE) return;
    if (etype[e] != rsel) return;
    float nrf = (float)nrp[0];
    int rw = erow[e], cl = ecol[e];
    float s = nrf / (qs[rw] + nrf);
    ushort4 v4 = *(const ushort4*)(QKV + (size_t)cl * 768 + 512 + lane * 4);
    float* xp = x_out + (size_t)rw * DD + lane * 4;
    atomicAdd(xp + 0, s * bf2f(v4.x));
    atomicAdd(xp + 1, s * bf2f(v4.y));
    atomicAdd(xp + 2, s * bf2f(v4.z));
    atomicAdd(xp + 3, s * bf2f(v4.w));
}

// ---------------------------------------------------------------------------
extern "C" void kernel_launch(void* const* d_in, const int* in_sizes, int n_in,
                              void* d_out, int out_size, void* d_ws, size_t ws_size,
                              hipStream_t stream)
{
    const float* x   = (const float*)d_in[0];
    const float* Wq  = (const float*)d_in[1];
    const float* Wk  = (const float*)d_in[2];
    const float* Wv  = (const float*)d_in[3];
    const float* Whp = (const float*)d_in[4];
    const int* eidx  = (const int*)d_in[5];
    const int* etyp  = (const int*)d_in[6];
    const int* erow = eidx;
    const int* ecol = eidx + EE;
    float* out = (float*)d_out;

    char* p = (char*)d_ws;
    unsigned short* xb    = (unsigned short*)p; p += (size_t)NN * DD * 2;       // 25.6MB
    unsigned short* QKV   = (unsigned short*)p; p += (size_t)NN * 768 * 2;      // 76.8MB
    float*          x_out = (float*)p;          p += (size_t)NN * DD * 4;       // 51.2MB
    unsigned short* WqkvT = (unsigned short*)p; p += (size_t)RR * 768 * DD * 2; // 1.2MB
    unsigned short* WhpT  = (unsigned short*)p; p += DD * DD * 2;
    float*          kvsT  = (float*)p;          p += DD * DD * 4;
    float*          ks    = (float*)p;          p += DD * 4;
    unsigned short* kvsb  = (unsigned short*)p; p += DD * DD * 2;
    float*          qs    = (float*)p;          p += (size_t)NN * 4;
    int*            c_in  = (int*)p;            p += (size_t)3 * NN * 4;
    int*            c_out = (int*)p;            p += (size_t)3 * NN * 4;
    int*            nr    = (int*)p;
    unsigned short* xob   = QKV;  // alias: QKV dead by the time xob is written

    prep_w<<<(RR * 3 * DD * DD + DD * DD + 255) / 256, 256, 0, stream>>>(
        Wq, Wk, Wv, Whp, WqkvT, WhpT);
    conv_bf16<<<(NN * DD / 4 + 255) / 256, 256, 0, stream>>>(x, xb, NN * DD / 4);
    hipMemsetAsync(x_out, 0, (size_t)NN * DD * sizeof(float), stream);
    hipMemsetAsync(c_in, 0, (size_t)(6 * NN + 3) * sizeof(int), stream);
    count_kernel<<<512, 256, 0, stream>>>(erow, ecol, etyp, c_in, c_out, nr);

    const int MB = (NN + 127) / 128;  // 391
    for (int r = 0; r < RR; r++) {
        gemm_nt<0><<<dim3(MB, 6), 256, 0, stream>>>(
            xb, DD, WqkvT + (size_t)r * 768 * DD, DD, QKV, 768, NN,
            nullptr, nullptr, nullptr);
        hipMemsetAsync(kvsT, 0, (DD * DD + DD) * sizeof(float), stream);
        kvs_kernel<<<dim3(2, 2, 256), 256, 0, stream>>>(QKV, c_in + (size_t)r * NN, kvsT, ks);
        conv_bf16<<<(DD * DD / 4 + 255) / 256, 256, 0, stream>>>(kvsT, kvsb, DD * DD / 4);
        qs_kernel<<<(NN + 3) / 4, 256, 0, stream>>>(QKV, ks, qs);
        gemm_nt<2><<<dim3(MB, 2), 256, 0, stream>>>(
            QKV, 768, kvsb, DD, x_out, DD, NN, qs, c_out + (size_t)r * NN, nr + r);
        scatter_kernel<<<(EE * 64) / 256, 256, 0, stream>>>(
            erow, ecol, etyp, r, QKV, qs, nr + r, x_out);
    }
    conv_bf16<<<(NN * DD / 4 + 255) / 256, 256, 0, stream>>>(x_out, xob, NN * DD / 4);
    gemm_nt<1><<<dim3(MB, 2), 256, 0, stream>>>(
        xob, DD, WhpT, DD, out, DD, NN, nullptr, nullptr, nullptr);
}

// Round 3
// 1426.698 us; speedup vs baseline: 3.1978x; 1.8855x over previous
//
#include <hip/hip_runtime.h>

#define NN 50000
#define EE 300000
#define DD 256
#define RR 3
#define NPAD 50048            // 782 * 64
#define GS 64                 // split-K slices for G

using bf16x8 = __attribute__((ext_vector_type(8))) short;
using f32x4  = __attribute__((ext_vector_type(4))) float;

__device__ __forceinline__ float bf2f(unsigned short u) {
    return __uint_as_float(((unsigned)u) << 16);
}
__device__ __forceinline__ unsigned short f2bf(float f) {
    unsigned u = __float_as_uint(f);
    return (unsigned short)((u + 0x7fffu + ((u >> 16) & 1u)) >> 16);
}
__device__ __forceinline__ void gload_lds16(const void* g, void* l) {
    __builtin_amdgcn_global_load_lds(
        (const __attribute__((address_space(1))) unsigned int*)g,
        (__attribute__((address_space(3))) unsigned int*)l, 16, 0, 0);
}

// ---------------------------------------------------------------------------
// Weight prep: WvT[r][n][k]=Wv[r][k][n], WkT[r][m][l]=Wk[r][l][m],
// Wqb[r][k][p]=Wq[r][k][p] (no transpose), WhpT[n][k]=Whp[k][n]  (all bf16)
__global__ __launch_bounds__(256) void prep_w(
    const float* __restrict__ Wq, const float* __restrict__ Wk,
    const float* __restrict__ Wv, const float* __restrict__ Whp,
    unsigned short* __restrict__ WvT, unsigned short* __restrict__ WkT,
    unsigned short* __restrict__ Wqb, unsigned short* __restrict__ WhpT)
{
    int t = blockIdx.x * 256 + threadIdx.x;
    int slot = t >> 16, o = t & 65535;
    int a = o >> 8, b = o & 255;
    if (slot < 9) {
        int r = slot / 3, kind = slot % 3;
        if (kind == 0)      WvT[(size_t)r * 65536 + o] = f2bf(Wv[(size_t)r * 65536 + b * 256 + a]);
        else if (kind == 1) WkT[(size_t)r * 65536 + o] = f2bf(Wk[(size_t)r * 65536 + b * 256 + a]);
        else                Wqb[(size_t)r * 65536 + o] = f2bf(Wq[(size_t)r * 65536 + a * 256 + b]);
    } else if (slot == 9) {
        WhpT[o] = f2bf(Whp[b * 256 + a]);
    }
}

// fp32 -> bf16, 4 elems/thread
__global__ __launch_bounds__(256) void conv_bf16(
    const float* __restrict__ in, unsigned short* __restrict__ out, int n4)
{
    int t = blockIdx.x * 256 + threadIdx.x;
    if (t < n4) {
        float4 v = ((const float4*)in)[t];
        ushort4 o;
        o.x = f2bf(v.x); o.y = f2bf(v.y); o.z = f2bf(v.z); o.w = f2bf(v.w);
        ((ushort4*)out)[t] = o;
    }
}

// ---------------------------------------------------------------------------
// x (fp32) -> xb (bf16 row-major) + xT (bf16 transposed [256][NPAD], zero-pad)
__global__ __launch_bounds__(256) void transpose_conv(
    const float* __restrict__ x, unsigned short* __restrict__ xb,
    unsigned short* __restrict__ xT)
{
    __shared__ unsigned short t[64][66];
    const int n0 = blockIdx.x * 64, i0 = blockIdx.y * 64;
    const int tid = threadIdx.x;
    const int nl = tid >> 2, c0 = (tid & 3) * 16;
    unsigned short vb[16];
    int n = n0 + nl;
    if (n < NN) {
        const float* src = x + (size_t)n * DD + i0 + c0;
#pragma unroll
        for (int q = 0; q < 16; q += 4) {
            float4 v = *(const float4*)(src + q);
            vb[q] = f2bf(v.x); vb[q + 1] = f2bf(v.y);
            vb[q + 2] = f2bf(v.z); vb[q + 3] = f2bf(v.w);
        }
#pragma unroll
        for (int q = 0; q < 16; q += 4)
            *(ushort4*)(xb + (size_t)n * DD + i0 + c0 + q) =
                make_ushort4(vb[q], vb[q + 1], vb[q + 2], vb[q + 3]);
    } else {
#pragma unroll
        for (int q = 0; q < 16; q++) vb[q] = 0;
    }
#pragma unroll
    for (int q = 0; q < 16; q++) t[nl][c0 + q] = vb[q];
    __syncthreads();
    const int il = tid >> 2, nc0 = (tid & 3) * 16;
    unsigned short ob[16];
#pragma unroll
    for (int q = 0; q < 16; q++) ob[q] = t[nc0 + q][il];
#pragma unroll
    for (int q = 0; q < 16; q += 4)
        *(ushort4*)(xT + (size_t)(i0 + il) * NPAD + n0 + nc0 + q) =
            make_ushort4(ob[q], ob[q + 1], ob[q + 2], ob[q + 3]);
}

// ---------------------------------------------------------------------------
// Degree counts; nr via LDS block counters.
__global__ __launch_bounds__(256) void count_kernel(
    const int* __restrict__ erow, const int* __restrict__ ecol,
    const int* __restrict__ etype, int* __restrict__ c_in,
    int* __restrict__ c_out, int* __restrict__ nr)
{
    __shared__ int lnr[RR];
    if (threadIdx.x < RR) lnr[threadIdx.x] = 0;
    __syncthreads();
    int g = blockIdx.x * blockDim.x + threadIdx.x;
    int stride = gridDim.x * blockDim.x;
    for (int e = g; e < EE; e += stride) {
        int t = etype[e];
        atomicAdd(&c_out[t * NN + erow[e]], 1);
        atomicAdd(&c_in[t * NN + ecol[e]], 1);
        atomicAdd(&lnr[t], 1);
    }
    __syncthreads();
    if (threadIdx.x < RR) atomicAdd(&nr[threadIdx.x], lnr[threadIdx.x]);
}

// c_in -> bf16 weight arrays wbf[3][NPAD] (pad zeros)
__global__ __launch_bounds__(256) void wbf_kernel(
    const int* __restrict__ c_in, unsigned short* __restrict__ wbf)
{
    int t = blockIdx.x * 256 + threadIdx.x;
    if (t < 3 * NPAD) {
        int r = t / NPAD, n = t % NPAD;
        wbf[t] = f2bf(n < NN ? (float)c_in[r * NN + n] : 0.f);
    }
}

// xw[r][i] = sum_n c_in[r][n] * x[n][i]   (block-LDS partials, few atomics)
__global__ __launch_bounds__(256) void xw_kernel(
    const unsigned short* __restrict__ xb, const int* __restrict__ c_in,
    float* __restrict__ xw)
{
    __shared__ float xws[768];
    const int tid = threadIdx.x;
    for (int k = tid; k < 768; k += 256) xws[k] = 0.f;
    __syncthreads();
    const int wid = tid >> 6, lane = tid & 63;
    const int gw = blockIdx.x * 4 + wid;  // 256 waves total (grid 64)
    float acc[3][4] = {};
    for (int n = gw; n < NN; n += 256) {
        ushort4 xv = *(const ushort4*)(xb + (size_t)n * DD + lane * 4);
        float xf[4] = {bf2f(xv.x), bf2f(xv.y), bf2f(xv.z), bf2f(xv.w)};
        float w0 = (float)c_in[n], w1 = (float)c_in[NN + n], w2 = (float)c_in[2 * NN + n];
#pragma unroll
        for (int c = 0; c < 4; c++) {
            acc[0][c] += w0 * xf[c];
            acc[1][c] += w1 * xf[c];
            acc[2][c] += w2 * xf[c];
        }
    }
#pragma unroll
    for (int r = 0; r < 3; r++)
#pragma unroll
        for (int c = 0; c < 4; c++)
            atomicAdd(&xws[r * 256 + lane * 4 + c], acc[r][c]);
    __syncthreads();
    for (int k = tid; k < 768; k += 256) atomicAdd(&xw[k], xws[k]);
}

// ---------------------------------------------------------------------------
// G partials: Gp[z][tile][r][128*128] += xT(w-scaled) @ xT^T over node chunk z
__global__ __launch_bounds__(512) void g_kernel(
    const unsigned short* __restrict__ xT, const unsigned short* __restrict__ wbf,
    float* __restrict__ Gp)
{
    __shared__ __align__(16) char ldsA[16384];
    __shared__ __align__(16) char ldsB[16384];
    const int tid = threadIdx.x, lane = tid & 63, wid = tid >> 6;
    const int wr = wid >> 1, wc = wid & 1;  // 4x2 waves, 32x64 tiles
    const int i0 = blockIdx.x * 128, j0 = blockIdx.y * 128;
    const int TPZ = (NPAD / 64 + GS - 1) / GS;  // 13
    const int kt0 = blockIdx.z * TPZ;
    const int kt1 = min(NPAD / 64, kt0 + TPZ);

    f32x4 acc[3][2][4];
#pragma unroll
    for (int r = 0; r < 3; r++)
#pragma unroll
        for (int m = 0; m < 2; m++)
#pragma unroll
            for (int n = 0; n < 4; n++) acc[r][m][n] = (f32x4){0.f, 0.f, 0.f, 0.f};

    for (int kt = kt0; kt < kt1; kt++) {
        const int kbyte = kt * 128;
#pragma unroll
        for (int is = 0; is < 2; is++) {
            int lb = is * 8192 + wid * 1024;
            int d = lb + lane * 16;
            int row = d >> 7;
            int sc_ = (d & 127) ^ ((row & 7) << 4);
            gload_lds16((const char*)xT + (size_t)(i0 + row) * (NPAD * 2) + kbyte + sc_, ldsA + lb);
            gload_lds16((const char*)xT + (size_t)(j0 + row) * (NPAD * 2) + kbyte + sc_, ldsB + lb);
        }
        __syncthreads();
#pragma unroll
        for (int kk = 0; kk < 2; kk++) {
            const int cb = kk * 64 + ((lane >> 4) << 4);
            bf16x8 bfr[4];
#pragma unroll
            for (int n = 0; n < 4; n++) {
                int rn = wc * 64 + n * 16 + (lane & 15);
                bfr[n] = *(const bf16x8*)(ldsB + rn * 128 + (cb ^ ((rn & 7) << 4)));
            }
            float au[2][8];
#pragma unroll
            for (int m = 0; m < 2; m++) {
                int row = wr * 32 + m * 16 + (lane & 15);
                bf16x8 ar = *(const bf16x8*)(ldsA + row * 128 + (cb ^ ((row & 7) << 4)));
#pragma unroll
                for (int q = 0; q < 8; q++) au[m][q] = bf2f((unsigned short)ar[q]);
            }
            const int nb = kt * 64 + kk * 32 + ((lane >> 4) << 3);
#pragma unroll
            for (int r = 0; r < 3; r++) {
                bf16x8 wv = *(const bf16x8*)(wbf + (size_t)r * NPAD + nb);
                float wf[8];
#pragma unroll
                for (int q = 0; q < 8; q++) wf[q] = bf2f((unsigned short)wv[q]);
                bf16x8 am[2];
#pragma unroll
                for (int m = 0; m < 2; m++)
#pragma unroll
                    for (int q = 0; q < 8; q++)
                        am[m][q] = (short)f2bf(au[m][q] * wf[q]);
#pragma unroll
                for (int m = 0; m < 2; m++)
#pragma unroll
                    for (int n = 0; n < 4; n++)
                        acc[r][m][n] = __builtin_amdgcn_mfma_f32_16x16x32_bf16(
                            am[m], bfr[n], acc[r][m][n], 0, 0, 0);
            }
        }
        __syncthreads();
    }
    float* base = Gp + ((size_t)blockIdx.z * 4 + blockIdx.x * 2 + blockIdx.y) * 3 * 16384;
#pragma unroll
    for (int r = 0; r < 3; r++)
#pragma unroll
        for (int m = 0; m < 2; m++)
#pragma unroll
            for (int n = 0; n < 4; n++) {
                int col = wc * 64 + n * 16 + (lane & 15);
                int rw0 = wr * 32 + m * 16 + ((lane >> 4) << 2);
#pragma unroll
                for (int reg = 0; reg < 4; reg++)
                    base[r * 16384 + (rw0 + reg) * 128 + col] = acc[r][m][n][reg];
            }
}

// Reduce Gp over z, emit Gb (bf16 [3][256][256])
__global__ __launch_bounds__(256) void greduce_kernel(
    const float* __restrict__ Gp, unsigned short* __restrict__ Gb)
{
    int gid = blockIdx.x * 256 + threadIdx.x;  // 12*16384 total
    int t = gid >> 14, rem = gid & 16383;
    int r = t % 3, tile = t / 3;
    float s = 0.f;
    for (int z = 0; z < GS; z++)
        s += Gp[(size_t)z * 196608 + ((size_t)tile * 3 + r) * 16384 + rem];
    int i = (tile >> 1) * 128 + (rem >> 7);
    int j = (tile & 1) * 128 + (rem & 127);
    Gb[(size_t)r * 65536 + i * 256 + j] = f2bf(s);
}

// y[r][row] = dot(Mat[r] row (bf16,256), v[r] (f32,256))
__global__ __launch_bounds__(256) void matvec_bf(
    const unsigned short* __restrict__ Mat, const float* __restrict__ v,
    float* __restrict__ y)
{
    __shared__ float vs[256];
    const int b = blockIdx.x;
    const int r = b >> 6, rb = (b & 63) * 4;
    const int tid = threadIdx.x;
    vs[tid] = v[r * 256 + tid];
    __syncthreads();
    const int wid = tid >> 6, lane = tid & 63;
    const int row = rb + wid;
    ushort4 m4 = *(const ushort4*)(Mat + (size_t)r * 65536 + row * 256 + lane * 4);
    float s = bf2f(m4.x) * vs[lane * 4] + bf2f(m4.y) * vs[lane * 4 + 1] +
              bf2f(m4.z) * vs[lane * 4 + 2] + bf2f(m4.w) * vs[lane * 4 + 3];
#pragma unroll
    for (int off = 32; off; off >>= 1) s += __shfl_down(s, off, 64);
    if (lane == 0) y[r * 256 + row] = s;
}

// qs[r][n] = x[n] . t[r]   (one wave per node, 3 relations at once)
__global__ __launch_bounds__(256) void qs_kernel(
    const unsigned short* __restrict__ xb, const float* __restrict__ tv,
    float* __restrict__ qs)
{
    __shared__ float ts[768];
    const int tid = threadIdx.x;
    for (int k = tid; k < 768; k += 256) ts[k] = tv[k];
    __syncthreads();
    const int wid = tid >> 6, lane = tid & 63;
    const int n = blockIdx.x * 4 + wid;
    if (n < NN) {
        ushort4 xv = *(const ushort4*)(xb + (size_t)n * DD + lane * 4);
        float xf[4] = {bf2f(xv.x), bf2f(xv.y), bf2f(xv.z), bf2f(xv.w)};
        float s0 = 0, s1 = 0, s2 = 0;
#pragma unroll
        for (int c = 0; c < 4; c++) {
            s0 += xf[c] * ts[lane * 4 + c];
            s1 += xf[c] * ts[256 + lane * 4 + c];
            s2 += xf[c] * ts[512 + lane * 4 + c];
        }
#pragma unroll
        for (int off = 32; off; off >>= 1) {
            s0 += __shfl_down(s0, off, 64);
            s1 += __shfl_down(s1, off, 64);
            s2 += __shfl_down(s2, off, 64);
        }
        if (lane == 0) { qs[n] = s0; qs[NN + n] = s1; qs[2 * NN + n] = s2; }
    }
}

// ---------------------------------------------------------------------------
// MFMA NT GEMM: C[M,N=256] = A[M,256] @ B[256,256]^T (bf16 in, fp32 acc)
// MODE 0: bf16 store; MODE 1: fp32 store; MODE 2: C += cnt[row]/(qs[row]+Nr)*acc
template <int MODE>
__global__ __launch_bounds__(256) void gemm_nt(
    const unsigned short* __restrict__ A, int lda,
    const unsigned short* __restrict__ B, int ldb,
    void* __restrict__ Cv, int ldc, int M,
    size_t sa, size_t sb, size_t sc,
    const float* __restrict__ qs, const int* __restrict__ cnt,
    const int* __restrict__ nrp)
{
    A += (size_t)blockIdx.z * sa;
    B += (size_t)blockIdx.z * sb;
    __shared__ __align__(16) char ldsA[16384];
    __shared__ __align__(16) char ldsB[16384];
    const int tid = threadIdx.x, lane = tid & 63, wid = tid >> 6;
    const int wr = wid >> 1, wc = wid & 1;
    const int row0 = blockIdx.x * 128, col0 = blockIdx.y * 128;

    f32x4 acc[4][4];
#pragma unroll
    for (int m = 0; m < 4; m++)
#pragma unroll
        for (int n = 0; n < 4; n++) acc[m][n] = (f32x4){0.f, 0.f, 0.f, 0.f};

    for (int k0 = 0; k0 < DD; k0 += 64) {
#pragma unroll
        for (int is = 0; is < 4; is++) {
            int lb = is * 4096 + wid * 1024;
            int d = lb + lane * 16;
            int row = d >> 7;
            int sc_ = (d & 127) ^ ((row & 7) << 4);
            int gr = row0 + row; gr = gr < M ? gr : M - 1;
            gload_lds16((const char*)(A + (size_t)gr * lda + k0) + sc_, ldsA + lb);
            int rn = col0 + row;
            gload_lds16((const char*)(B + (size_t)rn * ldb + k0) + sc_, ldsB + lb);
        }
        __syncthreads();
#pragma unroll
        for (int kk = 0; kk < 2; kk++) {
            bf16x8 af[4], bf_[4];
            const int cb = kk * 64 + ((lane >> 4) << 4);
#pragma unroll
            for (int m = 0; m < 4; m++) {
                int row = wr * 64 + m * 16 + (lane & 15);
                af[m] = *(const bf16x8*)(ldsA + row * 128 + (cb ^ ((row & 7) << 4)));
                int rn = wc * 64 + m * 16 + (lane & 15);
                bf_[m] = *(const bf16x8*)(ldsB + rn * 128 + (cb ^ ((rn & 7) << 4)));
            }
#pragma unroll
            for (int m = 0; m < 4; m++)
#pragma unroll
                for (int n = 0; n < 4; n++)
                    acc[m][n] = __builtin_amdgcn_mfma_f32_16x16x32_bf16(
                        af[m], bf_[n], acc[m][n], 0, 0, 0);
        }
        __syncthreads();
    }

    float nrf = 0.f;
    if (MODE == 2) nrf = (float)nrp[0];
#pragma unroll
    for (int m = 0; m < 4; m++) {
#pragma unroll
        for (int reg = 0; reg < 4; reg++) {
            int r = row0 + wr * 64 + m * 16 + ((lane >> 4) << 2) + reg;
            if (r >= M) continue;
            float s = 0.f;
            if (MODE == 2) {
                int c = cnt[r];
                s = c ? (float)c / (qs[r] + nrf) : 0.f;
            }
#pragma unroll
            for (int n = 0; n < 4; n++) {
                int c = col0 + wc * 64 + n * 16 + (lane & 15);
                float v = acc[m][n][reg];
                if (MODE == 0)
                    ((unsigned short*)Cv)[(size_t)blockIdx.z * sc + (size_t)r * ldc + c] = f2bf(v);
                else if (MODE == 1)
                    ((float*)Cv)[(size_t)blockIdx.z * sc + (size_t)r * ldc + c] = v;
                else
                    ((float*)Cv)[(size_t)r * ldc + c] += s * v;
            }
        }
    }
}

// ---------------------------------------------------------------------------
// x_out[row] += (Nr_t/(qs[t][row]+Nr_t)) * V_t[col]   (one wave per edge)
__global__ __launch_bounds__(256) void scatter_kernel(
    const int* __restrict__ erow, const int* __restrict__ ecol,
    const int* __restrict__ etype,
    const unsigned short* __restrict__ V, const float* __restrict__ qs,
    const int* __restrict__ nr, float* __restrict__ x_out)
{
    long long g = (long long)blockIdx.x * blockDim.x + threadIdx.x;
    int e = (int)(g >> 6);
    int lane = (int)(g & 63);
    if (e >= EE) return;
    int t = etype[e], rw = erow[e], cl = ecol[e];
    float nrf = (float)nr[t];
    float s = nrf / (qs[(size_t)t * NN + rw] + nrf);
    ushort4 v4 = *(const ushort4*)(V + ((size_t)t * NN + cl) * DD + lane * 4);
    float* xp = x_out + (size_t)rw * DD + lane * 4;
    atomicAdd(xp + 0, s * bf2f(v4.x));
    atomicAdd(xp + 1, s * bf2f(v4.y));
    atomicAdd(xp + 2, s * bf2f(v4.z));
    atomicAdd(xp + 3, s * bf2f(v4.w));
}

// ---------------------------------------------------------------------------
extern "C" void kernel_launch(void* const* d_in, const int* in_sizes, int n_in,
                              void* d_out, int out_size, void* d_ws, size_t ws_size,
                              hipStream_t stream)
{
    const float* x   = (const float*)d_in[0];
    const float* Wq  = (const float*)d_in[1];
    const float* Wk  = (const float*)d_in[2];
    const float* Wv  = (const float*)d_in[3];
    const float* Whp = (const float*)d_in[4];
    const int* eidx  = (const int*)d_in[5];
    const int* etyp  = (const int*)d_in[6];
    const int* erow = eidx;
    const int* ecol = eidx + EE;
    float* out = (float*)d_out;

    char* p = (char*)d_ws;
    unsigned short* xb   = (unsigned short*)p; p += (size_t)NN * DD * 2;        // 25.6 MB
    unsigned short* xT   = (unsigned short*)p; p += (size_t)DD * NPAD * 2;      // 25.6 MB
    char*           regB = p;                  p += (size_t)RR * NN * DD * 2;   // 76.8 MB (Gp then V)
    float*          x_out= (float*)p;          p += (size_t)NN * DD * 4;        // 51.2 MB
    unsigned short* Gb   = (unsigned short*)p; p += (size_t)RR * 65536 * 2;
    unsigned short* U1   = (unsigned short*)p; p += (size_t)RR * 65536 * 2;
    unsigned short* U2   = (unsigned short*)p; p += (size_t)RR * 65536 * 2;
    unsigned short* U3   = (unsigned short*)p; p += (size_t)RR * 65536 * 2;
    unsigned short* WvT  = (unsigned short*)p; p += (size_t)RR * 65536 * 2;
    unsigned short* WkT  = (unsigned short*)p; p += (size_t)RR * 65536 * 2;
    unsigned short* Wqb  = (unsigned short*)p; p += (size_t)RR * 65536 * 2;
    unsigned short* WhpT = (unsigned short*)p; p += 65536 * 2;
    unsigned short* wbf  = (unsigned short*)p; p += (size_t)RR * NPAD * 2;
    float*          qs   = (float*)p;          p += (size_t)RR * NN * 4;
    float*          xw   = (float*)p;          p += 768 * 4;
    float*          ks   = (float*)p;          p += 768 * 4;
    float*          tv   = (float*)p;          p += 768 * 4;
    int*            c_in = (int*)p;            p += (size_t)RR * NN * 4;
    int*            c_out= (int*)p;            p += (size_t)RR * NN * 4;
    int*            nr   = (int*)p;
    float*          Gp   = (float*)regB;       // 50.3 MB, dead before V written
    unsigned short* V    = (unsigned short*)regB;
    unsigned short* xob  = xT;                 // xT dead after g_kernel

    prep_w<<<2560, 256, 0, stream>>>(Wq, Wk, Wv, Whp, WvT, WkT, Wqb, WhpT);
    transpose_conv<<<dim3(NPAD / 64, 4), 256, 0, stream>>>(x, xb, xT);
    hipMemsetAsync(x_out, 0, (size_t)NN * DD * sizeof(float), stream);
    hipMemsetAsync(c_in, 0, (size_t)(6 * NN + 3) * sizeof(int), stream);
    hipMemsetAsync(xw, 0, 768 * sizeof(float), stream);
    count_kernel<<<512, 256, 0, stream>>>(erow, ecol, etyp, c_in, c_out, nr);
    wbf_kernel<<<(3 * NPAD + 255) / 256, 256, 0, stream>>>(c_in, wbf);
    xw_kernel<<<64, 256, 0, stream>>>(xb, c_in, xw);

    g_kernel<<<dim3(2, 2, GS), 512, 0, stream>>>(xT, wbf, Gp);
    greduce_kernel<<<12 * 64, 256, 0, stream>>>(Gp, Gb);

    // kvs^T = Wv^T G Wk ; num B-operand U3 = kvs^T Wq^T   (batched over r)
    gemm_nt<0><<<dim3(2, 2, 3), 256, 0, stream>>>(WvT, 256, Gb, 256, U1, 256, 256,
                                                  65536, 65536, 65536, nullptr, nullptr, nullptr);
    gemm_nt<0><<<dim3(2, 2, 3), 256, 0, stream>>>(U1, 256, WkT, 256, U2, 256, 256,
                                                  65536, 65536, 65536, nullptr, nullptr, nullptr);
    gemm_nt<0><<<dim3(2, 2, 3), 256, 0, stream>>>(U2, 256, Wqb, 256, U3, 256, 256,
                                                  65536, 65536, 65536, nullptr, nullptr, nullptr);
    matvec_bf<<<192, 256, 0, stream>>>(WkT, xw, ks);   // ks = Wk^T (x^T w)
    matvec_bf<<<192, 256, 0, stream>>>(Wqb, ks, tv);   // t  = Wq ks
    qs_kernel<<<(NN + 3) / 4, 256, 0, stream>>>(xb, tv, qs);

    const int MB = (NN + 127) / 128;  // 391
    gemm_nt<0><<<dim3(MB, 2, 3), 256, 0, stream>>>(xb, 256, WvT, 256, V, 256, NN,
                                                   0, 65536, (size_t)NN * DD, nullptr, nullptr, nullptr);
    for (int r = 0; r < RR; r++)
        gemm_nt<2><<<dim3(MB, 2), 256, 0, stream>>>(xb, 256, U3 + (size_t)r * 65536, 256,
                                                    x_out, 256, NN, 0, 0, 0,
                                                    qs + (size_t)r * NN, c_out + (size_t)r * NN, nr + r);
    scatter_kernel<<<(EE * 64) / 256, 256, 0, stream>>>(erow, ecol, etyp, V, qs, nr, x_out);

    conv_bf16<<<(NN * DD / 4 + 255) / 256, 256, 0, stream>>>(x_out, xob, NN * DD / 4);
    gemm_nt<1><<<dim3(MB, 2), 256, 0, stream>>>(xob, 256, WhpT, 256, out, 256, NN,
                                                0, 0, 0, nullptr, nullptr, nullptr);
}

// Round 5
// 846.736 us; speedup vs baseline: 5.3881x; 1.6849x over previous
//
#include <hip/hip_runtime.h>

#define NN 50000
#define EE 300000
#define DD 256
#define RR 3
#define NPAD 50048            // 782 * 64
#define GS 64                 // split-K slices for G

using bf16x8 = __attribute__((ext_vector_type(8))) short;
using f32x4  = __attribute__((ext_vector_type(4))) float;

__device__ __forceinline__ float bf2f(unsigned short u) {
    return __uint_as_float(((unsigned)u) << 16);
}
__device__ __forceinline__ unsigned short f2bf(float f) {
    unsigned u = __float_as_uint(f);
    return (unsigned short)((u + 0x7fffu + ((u >> 16) & 1u)) >> 16);
}
__device__ __forceinline__ void gload_lds16(const void* g, void* l) {
    __builtin_amdgcn_global_load_lds(
        (const __attribute__((address_space(1))) unsigned int*)g,
        (__attribute__((address_space(3))) unsigned int*)l, 16, 0, 0);
}

// ---------------------------------------------------------------------------
// Weight prep: WvTcat[j][r*256+k]=Wv[r][k][j]  (B-operand for K=768 GEMM and
// A-operand rows at offset r*256, lda=768);  WkT[r][m][l]=Wk[r][l][m];
// Wqb[r][k][p]=Wq[r][k][p];  WhpT[n][k]=Whp[k][n]   (all bf16)
__global__ __launch_bounds__(256) void prep_w(
    const float* __restrict__ Wq, const float* __restrict__ Wk,
    const float* __restrict__ Wv, const float* __restrict__ Whp,
    unsigned short* __restrict__ WvTcat, unsigned short* __restrict__ WkT,
    unsigned short* __restrict__ Wqb, unsigned short* __restrict__ WhpT)
{
    int t = blockIdx.x * 256 + threadIdx.x;
    int slot = t >> 16, o = t & 65535;
    int a = o >> 8, b = o & 255;
    if (slot < 9) {
        int r = slot / 3, kind = slot % 3;
        if (kind == 0)      WvTcat[(size_t)a * 768 + r * 256 + b] = f2bf(Wv[(size_t)r * 65536 + b * 256 + a]);
        else if (kind == 1) WkT[(size_t)r * 65536 + o] = f2bf(Wk[(size_t)r * 65536 + b * 256 + a]);
        else                Wqb[(size_t)r * 65536 + o] = f2bf(Wq[(size_t)r * 65536 + a * 256 + b]);
    } else if (slot == 9) {
        WhpT[o] = f2bf(Whp[b * 256 + a]);
    }
}

// fp32 -> bf16, 4 elems/thread
__global__ __launch_bounds__(256) void conv_bf16(
    const float* __restrict__ in, unsigned short* __restrict__ out, int n4)
{
    int t = blockIdx.x * 256 + threadIdx.x;
    if (t < n4) {
        float4 v = ((const float4*)in)[t];
        ushort4 o;
        o.x = f2bf(v.x); o.y = f2bf(v.y); o.z = f2bf(v.z); o.w = f2bf(v.w);
        ((ushort4*)out)[t] = o;
    }
}

// ---------------------------------------------------------------------------
// x (fp32) -> xb (bf16 row-major) + xT (bf16 transposed [256][NPAD], zero-pad)
__global__ __launch_bounds__(256) void transpose_conv(
    const float* __restrict__ x, unsigned short* __restrict__ xb,
    unsigned short* __restrict__ xT)
{
    __shared__ unsigned short t[64][66];
    const int n0 = blockIdx.x * 64, i0 = blockIdx.y * 64;
    const int tid = threadIdx.x;
    const int nl = tid >> 2, c0 = (tid & 3) * 16;
    unsigned short vb[16];
    int n = n0 + nl;
    if (n < NN) {
        const float* src = x + (size_t)n * DD + i0 + c0;
#pragma unroll
        for (int q = 0; q < 16; q += 4) {
            float4 v = *(const float4*)(src + q);
            vb[q] = f2bf(v.x); vb[q + 1] = f2bf(v.y);
            vb[q + 2] = f2bf(v.z); vb[q + 3] = f2bf(v.w);
        }
#pragma unroll
        for (int q = 0; q < 16; q += 4)
            *(ushort4*)(xb + (size_t)n * DD + i0 + c0 + q) =
                make_ushort4(vb[q], vb[q + 1], vb[q + 2], vb[q + 3]);
    } else {
#pragma unroll
        for (int q = 0; q < 16; q++) vb[q] = 0;
    }
#pragma unroll
    for (int q = 0; q < 16; q++) t[nl][c0 + q] = vb[q];
    __syncthreads();
    const int il = tid >> 2, nc0 = (tid & 3) * 16;
    unsigned short ob[16];
#pragma unroll
    for (int q = 0; q < 16; q++) ob[q] = t[nc0 + q][il];
#pragma unroll
    for (int q = 0; q < 16; q += 4)
        *(ushort4*)(xT + (size_t)(i0 + il) * NPAD + n0 + nc0 + q) =
            make_ushort4(ob[q], ob[q + 1], ob[q + 2], ob[q + 3]);
}

// ---------------------------------------------------------------------------
// Degree counts; nr via LDS block counters.
__global__ __launch_bounds__(256) void count_kernel(
    const int* __restrict__ erow, const int* __restrict__ ecol,
    const int* __restrict__ etype, int* __restrict__ c_in,
    int* __restrict__ c_out, int* __restrict__ nr)
{
    __shared__ int lnr[RR];
    if (threadIdx.x < RR) lnr[threadIdx.x] = 0;
    __syncthreads();
    int g = blockIdx.x * blockDim.x + threadIdx.x;
    int stride = gridDim.x * blockDim.x;
    for (int e = g; e < EE; e += stride) {
        int t = etype[e];
        atomicAdd(&c_out[t * NN + erow[e]], 1);
        atomicAdd(&c_in[t * NN + ecol[e]], 1);
        atomicAdd(&lnr[t], 1);
    }
    __syncthreads();
    if (threadIdx.x < RR) atomicAdd(&nr[threadIdx.x], lnr[threadIdx.x]);
}

// Single-block exclusive scan of c_out[3*NN] -> off (and cursor copy cur).
__global__ __launch_bounds__(1024) void scan_kernel(
    const int* __restrict__ cnt, int* __restrict__ off, int* __restrict__ cur)
{
    __shared__ int bs[1024];
    const int T = RR * NN;
    const int tid = threadIdx.x;
    const int per = (T + 1023) / 1024;
    int s0 = tid * per, s1 = min(T, s0 + per);
    int sum = 0;
    for (int i = s0; i < s1; i++) sum += cnt[i];
    bs[tid] = sum;
    __syncthreads();
    for (int d = 1; d < 1024; d <<= 1) {
        int v = (tid >= d) ? bs[tid - d] : 0;
        __syncthreads();
        bs[tid] += v;
        __syncthreads();
    }
    int run = (tid > 0) ? bs[tid - 1] : 0;
    for (int i = s0; i < s1; i++) {
        int c = cnt[i];
        off[i] = run;
        cur[i] = run;
        run += c;
    }
    if (tid == 1023) off[T] = run;
}

// Bucket-fill: sorted_col grouped by key (t*NN+row).
__global__ __launch_bounds__(256) void fill_kernel(
    const int* __restrict__ erow, const int* __restrict__ ecol,
    const int* __restrict__ etype, int* __restrict__ cur,
    int* __restrict__ scol)
{
    int e = blockIdx.x * 256 + threadIdx.x;
    if (e < EE) {
        int key = etype[e] * NN + erow[e];
        int p = atomicAdd(&cur[key], 1);
        scol[p] = ecol[e];
    }
}

// One wave per node: Acat[n][t*256+:] = s(t,n) * sum_{e in seg(t,n)} x[col]
__global__ __launch_bounds__(256) void gather_kernel(
    const unsigned short* __restrict__ xb, const int* __restrict__ scol,
    const int* __restrict__ off, const float* __restrict__ qs,
    const int* __restrict__ nr, unsigned short* __restrict__ Acat)
{
    const int wid = threadIdx.x >> 6, lane = threadIdx.x & 63;
    const int n = blockIdx.x * 4 + wid;
    if (n >= NN) return;
#pragma unroll
    for (int t = 0; t < RR; t++) {
        float acc[4] = {0.f, 0.f, 0.f, 0.f};
        int b0 = off[t * NN + n], b1 = off[t * NN + n + 1];
        for (int i = b0; i < b1; i++) {
            int col = scol[i];
            ushort4 v = *(const ushort4*)(xb + (size_t)col * DD + lane * 4);
            acc[0] += bf2f(v.x); acc[1] += bf2f(v.y);
            acc[2] += bf2f(v.z); acc[3] += bf2f(v.w);
        }
        float nrf = (float)nr[t];
        float s = nrf / (qs[(size_t)t * NN + n] + nrf);
        ushort4 o;
        o.x = f2bf(s * acc[0]); o.y = f2bf(s * acc[1]);
        o.z = f2bf(s * acc[2]); o.w = f2bf(s * acc[3]);
        *(ushort4*)(Acat + (size_t)n * 768 + t * 256 + lane * 4) = o;
    }
}

// c_in -> bf16 weight arrays wbf[3][NPAD] (pad zeros)
__global__ __launch_bounds__(256) void wbf_kernel(
    const int* __restrict__ c_in, unsigned short* __restrict__ wbf)
{
    int t = blockIdx.x * 256 + threadIdx.x;
    if (t < 3 * NPAD) {
        int r = t / NPAD, n = t % NPAD;
        wbf[t] = f2bf(n < NN ? (float)c_in[r * NN + n] : 0.f);
    }
}

// xw[r][i] = sum_n c_in[r][n] * x[n][i]
__global__ __launch_bounds__(256) void xw_kernel(
    const unsigned short* __restrict__ xb, const int* __restrict__ c_in,
    float* __restrict__ xw)
{
    __shared__ float xws[768];
    const int tid = threadIdx.x;
    for (int k = tid; k < 768; k += 256) xws[k] = 0.f;
    __syncthreads();
    const int wid = tid >> 6, lane = tid & 63;
    const int gw = blockIdx.x * 4 + wid;
    float acc[3][4] = {};
    for (int n = gw; n < NN; n += 256) {
        ushort4 xv = *(const ushort4*)(xb + (size_t)n * DD + lane * 4);
        float xf[4] = {bf2f(xv.x), bf2f(xv.y), bf2f(xv.z), bf2f(xv.w)};
        float w0 = (float)c_in[n], w1 = (float)c_in[NN + n], w2 = (float)c_in[2 * NN + n];
#pragma unroll
        for (int c = 0; c < 4; c++) {
            acc[0][c] += w0 * xf[c];
            acc[1][c] += w1 * xf[c];
            acc[2][c] += w2 * xf[c];
        }
    }
#pragma unroll
    for (int r = 0; r < 3; r++)
#pragma unroll
        for (int c = 0; c < 4; c++)
            atomicAdd(&xws[r * 256 + lane * 4 + c], acc[r][c]);
    __syncthreads();
    for (int k = tid; k < 768; k += 256) atomicAdd(&xw[k], xws[k]);
}

// ---------------------------------------------------------------------------
// G partials: Gp[z][tile][r][128*128] += xT(w-scaled) @ xT^T over node chunk z
__global__ __launch_bounds__(512) void g_kernel(
    const unsigned short* __restrict__ xT, const unsigned short* __restrict__ wbf,
    float* __restrict__ Gp)
{
    __shared__ __align__(16) char ldsA[16384];
    __shared__ __align__(16) char ldsB[16384];
    const int tid = threadIdx.x, lane = tid & 63, wid = tid >> 6;
    const int wr = wid >> 1, wc = wid & 1;
    const int i0 = blockIdx.x * 128, j0 = blockIdx.y * 128;
    const int TPZ = (NPAD / 64 + GS - 1) / GS;
    const int kt0 = blockIdx.z * TPZ;
    const int kt1 = min(NPAD / 64, kt0 + TPZ);

    f32x4 acc[3][2][4];
#pragma unroll
    for (int r = 0; r < 3; r++)
#pragma unroll
        for (int m = 0; m < 2; m++)
#pragma unroll
            for (int n = 0; n < 4; n++) acc[r][m][n] = (f32x4){0.f, 0.f, 0.f, 0.f};

    for (int kt = kt0; kt < kt1; kt++) {
        const int kbyte = kt * 128;
#pragma unroll
        for (int is = 0; is < 2; is++) {
            int lb = is * 8192 + wid * 1024;
            int d = lb + lane * 16;
            int row = d >> 7;
            int sc_ = (d & 127) ^ ((row & 7) << 4);
            gload_lds16((const char*)xT + (size_t)(i0 + row) * (NPAD * 2) + kbyte + sc_, ldsA + lb);
            gload_lds16((const char*)xT + (size_t)(j0 + row) * (NPAD * 2) + kbyte + sc_, ldsB + lb);
        }
        __syncthreads();
#pragma unroll
        for (int kk = 0; kk < 2; kk++) {
            const int cb = kk * 64 + ((lane >> 4) << 4);
            bf16x8 bfr[4];
#pragma unroll
            for (int n = 0; n < 4; n++) {
                int rn = wc * 64 + n * 16 + (lane & 15);
                bfr[n] = *(const bf16x8*)(ldsB + rn * 128 + (cb ^ ((rn & 7) << 4)));
            }
            float au[2][8];
#pragma unroll
            for (int m = 0; m < 2; m++) {
                int row = wr * 32 + m * 16 + (lane & 15);
                bf16x8 ar = *(const bf16x8*)(ldsA + row * 128 + (cb ^ ((row & 7) << 4)));
#pragma unroll
                for (int q = 0; q < 8; q++) au[m][q] = bf2f((unsigned short)ar[q]);
            }
            const int nb = kt * 64 + kk * 32 + ((lane >> 4) << 3);
#pragma unroll
            for (int r = 0; r < 3; r++) {
                bf16x8 wv = *(const bf16x8*)(wbf + (size_t)r * NPAD + nb);
                float wf[8];
#pragma unroll
                for (int q = 0; q < 8; q++) wf[q] = bf2f((unsigned short)wv[q]);
                bf16x8 am[2];
#pragma unroll
                for (int m = 0; m < 2; m++)
#pragma unroll
                    for (int q = 0; q < 8; q++)
                        am[m][q] = (short)f2bf(au[m][q] * wf[q]);
#pragma unroll
                for (int m = 0; m < 2; m++)
#pragma unroll
                    for (int n = 0; n < 4; n++)
                        acc[r][m][n] = __builtin_amdgcn_mfma_f32_16x16x32_bf16(
                            am[m], bfr[n], acc[r][m][n], 0, 0, 0);
            }
        }
        __syncthreads();
    }
    float* base = Gp + ((size_t)blockIdx.z * 4 + blockIdx.x * 2 + blockIdx.y) * 3 * 16384;
#pragma unroll
    for (int r = 0; r < 3; r++)
#pragma unroll
        for (int m = 0; m < 2; m++)
#pragma unroll
            for (int n = 0; n < 4; n++) {
                int col = wc * 64 + n * 16 + (lane & 15);
                int rw0 = wr * 32 + m * 16 + ((lane >> 4) << 2);
#pragma unroll
                for (int reg = 0; reg < 4; reg++)
                    base[r * 16384 + (rw0 + reg) * 128 + col] = acc[r][m][n][reg];
            }
}

// Reduce Gp over z, emit Gb (bf16 [3][256][256])
__global__ __launch_bounds__(256) void greduce_kernel(
    const float* __restrict__ Gp, unsigned short* __restrict__ Gb)
{
    int gid = blockIdx.x * 256 + threadIdx.x;
    int t = gid >> 14, rem = gid & 16383;
    int r = t % 3, tile = t / 3;
    float s = 0.f;
    for (int z = 0; z < GS; z++)
        s += Gp[(size_t)z * 196608 + ((size_t)tile * 3 + r) * 16384 + rem];
    int i = (tile >> 1) * 128 + (rem >> 7);
    int j = (tile & 1) * 128 + (rem & 127);
    Gb[(size_t)r * 65536 + i * 256 + j] = f2bf(s);
}

// y[r][row] = dot(Mat[r] row (bf16,256), v[r] (f32,256))
__global__ __launch_bounds__(256) void matvec_bf(
    const unsigned short* __restrict__ Mat, const float* __restrict__ v,
    float* __restrict__ y)
{
    __shared__ float vs[256];
    const int b = blockIdx.x;
    const int r = b >> 6, rb = (b & 63) * 4;
    const int tid = threadIdx.x;
    vs[tid] = v[r * 256 + tid];
    __syncthreads();
    const int wid = tid >> 6, lane = tid & 63;
    const int row = rb + wid;
    ushort4 m4 = *(const ushort4*)(Mat + (size_t)r * 65536 + row * 256 + lane * 4);
    float s = bf2f(m4.x) * vs[lane * 4] + bf2f(m4.y) * vs[lane * 4 + 1] +
              bf2f(m4.z) * vs[lane * 4 + 2] + bf2f(m4.w) * vs[lane * 4 + 3];
#pragma unroll
    for (int off = 32; off; off >>= 1) s += __shfl_down(s, off, 64);
    if (lane == 0) y[r * 256 + row] = s;
}

// qs[r][n] = x[n] . t[r]
__global__ __launch_bounds__(256) void qs_kernel(
    const unsigned short* __restrict__ xb, const float* __restrict__ tv,
    float* __restrict__ qs)
{
    __shared__ float ts[768];
    const int tid = threadIdx.x;
    for (int k = tid; k < 768; k += 256) ts[k] = tv[k];
    __syncthreads();
    const int wid = tid >> 6, lane = tid & 63;
    const int n = blockIdx.x * 4 + wid;
    if (n < NN) {
        ushort4 xv = *(const ushort4*)(xb + (size_t)n * DD + lane * 4);
        float xf[4] = {bf2f(xv.x), bf2f(xv.y), bf2f(xv.z), bf2f(xv.w)};
        float s0 = 0, s1 = 0, s2 = 0;
#pragma unroll
        for (int c = 0; c < 4; c++) {
            s0 += xf[c] * ts[lane * 4 + c];
            s1 += xf[c] * ts[256 + lane * 4 + c];
            s2 += xf[c] * ts[512 + lane * 4 + c];
        }
#pragma unroll
        for (int off = 32; off; off >>= 1) {
            s0 += __shfl_down(s0, off, 64);
            s1 += __shfl_down(s1, off, 64);
            s2 += __shfl_down(s2, off, 64);
        }
        if (lane == 0) { qs[n] = s0; qs[NN + n] = s1; qs[2 * NN + n] = s2; }
    }
}

// ---------------------------------------------------------------------------
// MFMA NT GEMM: C[M,N=256] = A[M,KK] @ B[256,KK]^T (bf16 in, fp32 acc)
// MODE 0: bf16 store; MODE 1: fp32 store; MODE 2: C += cnt[row]/(qs[row]+Nr)*acc
// MODE 3: C += acc (fp32)
template <int MODE>
__global__ __launch_bounds__(256) void gemm_nt(
    const unsigned short* __restrict__ A, int lda,
    const unsigned short* __restrict__ B, int ldb,
    void* __restrict__ Cv, int ldc, int M, int KK,
    size_t sa, size_t sb, size_t sc,
    const float* __restrict__ qs, const int* __restrict__ cnt,
    const int* __restrict__ nrp)
{
    A += (size_t)blockIdx.z * sa;
    B += (size_t)blockIdx.z * sb;
    __shared__ __align__(16) char ldsA[16384];
    __shared__ __align__(16) char ldsB[16384];
    const int tid = threadIdx.x, lane = tid & 63, wid = tid >> 6;
    const int wr = wid >> 1, wc = wid & 1;
    const int row0 = blockIdx.x * 128, col0 = blockIdx.y * 128;

    f32x4 acc[4][4];
#pragma unroll
    for (int m = 0; m < 4; m++)
#pragma unroll
        for (int n = 0; n < 4; n++) acc[m][n] = (f32x4){0.f, 0.f, 0.f, 0.f};

    for (int k0 = 0; k0 < KK; k0 += 64) {
#pragma unroll
        for (int is = 0; is < 4; is++) {
            int lb = is * 4096 + wid * 1024;
            int d = lb + lane * 16;
            int row = d >> 7;
            int sc_ = (d & 127) ^ ((row & 7) << 4);
            int gr = row0 + row; gr = gr < M ? gr : M - 1;
            gload_lds16((const char*)(A + (size_t)gr * lda + k0) + sc_, ldsA + lb);
            int rn = col0 + row;
            gload_lds16((const char*)(B + (size_t)rn * ldb + k0) + sc_, ldsB + lb);
        }
        __syncthreads();
#pragma unroll
        for (int kk = 0; kk < 2; kk++) {
            bf16x8 af[4], bf_[4];
            const int cb = kk * 64 + ((lane >> 4) << 4);
#pragma unroll
            for (int m = 0; m < 4; m++) {
                int row = wr * 64 + m * 16 + (lane & 15);
                af[m] = *(const bf16x8*)(ldsA + row * 128 + (cb ^ ((row & 7) << 4)));
                int rn = wc * 64 + m * 16 + (lane & 15);
                bf_[m] = *(const bf16x8*)(ldsB + rn * 128 + (cb ^ ((rn & 7) << 4)));
            }
#pragma unroll
            for (int m = 0; m < 4; m++)
#pragma unroll
                for (int n = 0; n < 4; n++)
                    acc[m][n] = __builtin_amdgcn_mfma_f32_16x16x32_bf16(
                        af[m], bf_[n], acc[m][n], 0, 0, 0);
        }
        __syncthreads();
    }

    float nrf = 0.f;
    if (MODE == 2) nrf = (float)nrp[0];
#pragma unroll
    for (int m = 0; m < 4; m++) {
#pragma unroll
        for (int reg = 0; reg < 4; reg++) {
            int r = row0 + wr * 64 + m * 16 + ((lane >> 4) << 2) + reg;
            if (r >= M) continue;
            float s = 0.f;
            if (MODE == 2) {
                int c = cnt[r];
                s = c ? (float)c / (qs[r] + nrf) : 0.f;
            }
#pragma unroll
            for (int n = 0; n < 4; n++) {
                int c = col0 + wc * 64 + n * 16 + (lane & 15);
                float v = acc[m][n][reg];
                if (MODE == 0)
                    ((unsigned short*)Cv)[(size_t)blockIdx.z * sc + (size_t)r * ldc + c] = f2bf(v);
                else if (MODE == 1)
                    ((float*)Cv)[(size_t)blockIdx.z * sc + (size_t)r * ldc + c] = v;
                else if (MODE == 2)
                    ((float*)Cv)[(size_t)r * ldc + c] += s * v;
                else
                    ((float*)Cv)[(size_t)r * ldc + c] += v;
            }
        }
    }
}

// ---------------------------------------------------------------------------
extern "C" void kernel_launch(void* const* d_in, const int* in_sizes, int n_in,
                              void* d_out, int out_size, void* d_ws, size_t ws_size,
                              hipStream_t stream)
{
    const float* x   = (const float*)d_in[0];
    const float* Wq  = (const float*)d_in[1];
    const float* Wk  = (const float*)d_in[2];
    const float* Wv  = (const float*)d_in[3];
    const float* Whp = (const float*)d_in[4];
    const int* eidx  = (const int*)d_in[5];
    const int* etyp  = (const int*)d_in[6];
    const int* erow = eidx;
    const int* ecol = eidx + EE;
    float* out = (float*)d_out;

    char* p = (char*)d_ws;
    unsigned short* xb    = (unsigned short*)p; p += (size_t)NN * DD * 2;        // 25.6 MB
    unsigned short* xT    = (unsigned short*)p; p += (size_t)DD * NPAD * 2;      // 25.6 MB
    char*           regB  = p;                  p += (size_t)NN * 768 * 2;       // 76.8 MB (Gp then Acat)
    float*          x_out = (float*)p;          p += (size_t)NN * DD * 4;        // 51.2 MB
    unsigned short* Gb    = (unsigned short*)p; p += (size_t)RR * 65536 * 2;
    unsigned short* U1    = (unsigned short*)p; p += (size_t)RR * 65536 * 2;
    unsigned short* U2    = (unsigned short*)p; p += (size_t)RR * 65536 * 2;
    unsigned short* U3    = (unsigned short*)p; p += (size_t)RR * 65536 * 2;
    unsigned short* WvTcat= (unsigned short*)p; p += (size_t)256 * 768 * 2;
    unsigned short* WkT   = (unsigned short*)p; p += (size_t)RR * 65536 * 2;
    unsigned short* Wqb   = (unsigned short*)p; p += (size_t)RR * 65536 * 2;
    unsigned short* WhpT  = (unsigned short*)p; p += 65536 * 2;
    unsigned short* wbf   = (unsigned short*)p; p += (size_t)RR * NPAD * 2;
    float*          qs    = (float*)p;          p += (size_t)RR * NN * 4;
    float*          xw    = (float*)p;          p += 768 * 4;
    float*          ks    = (float*)p;          p += 768 * 4;
    float*          tv    = (float*)p;          p += 768 * 4;
    int*            c_in  = (int*)p;            p += (size_t)RR * NN * 4;
    int*            c_out = (int*)p;            p += (size_t)RR * NN * 4;
    int*            off   = (int*)p;            p += (size_t)(RR * NN + 1) * 4;
    int*            cur   = (int*)p;            p += (size_t)RR * NN * 4;
    int*            scol  = (int*)p;            p += (size_t)EE * 4;
    int*            nr    = (int*)p;            p += RR * 4;
    float*          Gp    = (float*)regB;       // 50.3 MB, dead before Acat written
    unsigned short* Acat  = (unsigned short*)regB;
    unsigned short* xob   = xT;                 // xT dead after g_kernel

    prep_w<<<2560, 256, 0, stream>>>(Wq, Wk, Wv, Whp, WvTcat, WkT, Wqb, WhpT);
    transpose_conv<<<dim3(NPAD / 64, 4), 256, 0, stream>>>(x, xb, xT);
    hipMemsetAsync(x_out, 0, (size_t)NN * DD * sizeof(float), stream);
    hipMemsetAsync(c_in, 0, (size_t)(6 * NN) * sizeof(int), stream);
    hipMemsetAsync(nr, 0, RR * sizeof(int), stream);   // FIX: nr was never zeroed (r4 bug)
    hipMemsetAsync(xw, 0, 768 * sizeof(float), stream);
    count_kernel<<<512, 256, 0, stream>>>(erow, ecol, etyp, c_in, c_out, nr);
    scan_kernel<<<1, 1024, 0, stream>>>(c_out, off, cur);
    fill_kernel<<<(EE + 255) / 256, 256, 0, stream>>>(erow, ecol, etyp, cur, scol);
    wbf_kernel<<<(3 * NPAD + 255) / 256, 256, 0, stream>>>(c_in, wbf);
    xw_kernel<<<64, 256, 0, stream>>>(xb, c_in, xw);

    g_kernel<<<dim3(2, 2, GS), 512, 0, stream>>>(xT, wbf, Gp);
    greduce_kernel<<<12 * 64, 256, 0, stream>>>(Gp, Gb);

    // kvs^T = Wv^T G Wk ; num B-operand U3 = kvs^T Wq^T   (batched over r)
    gemm_nt<0><<<dim3(2, 2, 3), 256, 0, stream>>>(WvTcat, 768, Gb, 256, U1, 256, 256, 256,
                                                  256, 65536, 65536, nullptr, nullptr, nullptr);
    gemm_nt<0><<<dim3(2, 2, 3), 256, 0, stream>>>(U1, 256, WkT, 256, U2, 256, 256, 256,
                                                  65536, 65536, 65536, nullptr, nullptr, nullptr);
    gemm_nt<0><<<dim3(2, 2, 3), 256, 0, stream>>>(U2, 256, Wqb, 256, U3, 256, 256, 256,
                                                  65536, 65536, 65536, nullptr, nullptr, nullptr);
    matvec_bf<<<192, 256, 0, stream>>>(WkT, xw, ks);   // ks = Wk^T (x^T w)
    matvec_bf<<<192, 256, 0, stream>>>(Wqb, ks, tv);   // t  = Wq ks
    qs_kernel<<<(NN + 3) / 4, 256, 0, stream>>>(xb, tv, qs);

    // Acat[n] = [s(0,n)*sum x, s(1,n)*sum x, s(2,n)*sum x]  (bf16, K-cat)
    gather_kernel<<<(NN + 3) / 4, 256, 0, stream>>>(xb, scol, off, qs, nr, Acat);

    const int MB = (NN + 127) / 128;  // 391
    for (int r = 0; r < RR; r++)
        gemm_nt<2><<<dim3(MB, 2), 256, 0, stream>>>(xb, 256, U3 + (size_t)r * 65536, 256,
                                                    x_out, 256, NN, 256, 0, 0, 0,
                                                    qs + (size_t)r * NN, c_out + (size_t)r * NN, nr + r);
    gemm_nt<3><<<dim3(MB, 2), 256, 0, stream>>>(Acat, 768, WvTcat, 768, x_out, 256, NN, 768,
                                                0, 0, 0, nullptr, nullptr, nullptr);

    conv_bf16<<<(NN * DD / 4 + 255) / 256, 256, 0, stream>>>(x_out, xob, NN * DD / 4);
    gemm_nt<1><<<dim3(MB, 2), 256, 0, stream>>>(xob, 256, WhpT, 256, out, 256, NN, 256,
                                                0, 0, 0, nullptr, nullptr, nullptr);
}

// Round 6
// 524.432 us; speedup vs baseline: 8.6995x; 1.6146x over previous
//
#include <hip/hip_runtime.h>

#define NN 50000
#define EE 300000
#define DD 256
#define RR 3
#define NPAD 50048            // 782 * 64
#define GS 64                 // split-K slices for G
#define SCT (RR * NN)         // 150000 (divisible by 4)
#define SCB 1024              // elements per scan block
#define SNB ((SCT + SCB - 1) / SCB)  // 147

using bf16x8 = __attribute__((ext_vector_type(8))) short;
using f32x4  = __attribute__((ext_vector_type(4))) float;

__device__ __forceinline__ float bf2f(unsigned short u) {
    return __uint_as_float(((unsigned)u) << 16);
}
__device__ __forceinline__ unsigned short f2bf(float f) {
    unsigned u = __float_as_uint(f);
    return (unsigned short)((u + 0x7fffu + ((u >> 16) & 1u)) >> 16);
}
__device__ __forceinline__ void gload_lds16(const void* g, void* l) {
    __builtin_amdgcn_global_load_lds(
        (const __attribute__((address_space(1))) unsigned int*)g,
        (__attribute__((address_space(3))) unsigned int*)l, 16, 0, 0);
}

// ---------------------------------------------------------------------------
// Weight prep: WvTcat[j][r*256+k]=Wv[r][k][j];  WkT[r][m][l]=Wk[r][l][m];
// Wqb[r][k][p]=Wq[r][k][p];  WhpT[n][k]=Whp[k][n]   (all bf16)
__global__ __launch_bounds__(256) void prep_w(
    const float* __restrict__ Wq, const float* __restrict__ Wk,
    const float* __restrict__ Wv, const float* __restrict__ Whp,
    unsigned short* __restrict__ WvTcat, unsigned short* __restrict__ WkT,
    unsigned short* __restrict__ Wqb, unsigned short* __restrict__ WhpT)
{
    int t = blockIdx.x * 256 + threadIdx.x;
    int slot = t >> 16, o = t & 65535;
    int a = o >> 8, b = o & 255;
    if (slot < 9) {
        int r = slot / 3, kind = slot % 3;
        if (kind == 0)      WvTcat[(size_t)a * 768 + r * 256 + b] = f2bf(Wv[(size_t)r * 65536 + b * 256 + a]);
        else if (kind == 1) WkT[(size_t)r * 65536 + o] = f2bf(Wk[(size_t)r * 65536 + b * 256 + a]);
        else                Wqb[(size_t)r * 65536 + o] = f2bf(Wq[(size_t)r * 65536 + a * 256 + b]);
    } else if (slot == 9) {
        WhpT[o] = f2bf(Whp[b * 256 + a]);
    }
}

// fp32 -> bf16, 4 elems/thread
__global__ __launch_bounds__(256) void conv_bf16(
    const float* __restrict__ in, unsigned short* __restrict__ out, int n4)
{
    int t = blockIdx.x * 256 + threadIdx.x;
    if (t < n4) {
        float4 v = ((const float4*)in)[t];
        ushort4 o;
        o.x = f2bf(v.x); o.y = f2bf(v.y); o.z = f2bf(v.z); o.w = f2bf(v.w);
        ((ushort4*)out)[t] = o;
    }
}

// ---------------------------------------------------------------------------
// x (fp32) -> xb (bf16 row-major) + xT (bf16 transposed [256][NPAD], zero-pad)
__global__ __launch_bounds__(256) void transpose_conv(
    const float* __restrict__ x, unsigned short* __restrict__ xb,
    unsigned short* __restrict__ xT)
{
    __shared__ unsigned short t[64][66];
    const int n0 = blockIdx.x * 64, i0 = blockIdx.y * 64;
    const int tid = threadIdx.x;
    const int nl = tid >> 2, c0 = (tid & 3) * 16;
    unsigned short vb[16];
    int n = n0 + nl;
    if (n < NN) {
        const float* src = x + (size_t)n * DD + i0 + c0;
#pragma unroll
        for (int q = 0; q < 16; q += 4) {
            float4 v = *(const float4*)(src + q);
            vb[q] = f2bf(v.x); vb[q + 1] = f2bf(v.y);
            vb[q + 2] = f2bf(v.z); vb[q + 3] = f2bf(v.w);
        }
#pragma unroll
        for (int q = 0; q < 16; q += 4)
            *(ushort4*)(xb + (size_t)n * DD + i0 + c0 + q) =
                make_ushort4(vb[q], vb[q + 1], vb[q + 2], vb[q + 3]);
    } else {
#pragma unroll
        for (int q = 0; q < 16; q++) vb[q] = 0;
    }
#pragma unroll
    for (int q = 0; q < 16; q++) t[nl][c0 + q] = vb[q];
    __syncthreads();
    const int il = tid >> 2, nc0 = (tid & 3) * 16;
    unsigned short ob[16];
#pragma unroll
    for (int q = 0; q < 16; q++) ob[q] = t[nc0 + q][il];
#pragma unroll
    for (int q = 0; q < 16; q += 4)
        *(ushort4*)(xT + (size_t)(i0 + il) * NPAD + n0 + nc0 + q) =
            make_ushort4(ob[q], ob[q + 1], ob[q + 2], ob[q + 3]);
}

// ---------------------------------------------------------------------------
// Degree counts; nr via LDS block counters.
__global__ __launch_bounds__(256) void count_kernel(
    const int* __restrict__ erow, const int* __restrict__ ecol,
    const int* __restrict__ etype, int* __restrict__ c_in,
    int* __restrict__ c_out, int* __restrict__ nr)
{
    __shared__ int lnr[RR];
    if (threadIdx.x < RR) lnr[threadIdx.x] = 0;
    __syncthreads();
    int g = blockIdx.x * blockDim.x + threadIdx.x;
    int stride = gridDim.x * blockDim.x;
    for (int e = g; e < EE; e += stride) {
        int t = etype[e];
        atomicAdd(&c_out[t * NN + erow[e]], 1);
        atomicAdd(&c_in[t * NN + ecol[e]], 1);
        atomicAdd(&lnr[t], 1);
    }
    __syncthreads();
    if (threadIdx.x < RR) atomicAdd(&nr[threadIdx.x], lnr[threadIdx.x]);
}

// ---------------------------------------------------------------------------
// Multi-block scan, phase 1: per-block (1024 elems) reduce -> bsum[b]
__global__ __launch_bounds__(256) void scan_reduce(
    const int* __restrict__ cnt, int* __restrict__ bsum)
{
    __shared__ int ws[4];
    const int b = blockIdx.x, tid = threadIdx.x;
    const int i = b * SCB + tid * 4;
    int s = 0;
    if (i < SCT) {
        int4 v = *(const int4*)(cnt + i);
        s = v.x + v.y + v.z + v.w;
    }
#pragma unroll
    for (int off = 32; off; off >>= 1) s += __shfl_down(s, off, 64);
    if ((tid & 63) == 0) ws[tid >> 6] = s;
    __syncthreads();
    if (tid == 0) bsum[b] = ws[0] + ws[1] + ws[2] + ws[3];
}

// Phase 2: one block scans the SNB block sums -> boff (exclusive), off[SCT]=total
__global__ __launch_bounds__(256) void scan_top(
    const int* __restrict__ bsum, int* __restrict__ boff, int* __restrict__ offT)
{
    __shared__ int bs[256];
    const int tid = threadIdx.x;
    int v = tid < SNB ? bsum[tid] : 0;
    bs[tid] = v;
    __syncthreads();
    for (int d = 1; d < 256; d <<= 1) {
        int t = (tid >= d) ? bs[tid - d] : 0;
        __syncthreads();
        bs[tid] += t;
        __syncthreads();
    }
    if (tid < SNB) boff[tid] = tid ? bs[tid - 1] : 0;
    if (tid == 255) *offT = bs[255];
}

// Phase 3: per-block local scan + block offset -> off, cur
__global__ __launch_bounds__(256) void scan_bot(
    const int* __restrict__ cnt, const int* __restrict__ boff,
    int* __restrict__ off, int* __restrict__ cur)
{
    __shared__ int bs[256];
    const int b = blockIdx.x, tid = threadIdx.x;
    const int i = b * SCB + tid * 4;
    int4 v = make_int4(0, 0, 0, 0);
    if (i < SCT) v = *(const int4*)(cnt + i);
    int s = v.x + v.y + v.z + v.w;
    bs[tid] = s;
    __syncthreads();
    for (int d = 1; d < 256; d <<= 1) {
        int t = (tid >= d) ? bs[tid - d] : 0;
        __syncthreads();
        bs[tid] += t;
        __syncthreads();
    }
    if (i < SCT) {
        int pre = boff[b] + (tid ? bs[tid - 1] : 0);
        int4 o;
        o.x = pre;
        o.y = pre + v.x;
        o.z = pre + v.x + v.y;
        o.w = pre + v.x + v.y + v.z;
        *(int4*)(off + i) = o;
        *(int4*)(cur + i) = o;
    }
}

// Bucket-fill: sorted_col grouped by key (t*NN+row).
__global__ __launch_bounds__(256) void fill_kernel(
    const int* __restrict__ erow, const int* __restrict__ ecol,
    const int* __restrict__ etype, int* __restrict__ cur,
    int* __restrict__ scol)
{
    int e = blockIdx.x * 256 + threadIdx.x;
    if (e < EE) {
        int key = etype[e] * NN + erow[e];
        int p = atomicAdd(&cur[key], 1);
        scol[p] = ecol[e];
    }
}

// One wave per node: Acat[n][t*256+:] = s(t,n) * sum_{e in seg(t,n)} x[col]
__global__ __launch_bounds__(256) void gather_kernel(
    const unsigned short* __restrict__ xb, const int* __restrict__ scol,
    const int* __restrict__ off, const float* __restrict__ qs,
    const int* __restrict__ nr, unsigned short* __restrict__ Acat)
{
    const int wid = threadIdx.x >> 6, lane = threadIdx.x & 63;
    const int n = blockIdx.x * 4 + wid;
    if (n >= NN) return;
#pragma unroll
    for (int t = 0; t < RR; t++) {
        float acc[4] = {0.f, 0.f, 0.f, 0.f};
        int b0 = off[t * NN + n], b1 = off[t * NN + n + 1];
        for (int i = b0; i < b1; i++) {
            int col = scol[i];
            ushort4 v = *(const ushort4*)(xb + (size_t)col * DD + lane * 4);
            acc[0] += bf2f(v.x); acc[1] += bf2f(v.y);
            acc[2] += bf2f(v.z); acc[3] += bf2f(v.w);
        }
        float nrf = (float)nr[t];
        float s = nrf / (qs[(size_t)t * NN + n] + nrf);
        ushort4 o;
        o.x = f2bf(s * acc[0]); o.y = f2bf(s * acc[1]);
        o.z = f2bf(s * acc[2]); o.w = f2bf(s * acc[3]);
        *(ushort4*)(Acat + (size_t)n * 768 + t * 256 + lane * 4) = o;
    }
}

// c_in -> bf16 weight arrays wbf[3][NPAD] (pad zeros)
__global__ __launch_bounds__(256) void wbf_kernel(
    const int* __restrict__ c_in, unsigned short* __restrict__ wbf)
{
    int t = blockIdx.x * 256 + threadIdx.x;
    if (t < 3 * NPAD) {
        int r = t / NPAD, n = t % NPAD;
        wbf[t] = f2bf(n < NN ? (float)c_in[r * NN + n] : 0.f);
    }
}

// xw[r][i] = sum_n c_in[r][n] * x[n][i]
__global__ __launch_bounds__(256) void xw_kernel(
    const unsigned short* __restrict__ xb, const int* __restrict__ c_in,
    float* __restrict__ xw)
{
    __shared__ float xws[768];
    const int tid = threadIdx.x;
    for (int k = tid; k < 768; k += 256) xws[k] = 0.f;
    __syncthreads();
    const int wid = tid >> 6, lane = tid & 63;
    const int gw = blockIdx.x * 4 + wid;
    float acc[3][4] = {};
    for (int n = gw; n < NN; n += 256) {
        ushort4 xv = *(const ushort4*)(xb + (size_t)n * DD + lane * 4);
        float xf[4] = {bf2f(xv.x), bf2f(xv.y), bf2f(xv.z), bf2f(xv.w)};
        float w0 = (float)c_in[n], w1 = (float)c_in[NN + n], w2 = (float)c_in[2 * NN + n];
#pragma unroll
        for (int c = 0; c < 4; c++) {
            acc[0][c] += w0 * xf[c];
            acc[1][c] += w1 * xf[c];
            acc[2][c] += w2 * xf[c];
        }
    }
#pragma unroll
    for (int r = 0; r < 3; r++)
#pragma unroll
        for (int c = 0; c < 4; c++)
            atomicAdd(&xws[r * 256 + lane * 4 + c], acc[r][c]);
    __syncthreads();
    for (int k = tid; k < 768; k += 256) atomicAdd(&xw[k], xws[k]);
}

// ---------------------------------------------------------------------------
// G partials: Gp[z][tile][r][128*128] += xT(w-scaled) @ xT^T over node chunk z
__global__ __launch_bounds__(512) void g_kernel(
    const unsigned short* __restrict__ xT, const unsigned short* __restrict__ wbf,
    float* __restrict__ Gp)
{
    __shared__ __align__(16) char ldsA[16384];
    __shared__ __align__(16) char ldsB[16384];
    const int tid = threadIdx.x, lane = tid & 63, wid = tid >> 6;
    const int wr = wid >> 1, wc = wid & 1;
    const int i0 = blockIdx.x * 128, j0 = blockIdx.y * 128;
    const int TPZ = (NPAD / 64 + GS - 1) / GS;
    const int kt0 = blockIdx.z * TPZ;
    const int kt1 = min(NPAD / 64, kt0 + TPZ);

    f32x4 acc[3][2][4];
#pragma unroll
    for (int r = 0; r < 3; r++)
#pragma unroll
        for (int m = 0; m < 2; m++)
#pragma unroll
            for (int n = 0; n < 4; n++) acc[r][m][n] = (f32x4){0.f, 0.f, 0.f, 0.f};

    for (int kt = kt0; kt < kt1; kt++) {
        const int kbyte = kt * 128;
#pragma unroll
        for (int is = 0; is < 2; is++) {
            int lb = is * 8192 + wid * 1024;
            int d = lb + lane * 16;
            int row = d >> 7;
            int sc_ = (d & 127) ^ ((row & 7) << 4);
            gload_lds16((const char*)xT + (size_t)(i0 + row) * (NPAD * 2) + kbyte + sc_, ldsA + lb);
            gload_lds16((const char*)xT + (size_t)(j0 + row) * (NPAD * 2) + kbyte + sc_, ldsB + lb);
        }
        __syncthreads();
#pragma unroll
        for (int kk = 0; kk < 2; kk++) {
            const int cb = kk * 64 + ((lane >> 4) << 4);
            bf16x8 bfr[4];
#pragma unroll
            for (int n = 0; n < 4; n++) {
                int rn = wc * 64 + n * 16 + (lane & 15);
                bfr[n] = *(const bf16x8*)(ldsB + rn * 128 + (cb ^ ((rn & 7) << 4)));
            }
            float au[2][8];
#pragma unroll
            for (int m = 0; m < 2; m++) {
                int row = wr * 32 + m * 16 + (lane & 15);
                bf16x8 ar = *(const bf16x8*)(ldsA + row * 128 + (cb ^ ((row & 7) << 4)));
#pragma unroll
                for (int q = 0; q < 8; q++) au[m][q] = bf2f((unsigned short)ar[q]);
            }
            const int nb = kt * 64 + kk * 32 + ((lane >> 4) << 3);
#pragma unroll
            for (int r = 0; r < 3; r++) {
                bf16x8 wv = *(const bf16x8*)(wbf + (size_t)r * NPAD + nb);
                float wf[8];
#pragma unroll
                for (int q = 0; q < 8; q++) wf[q] = bf2f((unsigned short)wv[q]);
                bf16x8 am[2];
#pragma unroll
                for (int m = 0; m < 2; m++)
#pragma unroll
                    for (int q = 0; q < 8; q++)
                        am[m][q] = (short)f2bf(au[m][q] * wf[q]);
#pragma unroll
                for (int m = 0; m < 2; m++)
#pragma unroll
                    for (int n = 0; n < 4; n++)
                        acc[r][m][n] = __builtin_amdgcn_mfma_f32_16x16x32_bf16(
                            am[m], bfr[n], acc[r][m][n], 0, 0, 0);
            }
        }
        __syncthreads();
    }
    float* base = Gp + ((size_t)blockIdx.z * 4 + blockIdx.x * 2 + blockIdx.y) * 3 * 16384;
#pragma unroll
    for (int r = 0; r < 3; r++)
#pragma unroll
        for (int m = 0; m < 2; m++)
#pragma unroll
            for (int n = 0; n < 4; n++) {
                int col = wc * 64 + n * 16 + (lane & 15);
                int rw0 = wr * 32 + m * 16 + ((lane >> 4) << 2);
#pragma unroll
                for (int reg = 0; reg < 4; reg++)
                    base[r * 16384 + (rw0 + reg) * 128 + col] = acc[r][m][n][reg];
            }
}

// Reduce Gp over z, emit Gb (bf16 [3][256][256])
__global__ __launch_bounds__(256) void greduce_kernel(
    const float* __restrict__ Gp, unsigned short* __restrict__ Gb)
{
    int gid = blockIdx.x * 256 + threadIdx.x;
    int t = gid >> 14, rem = gid & 16383;
    int r = t % 3, tile = t / 3;
    float s = 0.f;
    for (int z = 0; z < GS; z++)
        s += Gp[(size_t)z * 196608 + ((size_t)tile * 3 + r) * 16384 + rem];
    int i = (tile >> 1) * 128 + (rem >> 7);
    int j = (tile & 1) * 128 + (rem & 127);
    Gb[(size_t)r * 65536 + i * 256 + j] = f2bf(s);
}

// y[r][row] = dot(Mat[r] row (bf16,256), v[r] (f32,256))
__global__ __launch_bounds__(256) void matvec_bf(
    const unsigned short* __restrict__ Mat, const float* __restrict__ v,
    float* __restrict__ y)
{
    __shared__ float vs[256];
    const int b = blockIdx.x;
    const int r = b >> 6, rb = (b & 63) * 4;
    const int tid = threadIdx.x;
    vs[tid] = v[r * 256 + tid];
    __syncthreads();
    const int wid = tid >> 6, lane = tid & 63;
    const int row = rb + wid;
    ushort4 m4 = *(const ushort4*)(Mat + (size_t)r * 65536 + row * 256 + lane * 4);
    float s = bf2f(m4.x) * vs[lane * 4] + bf2f(m4.y) * vs[lane * 4 + 1] +
              bf2f(m4.z) * vs[lane * 4 + 2] + bf2f(m4.w) * vs[lane * 4 + 3];
#pragma unroll
    for (int off = 32; off; off >>= 1) s += __shfl_down(s, off, 64);
    if (lane == 0) y[r * 256 + row] = s;
}

// qs[r][n] = x[n] . t[r]
__global__ __launch_bounds__(256) void qs_kernel(
    const unsigned short* __restrict__ xb, const float* __restrict__ tv,
    float* __restrict__ qs)
{
    __shared__ float ts[768];
    const int tid = threadIdx.x;
    for (int k = tid; k < 768; k += 256) ts[k] = tv[k];
    __syncthreads();
    const int wid = tid >> 6, lane = tid & 63;
    const int n = blockIdx.x * 4 + wid;
    if (n < NN) {
        ushort4 xv = *(const ushort4*)(xb + (size_t)n * DD + lane * 4);
        float xf[4] = {bf2f(xv.x), bf2f(xv.y), bf2f(xv.z), bf2f(xv.w)};
        float s0 = 0, s1 = 0, s2 = 0;
#pragma unroll
        for (int c = 0; c < 4; c++) {
            s0 += xf[c] * ts[lane * 4 + c];
            s1 += xf[c] * ts[256 + lane * 4 + c];
            s2 += xf[c] * ts[512 + lane * 4 + c];
        }
#pragma unroll
        for (int off = 32; off; off >>= 1) {
            s0 += __shfl_down(s0, off, 64);
            s1 += __shfl_down(s1, off, 64);
            s2 += __shfl_down(s2, off, 64);
        }
        if (lane == 0) { qs[n] = s0; qs[NN + n] = s1; qs[2 * NN + n] = s2; }
    }
}

// ---------------------------------------------------------------------------
// MFMA NT GEMM: C[M,N=256] = A[M,KK] @ B[256,KK]^T (bf16 in, fp32 acc)
// MODE 0: bf16 store; MODE 1: fp32 store; MODE 2: C += cnt[row]/(qs[row]+Nr)*acc
// MODE 3: C += acc (fp32)
template <int MODE>
__global__ __launch_bounds__(256) void gemm_nt(
    const unsigned short* __restrict__ A, int lda,
    const unsigned short* __restrict__ B, int ldb,
    void* __restrict__ Cv, int ldc, int M, int KK,
    size_t sa, size_t sb, size_t sc,
    const float* __restrict__ qs, const int* __restrict__ cnt,
    const int* __restrict__ nrp)
{
    A += (size_t)blockIdx.z * sa;
    B += (size_t)blockIdx.z * sb;
    __shared__ __align__(16) char ldsA[16384];
    __shared__ __align__(16) char ldsB[16384];
    const int tid = threadIdx.x, lane = tid & 63, wid = tid >> 6;
    const int wr = wid >> 1, wc = wid & 1;
    const int row0 = blockIdx.x * 128, col0 = blockIdx.y * 128;

    f32x4 acc[4][4];
#pragma unroll
    for (int m = 0; m < 4; m++)
#pragma unroll
        for (int n = 0; n < 4; n++) acc[m][n] = (f32x4){0.f, 0.f, 0.f, 0.f};

    for (int k0 = 0; k0 < KK; k0 += 64) {
#pragma unroll
        for (int is = 0; is < 4; is++) {
            int lb = is * 4096 + wid * 1024;
            int d = lb + lane * 16;
            int row = d >> 7;
            int sc_ = (d & 127) ^ ((row & 7) << 4);
            int gr = row0 + row; gr = gr < M ? gr : M - 1;
            gload_lds16((const char*)(A + (size_t)gr * lda + k0) + sc_, ldsA + lb);
            int rn = col0 + row;
            gload_lds16((const char*)(B + (size_t)rn * ldb + k0) + sc_, ldsB + lb);
        }
        __syncthreads();
#pragma unroll
        for (int kk = 0; kk < 2; kk++) {
            bf16x8 af[4], bf_[4];
            const int cb = kk * 64 + ((lane >> 4) << 4);
#pragma unroll
            for (int m = 0; m < 4; m++) {
                int row = wr * 64 + m * 16 + (lane & 15);
                af[m] = *(const bf16x8*)(ldsA + row * 128 + (cb ^ ((row & 7) << 4)));
                int rn = wc * 64 + m * 16 + (lane & 15);
                bf_[m] = *(const bf16x8*)(ldsB + rn * 128 + (cb ^ ((rn & 7) << 4)));
            }
#pragma unroll
            for (int m = 0; m < 4; m++)
#pragma unroll
                for (int n = 0; n < 4; n++)
                    acc[m][n] = __builtin_amdgcn_mfma_f32_16x16x32_bf16(
                        af[m], bf_[n], acc[m][n], 0, 0, 0);
        }
        __syncthreads();
    }

    float nrf = 0.f;
    if (MODE == 2) nrf = (float)nrp[0];
#pragma unroll
    for (int m = 0; m < 4; m++) {
#pragma unroll
        for (int reg = 0; reg < 4; reg++) {
            int r = row0 + wr * 64 + m * 16 + ((lane >> 4) << 2) + reg;
            if (r >= M) continue;
            float s = 0.f;
            if (MODE == 2) {
                int c = cnt[r];
                s = c ? (float)c / (qs[r] + nrf) : 0.f;
            }
#pragma unroll
            for (int n = 0; n < 4; n++) {
                int c = col0 + wc * 64 + n * 16 + (lane & 15);
                float v = acc[m][n][reg];
                if (MODE == 0)
                    ((unsigned short*)Cv)[(size_t)blockIdx.z * sc + (size_t)r * ldc + c] = f2bf(v);
                else if (MODE == 1)
                    ((float*)Cv)[(size_t)blockIdx.z * sc + (size_t)r * ldc + c] = v;
                else if (MODE == 2)
                    ((float*)Cv)[(size_t)r * ldc + c] += s * v;
                else
                    ((float*)Cv)[(size_t)r * ldc + c] += v;
            }
        }
    }
}

// ---------------------------------------------------------------------------
extern "C" void kernel_launch(void* const* d_in, const int* in_sizes, int n_in,
                              void* d_out, int out_size, void* d_ws, size_t ws_size,
                              hipStream_t stream)
{
    const float* x   = (const float*)d_in[0];
    const float* Wq  = (const float*)d_in[1];
    const float* Wk  = (const float*)d_in[2];
    const float* Wv  = (const float*)d_in[3];
    const float* Whp = (const float*)d_in[4];
    const int* eidx  = (const int*)d_in[5];
    const int* etyp  = (const int*)d_in[6];
    const int* erow = eidx;
    const int* ecol = eidx + EE;
    float* out = (float*)d_out;

    char* p = (char*)d_ws;
    unsigned short* xb    = (unsigned short*)p; p += (size_t)NN * DD * 2;        // 25.6 MB
    unsigned short* xT    = (unsigned short*)p; p += (size_t)DD * NPAD * 2;      // 25.6 MB
    char*           regB  = p;                  p += (size_t)NN * 768 * 2;       // 76.8 MB (Gp then Acat)
    float*          x_out = (float*)p;          p += (size_t)NN * DD * 4;        // 51.2 MB
    unsigned short* Gb    = (unsigned short*)p; p += (size_t)RR * 65536 * 2;
    unsigned short* U1    = (unsigned short*)p; p += (size_t)RR * 65536 * 2;
    unsigned short* U2    = (unsigned short*)p; p += (size_t)RR * 65536 * 2;
    unsigned short* U3    = (unsigned short*)p; p += (size_t)RR * 65536 * 2;
    unsigned short* WvTcat= (unsigned short*)p; p += (size_t)256 * 768 * 2;
    unsigned short* WkT   = (unsigned short*)p; p += (size_t)RR * 65536 * 2;
    unsigned short* Wqb   = (unsigned short*)p; p += (size_t)RR * 65536 * 2;
    unsigned short* WhpT  = (unsigned short*)p; p += 65536 * 2;
    unsigned short* wbf   = (unsigned short*)p; p += (size_t)RR * NPAD * 2;
    float*          qs    = (float*)p;          p += (size_t)RR * NN * 4;
    float*          xw    = (float*)p;          p += 768 * 4;
    float*          ks    = (float*)p;          p += 768 * 4;
    float*          tv    = (float*)p;          p += 768 * 4;
    int*            c_in  = (int*)p;            p += (size_t)RR * NN * 4;
    int*            c_out = (int*)p;            p += (size_t)RR * NN * 4;
    int*            off   = (int*)p;            p += (size_t)(RR * NN + 1) * 4;
    int*            cur   = (int*)p;            p += (size_t)RR * NN * 4;
    int*            scol  = (int*)p;            p += (size_t)EE * 4;
    int*            nr    = (int*)p;            p += RR * 4;
    int*            bsum  = (int*)p;            p += SNB * 4;
    int*            boff  = (int*)p;            p += SNB * 4;
    float*          Gp    = (float*)regB;       // 50.3 MB, dead before Acat written
    unsigned short* Acat  = (unsigned short*)regB;
    unsigned short* xob   = xT;                 // xT dead after g_kernel

    prep_w<<<2560, 256, 0, stream>>>(Wq, Wk, Wv, Whp, WvTcat, WkT, Wqb, WhpT);
    transpose_conv<<<dim3(NPAD / 64, 4), 256, 0, stream>>>(x, xb, xT);
    hipMemsetAsync(x_out, 0, (size_t)NN * DD * sizeof(float), stream);
    hipMemsetAsync(c_in, 0, (size_t)(6 * NN) * sizeof(int), stream);
    hipMemsetAsync(nr, 0, RR * sizeof(int), stream);
    hipMemsetAsync(xw, 0, 768 * sizeof(float), stream);
    count_kernel<<<512, 256, 0, stream>>>(erow, ecol, etyp, c_in, c_out, nr);
    scan_reduce<<<SNB, 256, 0, stream>>>(c_out, bsum);
    scan_top<<<1, 256, 0, stream>>>(bsum, boff, off + SCT);
    scan_bot<<<SNB, 256, 0, stream>>>(c_out, boff, off, cur);
    fill_kernel<<<(EE + 255) / 256, 256, 0, stream>>>(erow, ecol, etyp, cur, scol);
    wbf_kernel<<<(3 * NPAD + 255) / 256, 256, 0, stream>>>(c_in, wbf);
    xw_kernel<<<64, 256, 0, stream>>>(xb, c_in, xw);

    g_kernel<<<dim3(2, 2, GS), 512, 0, stream>>>(xT, wbf, Gp);
    greduce_kernel<<<12 * 64, 256, 0, stream>>>(Gp, Gb);

    // kvs^T = Wv^T G Wk ; num B-operand U3 = kvs^T Wq^T   (batched over r)
    gemm_nt<0><<<dim3(2, 2, 3), 256, 0, stream>>>(WvTcat, 768, Gb, 256, U1, 256, 256, 256,
                                                  256, 65536, 65536, nullptr, nullptr, nullptr);
    gemm_nt<0><<<dim3(2, 2, 3), 256, 0, stream>>>(U1, 256, WkT, 256, U2, 256, 256, 256,
                                                  65536, 65536, 65536, nullptr, nullptr, nullptr);
    gemm_nt<0><<<dim3(2, 2, 3), 256, 0, stream>>>(U2, 256, Wqb, 256, U3, 256, 256, 256,
                                                  65536, 65536, 65536, nullptr, nullptr, nullptr);
    matvec_bf<<<192, 256, 0, stream>>>(WkT, xw, ks);   // ks = Wk^T (x^T w)
    matvec_bf<<<192, 256, 0, stream>>>(Wqb, ks, tv);   // t  = Wq ks
    qs_kernel<<<(NN + 3) / 4, 256, 0, stream>>>(xb, tv, qs);

    // Acat[n] = [s(0,n)*sum x, s(1,n)*sum x, s(2,n)*sum x]  (bf16, K-cat)
    gather_kernel<<<(NN + 3) / 4, 256, 0, stream>>>(xb, scol, off, qs, nr, Acat);

    const int MB = (NN + 127) / 128;  // 391
    for (int r = 0; r < RR; r++)
        gemm_nt<2><<<dim3(MB, 2), 256, 0, stream>>>(xb, 256, U3 + (size_t)r * 65536, 256,
                                                    x_out, 256, NN, 256, 0, 0, 0,
                                                    qs + (size_t)r * NN, c_out + (size_t)r * NN, nr + r);
    gemm_nt<3><<<dim3(MB, 2), 256, 0, stream>>>(Acat, 768, WvTcat, 768, x_out, 256, NN, 768,
                                                0, 0, 0, nullptr, nullptr, nullptr);

    conv_bf16<<<(NN * DD / 4 + 255) / 256, 256, 0, stream>>>(x_out, xob, NN * DD / 4);
    gemm_nt<1><<<dim3(MB, 2), 256, 0, stream>>>(xob, 256, WhpT, 256, out, 256, NN, 256,
                                                0, 0, 0, nullptr, nullptr, nullptr);
}

// Round 7
// 341.141 us; speedup vs baseline: 13.3737x; 1.5373x over previous
//
#include <hip/hip_runtime.h>

#define NN 50000
#define EE 300000
#define DD 256
#define RR 3
#define NPAD 50048            // 782 * 64
#define GS 64                 // split-K slices for G
#define SCT (RR * NN)         // 150000
#define SCB 1024
#define SNB ((SCT + SCB - 1) / SCB)  // 147

using bf16x8 = __attribute__((ext_vector_type(8))) short;
using f32x4  = __attribute__((ext_vector_type(4))) float;

__device__ __forceinline__ float bf2f(unsigned short u) {
    return __uint_as_float(((unsigned)u) << 16);
}
__device__ __forceinline__ unsigned short f2bf(float f) {
    unsigned u = __float_as_uint(f);
    return (unsigned short)((u + 0x7fffu + ((u >> 16) & 1u)) >> 16);
}
__device__ __forceinline__ void gload_lds16(const void* g, void* l) {
    __builtin_amdgcn_global_load_lds(
        (const __attribute__((address_space(1))) unsigned int*)g,
        (__attribute__((address_space(3))) unsigned int*)l, 16, 0, 0);
}

// ---------------------------------------------------------------------------
// Weight prep: WvTcat[j][r*256+k]=Wv[r][k][j]; WkT[r][m][l]=Wk[r][l][m];
// Wqb = Wq (bf16 copy); WhpT[n][k]=Whp[k][n];
// BfullT rows 768+r*256+k = plain Wv_r row k (bf16).
__global__ __launch_bounds__(256) void prep_w(
    const float* __restrict__ Wq, const float* __restrict__ Wk,
    const float* __restrict__ Wv, const float* __restrict__ Whp,
    unsigned short* __restrict__ WvTcat, unsigned short* __restrict__ WkT,
    unsigned short* __restrict__ Wqb, unsigned short* __restrict__ WhpT,
    unsigned short* __restrict__ BfullT)
{
    int t = blockIdx.x * 256 + threadIdx.x;
    int slot = t >> 16, o = t & 65535;
    int a = o >> 8, b = o & 255;
    if (slot < 9) {
        int r = slot / 3, kind = slot % 3;
        if (kind == 0)      WvTcat[(size_t)a * 768 + r * 256 + b] = f2bf(Wv[(size_t)r * 65536 + b * 256 + a]);
        else if (kind == 1) WkT[(size_t)r * 65536 + o] = f2bf(Wk[(size_t)r * 65536 + b * 256 + a]);
        else                Wqb[(size_t)r * 65536 + o] = f2bf(Wq[(size_t)r * 65536 + a * 256 + b]);
    } else if (slot == 9) {
        WhpT[o] = f2bf(Whp[b * 256 + a]);
    } else if (slot < 13) {
        int r = slot - 10;
        BfullT[(size_t)768 * 256 + (size_t)r * 65536 + o] = f2bf(Wv[(size_t)r * 65536 + o]);
    }
}

// ---------------------------------------------------------------------------
// x (fp32) -> xb (bf16 row-major) + xT (bf16 transposed [256][NPAD], zero-pad)
__global__ __launch_bounds__(256) void transpose_conv(
    const float* __restrict__ x, unsigned short* __restrict__ xb,
    unsigned short* __restrict__ xT)
{
    __shared__ unsigned short t[64][66];
    const int n0 = blockIdx.x * 64, i0 = blockIdx.y * 64;
    const int tid = threadIdx.x;
    const int nl = tid >> 2, c0 = (tid & 3) * 16;
    unsigned short vb[16];
    int n = n0 + nl;
    if (n < NN) {
        const float* src = x + (size_t)n * DD + i0 + c0;
#pragma unroll
        for (int q = 0; q < 16; q += 4) {
            float4 v = *(const float4*)(src + q);
            vb[q] = f2bf(v.x); vb[q + 1] = f2bf(v.y);
            vb[q + 2] = f2bf(v.z); vb[q + 3] = f2bf(v.w);
        }
#pragma unroll
        for (int q = 0; q < 16; q += 4)
            *(ushort4*)(xb + (size_t)n * DD + i0 + c0 + q) =
                make_ushort4(vb[q], vb[q + 1], vb[q + 2], vb[q + 3]);
    } else {
#pragma unroll
        for (int q = 0; q < 16; q++) vb[q] = 0;
    }
#pragma unroll
    for (int q = 0; q < 16; q++) t[nl][c0 + q] = vb[q];
    __syncthreads();
    const int il = tid >> 2, nc0 = (tid & 3) * 16;
    unsigned short ob[16];
#pragma unroll
    for (int q = 0; q < 16; q++) ob[q] = t[nc0 + q][il];
#pragma unroll
    for (int q = 0; q < 16; q += 4)
        *(ushort4*)(xT + (size_t)(i0 + il) * NPAD + n0 + nc0 + q) =
            make_ushort4(ob[q], ob[q + 1], ob[q + 2], ob[q + 3]);
}

// ---------------------------------------------------------------------------
// Degree counts; nr via LDS block counters.
__global__ __launch_bounds__(256) void count_kernel(
    const int* __restrict__ erow, const int* __restrict__ ecol,
    const int* __restrict__ etype, int* __restrict__ c_in,
    int* __restrict__ c_out, int* __restrict__ nr)
{
    __shared__ int lnr[RR];
    if (threadIdx.x < RR) lnr[threadIdx.x] = 0;
    __syncthreads();
    int g = blockIdx.x * blockDim.x + threadIdx.x;
    int stride = gridDim.x * blockDim.x;
    for (int e = g; e < EE; e += stride) {
        int t = etype[e];
        atomicAdd(&c_out[t * NN + erow[e]], 1);
        atomicAdd(&c_in[t * NN + ecol[e]], 1);
        atomicAdd(&lnr[t], 1);
    }
    __syncthreads();
    if (threadIdx.x < RR) atomicAdd(&nr[threadIdx.x], lnr[threadIdx.x]);
}

// ---------------------------------------------------------------------------
// Multi-block scan
__global__ __launch_bounds__(256) void scan_reduce(
    const int* __restrict__ cnt, int* __restrict__ bsum)
{
    __shared__ int ws[4];
    const int b = blockIdx.x, tid = threadIdx.x;
    const int i = b * SCB + tid * 4;
    int s = 0;
    if (i < SCT) {
        int4 v = *(const int4*)(cnt + i);
        s = v.x + v.y + v.z + v.w;
    }
#pragma unroll
    for (int off = 32; off; off >>= 1) s += __shfl_down(s, off, 64);
    if ((tid & 63) == 0) ws[tid >> 6] = s;
    __syncthreads();
    if (tid == 0) bsum[b] = ws[0] + ws[1] + ws[2] + ws[3];
}

__global__ __launch_bounds__(256) void scan_top(
    const int* __restrict__ bsum, int* __restrict__ boff, int* __restrict__ offT)
{
    __shared__ int bs[256];
    const int tid = threadIdx.x;
    int v = tid < SNB ? bsum[tid] : 0;
    bs[tid] = v;
    __syncthreads();
    for (int d = 1; d < 256; d <<= 1) {
        int t = (tid >= d) ? bs[tid - d] : 0;
        __syncthreads();
        bs[tid] += t;
        __syncthreads();
    }
    if (tid < SNB) boff[tid] = tid ? bs[tid - 1] : 0;
    if (tid == 255) *offT = bs[255];
}

__global__ __launch_bounds__(256) void scan_bot(
    const int* __restrict__ cnt, const int* __restrict__ boff,
    int* __restrict__ off, int* __restrict__ cur)
{
    __shared__ int bs[256];
    const int b = blockIdx.x, tid = threadIdx.x;
    const int i = b * SCB + tid * 4;
    int4 v = make_int4(0, 0, 0, 0);
    if (i < SCT) v = *(const int4*)(cnt + i);
    int s = v.x + v.y + v.z + v.w;
    bs[tid] = s;
    __syncthreads();
    for (int d = 1; d < 256; d <<= 1) {
        int t = (tid >= d) ? bs[tid - d] : 0;
        __syncthreads();
        bs[tid] += t;
        __syncthreads();
    }
    if (i < SCT) {
        int pre = boff[b] + (tid ? bs[tid - 1] : 0);
        int4 o;
        o.x = pre;
        o.y = pre + v.x;
        o.z = pre + v.x + v.y;
        o.w = pre + v.x + v.y + v.z;
        *(int4*)(off + i) = o;
        *(int4*)(cur + i) = o;
    }
}

// Bucket-fill: sorted_col grouped by key (t*NN+row).
__global__ __launch_bounds__(256) void fill_kernel(
    const int* __restrict__ erow, const int* __restrict__ ecol,
    const int* __restrict__ etype, int* __restrict__ cur,
    int* __restrict__ scol)
{
    int e = blockIdx.x * 256 + threadIdx.x;
    if (e < EE) {
        int key = etype[e] * NN + erow[e];
        int p = atomicAdd(&cur[key], 1);
        scol[p] = ecol[e];
    }
}

// One wave per node: Afull[n][t*256+:]   = s2(t,n) * x[n]           (num term)
//                    Afull[n][768+t*256+:] = s1(t,n) * sum x[col]   (scatter term)
__global__ __launch_bounds__(256) void gather_kernel(
    const unsigned short* __restrict__ xb, const int* __restrict__ scol,
    const int* __restrict__ off, const float* __restrict__ qs,
    const int* __restrict__ c_out, const int* __restrict__ nr,
    unsigned short* __restrict__ Afull)
{
    const int wid = threadIdx.x >> 6, lane = threadIdx.x & 63;
    const int n = blockIdx.x * 4 + wid;
    if (n >= NN) return;
    ushort4 xv = *(const ushort4*)(xb + (size_t)n * DD + lane * 4);
    float xf[4] = {bf2f(xv.x), bf2f(xv.y), bf2f(xv.z), bf2f(xv.w)};
#pragma unroll
    for (int t = 0; t < RR; t++) {
        float nrf = (float)nr[t];
        float denom = qs[(size_t)t * NN + n] + nrf;
        int cnt = c_out[t * NN + n];
        float s2 = cnt ? (float)cnt / denom : 0.f;
        ushort4 o1;
        o1.x = f2bf(s2 * xf[0]); o1.y = f2bf(s2 * xf[1]);
        o1.z = f2bf(s2 * xf[2]); o1.w = f2bf(s2 * xf[3]);
        *(ushort4*)(Afull + (size_t)n * 1536 + t * 256 + lane * 4) = o1;

        float acc[4] = {0.f, 0.f, 0.f, 0.f};
        int b0 = off[t * NN + n], b1 = off[t * NN + n + 1];
        for (int i = b0; i < b1; i++) {
            int col = scol[i];
            ushort4 v = *(const ushort4*)(xb + (size_t)col * DD + lane * 4);
            acc[0] += bf2f(v.x); acc[1] += bf2f(v.y);
            acc[2] += bf2f(v.z); acc[3] += bf2f(v.w);
        }
        float s1 = nrf / denom;
        ushort4 o2;
        o2.x = f2bf(s1 * acc[0]); o2.y = f2bf(s1 * acc[1]);
        o2.z = f2bf(s1 * acc[2]); o2.w = f2bf(s1 * acc[3]);
        *(ushort4*)(Afull + (size_t)n * 1536 + 768 + t * 256 + lane * 4) = o2;
    }
}

// c_in -> bf16 weight arrays wbf[3][NPAD] (pad zeros)
__global__ __launch_bounds__(256) void wbf_kernel(
    const int* __restrict__ c_in, unsigned short* __restrict__ wbf)
{
    int t = blockIdx.x * 256 + threadIdx.x;
    if (t < 3 * NPAD) {
        int r = t / NPAD, n = t % NPAD;
        wbf[t] = f2bf(n < NN ? (float)c_in[r * NN + n] : 0.f);
    }
}

// xw[r][i] = sum_n c_in[r][n] * x[n][i]  — one block per feature i, via xT.
__global__ __launch_bounds__(256) void xw_kernel(
    const unsigned short* __restrict__ xT, const int* __restrict__ c_in,
    float* __restrict__ xw)
{
    __shared__ float red[3][4];
    const int i = blockIdx.x;
    const int tid = threadIdx.x;
    float a0 = 0.f, a1 = 0.f, a2 = 0.f;
    for (int n = tid * 4; n < NN; n += 1024) {
        ushort4 xv = *(const ushort4*)(xT + (size_t)i * NPAD + n);
        int4 w0 = *(const int4*)(c_in + n);
        int4 w1 = *(const int4*)(c_in + NN + n);
        int4 w2 = *(const int4*)(c_in + 2 * NN + n);
        float f0 = bf2f(xv.x), f1 = bf2f(xv.y), f2 = bf2f(xv.z), f3 = bf2f(xv.w);
        a0 += f0 * w0.x + f1 * w0.y + f2 * w0.z + f3 * w0.w;
        a1 += f0 * w1.x + f1 * w1.y + f2 * w1.z + f3 * w1.w;
        a2 += f0 * w2.x + f1 * w2.y + f2 * w2.z + f3 * w2.w;
    }
#pragma unroll
    for (int off = 32; off; off >>= 1) {
        a0 += __shfl_down(a0, off, 64);
        a1 += __shfl_down(a1, off, 64);
        a2 += __shfl_down(a2, off, 64);
    }
    if ((tid & 63) == 0) {
        red[0][tid >> 6] = a0; red[1][tid >> 6] = a1; red[2][tid >> 6] = a2;
    }
    __syncthreads();
    if (tid < 3)
        xw[tid * 256 + i] = red[tid][0] + red[tid][1] + red[tid][2] + red[tid][3];
}

// ---------------------------------------------------------------------------
// G partials: Gp[z][tile][r][128*128] += xT(w-scaled) @ xT^T over node chunk z
__global__ __launch_bounds__(512) void g_kernel(
    const unsigned short* __restrict__ xT, const unsigned short* __restrict__ wbf,
    float* __restrict__ Gp)
{
    __shared__ __align__(16) char ldsA[16384];
    __shared__ __align__(16) char ldsB[16384];
    const int tid = threadIdx.x, lane = tid & 63, wid = tid >> 6;
    const int wr = wid >> 1, wc = wid & 1;
    const int i0 = blockIdx.x * 128, j0 = blockIdx.y * 128;
    const int TPZ = (NPAD / 64 + GS - 1) / GS;
    const int kt0 = blockIdx.z * TPZ;
    const int kt1 = min(NPAD / 64, kt0 + TPZ);

    f32x4 acc[3][2][4];
#pragma unroll
    for (int r = 0; r < 3; r++)
#pragma unroll
        for (int m = 0; m < 2; m++)
#pragma unroll
            for (int n = 0; n < 4; n++) acc[r][m][n] = (f32x4){0.f, 0.f, 0.f, 0.f};

    for (int kt = kt0; kt < kt1; kt++) {
        const int kbyte = kt * 128;
#pragma unroll
        for (int is = 0; is < 2; is++) {
            int lb = is * 8192 + wid * 1024;
            int d = lb + lane * 16;
            int row = d >> 7;
            int sc_ = (d & 127) ^ ((row & 7) << 4);
            gload_lds16((const char*)xT + (size_t)(i0 + row) * (NPAD * 2) + kbyte + sc_, ldsA + lb);
            gload_lds16((const char*)xT + (size_t)(j0 + row) * (NPAD * 2) + kbyte + sc_, ldsB + lb);
        }
        __syncthreads();
#pragma unroll
        for (int kk = 0; kk < 2; kk++) {
            const int cb = kk * 64 + ((lane >> 4) << 4);
            bf16x8 bfr[4];
#pragma unroll
            for (int n = 0; n < 4; n++) {
                int rn = wc * 64 + n * 16 + (lane & 15);
                bfr[n] = *(const bf16x8*)(ldsB + rn * 128 + (cb ^ ((rn & 7) << 4)));
            }
            float au[2][8];
#pragma unroll
            for (int m = 0; m < 2; m++) {
                int row = wr * 32 + m * 16 + (lane & 15);
                bf16x8 ar = *(const bf16x8*)(ldsA + row * 128 + (cb ^ ((row & 7) << 4)));
#pragma unroll
                for (int q = 0; q < 8; q++) au[m][q] = bf2f((unsigned short)ar[q]);
            }
            const int nb = kt * 64 + kk * 32 + ((lane >> 4) << 3);
#pragma unroll
            for (int r = 0; r < 3; r++) {
                bf16x8 wv = *(const bf16x8*)(wbf + (size_t)r * NPAD + nb);
                float wf[8];
#pragma unroll
                for (int q = 0; q < 8; q++) wf[q] = bf2f((unsigned short)wv[q]);
                bf16x8 am[2];
#pragma unroll
                for (int m = 0; m < 2; m++)
#pragma unroll
                    for (int q = 0; q < 8; q++)
                        am[m][q] = (short)f2bf(au[m][q] * wf[q]);
#pragma unroll
                for (int m = 0; m < 2; m++)
#pragma unroll
                    for (int n = 0; n < 4; n++)
                        acc[r][m][n] = __builtin_amdgcn_mfma_f32_16x16x32_bf16(
                            am[m], bfr[n], acc[r][m][n], 0, 0, 0);
            }
        }
        __syncthreads();
    }
    float* base = Gp + ((size_t)blockIdx.z * 4 + blockIdx.x * 2 + blockIdx.y) * 3 * 16384;
#pragma unroll
    for (int r = 0; r < 3; r++)
#pragma unroll
        for (int m = 0; m < 2; m++)
#pragma unroll
            for (int n = 0; n < 4; n++) {
                int col = wc * 64 + n * 16 + (lane & 15);
                int rw0 = wr * 32 + m * 16 + ((lane >> 4) << 2);
#pragma unroll
                for (int reg = 0; reg < 4; reg++)
                    base[r * 16384 + (rw0 + reg) * 128 + col] = acc[r][m][n][reg];
            }
}

// Reduce Gp over z, emit Gb (bf16 [3][256][256])
__global__ __launch_bounds__(256) void greduce_kernel(
    const float* __restrict__ Gp, unsigned short* __restrict__ Gb)
{
    int gid = blockIdx.x * 256 + threadIdx.x;
    int t = gid >> 14, rem = gid & 16383;
    int r = t % 3, tile = t / 3;
    float s = 0.f;
    for (int z = 0; z < GS; z++)
        s += Gp[(size_t)z * 196608 + ((size_t)tile * 3 + r) * 16384 + rem];
    int i = (tile >> 1) * 128 + (rem >> 7);
    int j = (tile & 1) * 128 + (rem & 127);
    Gb[(size_t)r * 65536 + i * 256 + j] = f2bf(s);
}

// y[r][row] = dot(Mat[r] row (bf16,256), v[r] (f32,256))
__global__ __launch_bounds__(256) void matvec_bf(
    const unsigned short* __restrict__ Mat, const float* __restrict__ v,
    float* __restrict__ y)
{
    __shared__ float vs[256];
    const int b = blockIdx.x;
    const int r = b >> 6, rb = (b & 63) * 4;
    const int tid = threadIdx.x;
    vs[tid] = v[r * 256 + tid];
    __syncthreads();
    const int wid = tid >> 6, lane = tid & 63;
    const int row = rb + wid;
    ushort4 m4 = *(const ushort4*)(Mat + (size_t)r * 65536 + row * 256 + lane * 4);
    float s = bf2f(m4.x) * vs[lane * 4] + bf2f(m4.y) * vs[lane * 4 + 1] +
              bf2f(m4.z) * vs[lane * 4 + 2] + bf2f(m4.w) * vs[lane * 4 + 3];
#pragma unroll
    for (int off = 32; off; off >>= 1) s += __shfl_down(s, off, 64);
    if (lane == 0) y[r * 256 + row] = s;
}

// qs[r][n] = x[n] . t[r]
__global__ __launch_bounds__(256) void qs_kernel(
    const unsigned short* __restrict__ xb, const float* __restrict__ tv,
    float* __restrict__ qs)
{
    __shared__ float ts[768];
    const int tid = threadIdx.x;
    for (int k = tid; k < 768; k += 256) ts[k] = tv[k];
    __syncthreads();
    const int wid = tid >> 6, lane = tid & 63;
    const int n = blockIdx.x * 4 + wid;
    if (n < NN) {
        ushort4 xv = *(const ushort4*)(xb + (size_t)n * DD + lane * 4);
        float xf[4] = {bf2f(xv.x), bf2f(xv.y), bf2f(xv.z), bf2f(xv.w)};
        float s0 = 0, s1 = 0, s2 = 0;
#pragma unroll
        for (int c = 0; c < 4; c++) {
            s0 += xf[c] * ts[lane * 4 + c];
            s1 += xf[c] * ts[256 + lane * 4 + c];
            s2 += xf[c] * ts[512 + lane * 4 + c];
        }
#pragma unroll
        for (int off = 32; off; off >>= 1) {
            s0 += __shfl_down(s0, off, 64);
            s1 += __shfl_down(s1, off, 64);
            s2 += __shfl_down(s2, off, 64);
        }
        if (lane == 0) { qs[n] = s0; qs[NN + n] = s1; qs[2 * NN + n] = s2; }
    }
}

// ---------------------------------------------------------------------------
// MFMA NT GEMM: C[M,N] = A[M,KK] @ B[N,KK]^T (bf16 in, fp32 acc)
// MODE 0: bf16 store; MODE 1: fp32 store
template <int MODE>
__global__ __launch_bounds__(256) void gemm_nt(
    const unsigned short* __restrict__ A, int lda,
    const unsigned short* __restrict__ B, int ldb,
    void* __restrict__ Cv, int ldc, int M, int KK,
    size_t sa, size_t sb, size_t sc)
{
    A += (size_t)blockIdx.z * sa;
    B += (size_t)blockIdx.z * sb;
    __shared__ __align__(16) char ldsA[16384];
    __shared__ __align__(16) char ldsB[16384];
    const int tid = threadIdx.x, lane = tid & 63, wid = tid >> 6;
    const int wr = wid >> 1, wc = wid & 1;
    const int row0 = blockIdx.x * 128, col0 = blockIdx.y * 128;

    f32x4 acc[4][4];
#pragma unroll
    for (int m = 0; m < 4; m++)
#pragma unroll
        for (int n = 0; n < 4; n++) acc[m][n] = (f32x4){0.f, 0.f, 0.f, 0.f};

    for (int k0 = 0; k0 < KK; k0 += 64) {
#pragma unroll
        for (int is = 0; is < 4; is++) {
            int lb = is * 4096 + wid * 1024;
            int d = lb + lane * 16;
            int row = d >> 7;
            int sc_ = (d & 127) ^ ((row & 7) << 4);
            int gr = row0 + row; gr = gr < M ? gr : M - 1;
            gload_lds16((const char*)(A + (size_t)gr * lda + k0) + sc_, ldsA + lb);
            int rn = col0 + row;
            gload_lds16((const char*)(B + (size_t)rn * ldb + k0) + sc_, ldsB + lb);
        }
        __syncthreads();
#pragma unroll
        for (int kk = 0; kk < 2; kk++) {
            bf16x8 af[4], bf_[4];
            const int cb = kk * 64 + ((lane >> 4) << 4);
#pragma unroll
            for (int m = 0; m < 4; m++) {
                int row = wr * 64 + m * 16 + (lane & 15);
                af[m] = *(const bf16x8*)(ldsA + row * 128 + (cb ^ ((row & 7) << 4)));
                int rn = wc * 64 + m * 16 + (lane & 15);
                bf_[m] = *(const bf16x8*)(ldsB + rn * 128 + (cb ^ ((rn & 7) << 4)));
            }
#pragma unroll
            for (int m = 0; m < 4; m++)
#pragma unroll
                for (int n = 0; n < 4; n++)
                    acc[m][n] = __builtin_amdgcn_mfma_f32_16x16x32_bf16(
                        af[m], bf_[n], acc[m][n], 0, 0, 0);
        }
        __syncthreads();
    }

#pragma unroll
    for (int m = 0; m < 4; m++) {
#pragma unroll
        for (int reg = 0; reg < 4; reg++) {
            int r = row0 + wr * 64 + m * 16 + ((lane >> 4) << 2) + reg;
            if (r >= M) continue;
#pragma unroll
            for (int n = 0; n < 4; n++) {
                int c = col0 + wc * 64 + n * 16 + (lane & 15);
                float v = acc[m][n][reg];
                if (MODE == 0)
                    ((unsigned short*)Cv)[(size_t)blockIdx.z * sc + (size_t)r * ldc + c] = f2bf(v);
                else
                    ((float*)Cv)[(size_t)blockIdx.z * sc + (size_t)r * ldc + c] = v;
            }
        }
    }
}

// ---------------------------------------------------------------------------
extern "C" void kernel_launch(void* const* d_in, const int* in_sizes, int n_in,
                              void* d_out, int out_size, void* d_ws, size_t ws_size,
                              hipStream_t stream)
{
    const float* x   = (const float*)d_in[0];
    const float* Wq  = (const float*)d_in[1];
    const float* Wk  = (const float*)d_in[2];
    const float* Wv  = (const float*)d_in[3];
    const float* Whp = (const float*)d_in[4];
    const int* eidx  = (const int*)d_in[5];
    const int* etyp  = (const int*)d_in[6];
    const int* erow = eidx;
    const int* ecol = eidx + EE;
    float* out = (float*)d_out;

    char* p = (char*)d_ws;
    unsigned short* xb    = (unsigned short*)p; p += (size_t)NN * DD * 2;        // 25.6 MB
    unsigned short* xT    = (unsigned short*)p; p += (size_t)DD * NPAD * 2;      // 25.6 MB
    char*           regB  = p;                  p += (size_t)NN * 1536 * 2;      // 153.6 MB (Gp then Afull)
    unsigned short* Gb    = (unsigned short*)p; p += (size_t)RR * 65536 * 2;
    unsigned short* U1    = (unsigned short*)p; p += (size_t)RR * 65536 * 2;
    unsigned short* U2    = (unsigned short*)p; p += (size_t)RR * 65536 * 2;
    unsigned short* BfullT= (unsigned short*)p; p += (size_t)1536 * 256 * 2;
    unsigned short* Bout  = (unsigned short*)p; p += (size_t)256 * 1536 * 2;
    unsigned short* WvTcat= (unsigned short*)p; p += (size_t)256 * 768 * 2;
    unsigned short* WkT   = (unsigned short*)p; p += (size_t)RR * 65536 * 2;
    unsigned short* Wqb   = (unsigned short*)p; p += (size_t)RR * 65536 * 2;
    unsigned short* WhpT  = (unsigned short*)p; p += 65536 * 2;
    unsigned short* wbf   = (unsigned short*)p; p += (size_t)RR * NPAD * 2;
    float*          qs    = (float*)p;          p += (size_t)RR * NN * 4;
    float*          xw    = (float*)p;          p += 768 * 4;
    float*          ks    = (float*)p;          p += 768 * 4;
    float*          tv    = (float*)p;          p += 768 * 4;
    int*            c_in  = (int*)p;            p += (size_t)RR * NN * 4;
    int*            c_out = (int*)p;            p += (size_t)RR * NN * 4;
    int*            off   = (int*)p;            p += (size_t)(RR * NN + 4) * 4;
    int*            cur   = (int*)p;            p += (size_t)RR * NN * 4;
    int*            scol  = (int*)p;            p += (size_t)EE * 4;
    int*            nr    = (int*)p;            p += RR * 4;
    int*            bsum  = (int*)p;            p += SNB * 4;
    int*            boff  = (int*)p;            p += SNB * 4;
    float*          Gp    = (float*)regB;       // 50.3 MB, dead before Afull written
    unsigned short* Afull = (unsigned short*)regB;

    prep_w<<<3328, 256, 0, stream>>>(Wq, Wk, Wv, Whp, WvTcat, WkT, Wqb, WhpT, BfullT);
    transpose_conv<<<dim3(NPAD / 64, 4), 256, 0, stream>>>(x, xb, xT);
    hipMemsetAsync(c_in, 0, (size_t)(6 * NN) * sizeof(int), stream);
    hipMemsetAsync(nr, 0, RR * sizeof(int), stream);
    count_kernel<<<512, 256, 0, stream>>>(erow, ecol, etyp, c_in, c_out, nr);
    scan_reduce<<<SNB, 256, 0, stream>>>(c_out, bsum);
    scan_top<<<1, 256, 0, stream>>>(bsum, boff, off + SCT);
    scan_bot<<<SNB, 256, 0, stream>>>(c_out, boff, off, cur);
    fill_kernel<<<(EE + 255) / 256, 256, 0, stream>>>(erow, ecol, etyp, cur, scol);
    wbf_kernel<<<(3 * NPAD + 255) / 256, 256, 0, stream>>>(c_in, wbf);
    xw_kernel<<<256, 256, 0, stream>>>(xT, c_in, xw);

    g_kernel<<<dim3(2, 2, GS), 512, 0, stream>>>(xT, wbf, Gp);
    greduce_kernel<<<12 * 64, 256, 0, stream>>>(Gp, Gb);

    // U1 = Wv^T G ; U2 = U1 Wk ; BfullT rows 0..767: U3^T[k][j] (swapped operands)
    gemm_nt<0><<<dim3(2, 2, 3), 256, 0, stream>>>(WvTcat, 768, Gb, 256, U1, 256, 256, 256,
                                                  256, 65536, 65536);
    gemm_nt<0><<<dim3(2, 2, 3), 256, 0, stream>>>(U1, 256, WkT, 256, U2, 256, 256, 256,
                                                  65536, 65536, 65536);
    gemm_nt<0><<<dim3(2, 2, 3), 256, 0, stream>>>(Wqb, 256, U2, 256, BfullT, 256, 256, 256,
                                                  65536, 65536, 65536);
    // Bout[j][k] = sum_p WhpT[j][p] * BfullT[k][p]   (256 x 1536, bf16)
    gemm_nt<0><<<dim3(2, 12), 256, 0, stream>>>(WhpT, 256, BfullT, 256, Bout, 1536, 256, 256,
                                                0, 0, 0);
    matvec_bf<<<192, 256, 0, stream>>>(WkT, xw, ks);   // ks = Wk^T (x^T w)
    matvec_bf<<<192, 256, 0, stream>>>(Wqb, ks, tv);   // t  = Wq ks
    qs_kernel<<<(NN + 3) / 4, 256, 0, stream>>>(xb, tv, qs);

    gather_kernel<<<(NN + 3) / 4, 256, 0, stream>>>(xb, scol, off, qs, c_out, nr, Afull);

    const int MB = (NN + 127) / 128;  // 391
    // out = Afull @ Bout^T   (K=1536, fp32 store)
    gemm_nt<1><<<dim3(MB, 2), 256, 0, stream>>>(Afull, 1536, Bout, 1536, out, 256, NN, 1536,
                                                0, 0, 0);
}

// Round 8
// 320.163 us; speedup vs baseline: 14.2499x; 1.0655x over previous
//
#include <hip/hip_runtime.h>

#define NN 50000
#define EE 300000
#define DD 256
#define RR 3
#define NPAD 50048            // 782 * 64
#define GS 64                 // split-K slices for G
#define SCT (RR * NN)         // 150000
#define SCB 1024
#define SNB ((SCT + SCB - 1) / SCB)  // 147
#define TBLK 3128             // transpose blocks in prep_tc (782*4)

using bf16x8 = __attribute__((ext_vector_type(8))) short;
using f32x4  = __attribute__((ext_vector_type(4))) float;

__device__ __forceinline__ float bf2f(unsigned short u) {
    return __uint_as_float(((unsigned)u) << 16);
}
__device__ __forceinline__ unsigned short f2bf(float f) {
    unsigned u = __float_as_uint(f);
    return (unsigned short)((u + 0x7fffu + ((u >> 16) & 1u)) >> 16);
}
__device__ __forceinline__ void gload_lds16(const void* g, void* l) {
    __builtin_amdgcn_global_load_lds(
        (const __attribute__((address_space(1))) unsigned int*)g,
        (__attribute__((address_space(3))) unsigned int*)l, 16, 0, 0);
}

// ---------------------------------------------------------------------------
// Merged: x transpose/convert (blocks 0..TBLK-1) + weight bf16 copies.
// Wqb/Wkb/Wvb = plain bf16 copies; WhpT[n][k] = Whp[k][n].
__global__ __launch_bounds__(256) void prep_tc(
    const float* __restrict__ x, const float* __restrict__ Wq,
    const float* __restrict__ Wk, const float* __restrict__ Wv,
    const float* __restrict__ Whp,
    unsigned short* __restrict__ xb, unsigned short* __restrict__ xT,
    unsigned short* __restrict__ Wqb, unsigned short* __restrict__ Wkb,
    unsigned short* __restrict__ Wvb, unsigned short* __restrict__ WhpT)
{
    const int tid = threadIdx.x;
    if (blockIdx.x < TBLK) {
        __shared__ unsigned short t[64][66];
        const int tb = blockIdx.x;
        const int n0 = (tb % 782) * 64, i0 = (tb / 782) * 64;
        const int nl = tid >> 2, c0 = (tid & 3) * 16;
        unsigned short vb[16];
        int n = n0 + nl;
        if (n < NN) {
            const float* src = x + (size_t)n * DD + i0 + c0;
#pragma unroll
            for (int q = 0; q < 16; q += 4) {
                float4 v = *(const float4*)(src + q);
                vb[q] = f2bf(v.x); vb[q + 1] = f2bf(v.y);
                vb[q + 2] = f2bf(v.z); vb[q + 3] = f2bf(v.w);
            }
#pragma unroll
            for (int q = 0; q < 16; q += 4)
                *(ushort4*)(xb + (size_t)n * DD + i0 + c0 + q) =
                    make_ushort4(vb[q], vb[q + 1], vb[q + 2], vb[q + 3]);
        } else {
#pragma unroll
            for (int q = 0; q < 16; q++) vb[q] = 0;
        }
#pragma unroll
        for (int q = 0; q < 16; q++) t[nl][c0 + q] = vb[q];
        __syncthreads();
        const int il = tid >> 2, nc0 = (tid & 3) * 16;
        unsigned short ob[16];
#pragma unroll
        for (int q = 0; q < 16; q++) ob[q] = t[nc0 + q][il];
#pragma unroll
        for (int q = 0; q < 16; q += 4)
            *(ushort4*)(xT + (size_t)(i0 + il) * NPAD + n0 + nc0 + q) =
                make_ushort4(ob[q], ob[q + 1], ob[q + 2], ob[q + 3]);
    } else {
        int t = (blockIdx.x - TBLK) * 256 + tid;
        int slot = t >> 16, o = t & 65535;
        int a = o >> 8, b = o & 255;
        if (slot < 3)       Wqb[(size_t)slot * 65536 + o] = f2bf(Wq[(size_t)slot * 65536 + o]);
        else if (slot < 6)  Wkb[(size_t)(slot - 3) * 65536 + o] = f2bf(Wk[(size_t)(slot - 3) * 65536 + o]);
        else if (slot < 9)  Wvb[(size_t)(slot - 6) * 65536 + o] = f2bf(Wv[(size_t)(slot - 6) * 65536 + o]);
        else if (slot == 9) WhpT[o] = f2bf(Whp[b * 256 + a]);
    }
}

// ---------------------------------------------------------------------------
// Degree counts; nr via LDS block counters.
__global__ __launch_bounds__(256) void count_kernel(
    const int* __restrict__ erow, const int* __restrict__ ecol,
    const int* __restrict__ etype, int* __restrict__ c_in,
    int* __restrict__ c_out, int* __restrict__ nr)
{
    __shared__ int lnr[RR];
    if (threadIdx.x < RR) lnr[threadIdx.x] = 0;
    __syncthreads();
    int g = blockIdx.x * blockDim.x + threadIdx.x;
    int stride = gridDim.x * blockDim.x;
    for (int e = g; e < EE; e += stride) {
        int t = etype[e];
        atomicAdd(&c_out[t * NN + erow[e]], 1);
        atomicAdd(&c_in[t * NN + ecol[e]], 1);
        atomicAdd(&lnr[t], 1);
    }
    __syncthreads();
    if (threadIdx.x < RR) atomicAdd(&nr[threadIdx.x], lnr[threadIdx.x]);
}

// ---------------------------------------------------------------------------
// Multi-block scan
__global__ __launch_bounds__(256) void scan_reduce(
    const int* __restrict__ cnt, int* __restrict__ bsum)
{
    __shared__ int ws[4];
    const int b = blockIdx.x, tid = threadIdx.x;
    const int i = b * SCB + tid * 4;
    int s = 0;
    if (i < SCT) {
        int4 v = *(const int4*)(cnt + i);
        s = v.x + v.y + v.z + v.w;
    }
#pragma unroll
    for (int off = 32; off; off >>= 1) s += __shfl_down(s, off, 64);
    if ((tid & 63) == 0) ws[tid >> 6] = s;
    __syncthreads();
    if (tid == 0) bsum[b] = ws[0] + ws[1] + ws[2] + ws[3];
}

__global__ __launch_bounds__(256) void scan_top(
    const int* __restrict__ bsum, int* __restrict__ boff, int* __restrict__ offT)
{
    __shared__ int bs[256];
    const int tid = threadIdx.x;
    int v = tid < SNB ? bsum[tid] : 0;
    bs[tid] = v;
    __syncthreads();
    for (int d = 1; d < 256; d <<= 1) {
        int t = (tid >= d) ? bs[tid - d] : 0;
        __syncthreads();
        bs[tid] += t;
        __syncthreads();
    }
    if (tid < SNB) boff[tid] = tid ? bs[tid - 1] : 0;
    if (tid == 255) *offT = bs[255];
}

__global__ __launch_bounds__(256) void scan_bot(
    const int* __restrict__ cnt, const int* __restrict__ boff,
    int* __restrict__ off, int* __restrict__ cur)
{
    __shared__ int bs[256];
    const int b = blockIdx.x, tid = threadIdx.x;
    const int i = b * SCB + tid * 4;
    int4 v = make_int4(0, 0, 0, 0);
    if (i < SCT) v = *(const int4*)(cnt + i);
    int s = v.x + v.y + v.z + v.w;
    bs[tid] = s;
    __syncthreads();
    for (int d = 1; d < 256; d <<= 1) {
        int t = (tid >= d) ? bs[tid - d] : 0;
        __syncthreads();
        bs[tid] += t;
        __syncthreads();
    }
    if (i < SCT) {
        int pre = boff[b] + (tid ? bs[tid - 1] : 0);
        int4 o;
        o.x = pre;
        o.y = pre + v.x;
        o.z = pre + v.x + v.y;
        o.w = pre + v.x + v.y + v.z;
        *(int4*)(off + i) = o;
        *(int4*)(cur + i) = o;
    }
}

// Bucket-fill: sorted_col grouped by key (t*NN+row).
__global__ __launch_bounds__(256) void fill_kernel(
    const int* __restrict__ erow, const int* __restrict__ ecol,
    const int* __restrict__ etype, int* __restrict__ cur,
    int* __restrict__ scol)
{
    int e = blockIdx.x * 256 + threadIdx.x;
    if (e < EE) {
        int key = etype[e] * NN + erow[e];
        int p = atomicAdd(&cur[key], 1);
        scol[p] = ecol[e];
    }
}

// ---------------------------------------------------------------------------
// Merged: blocks 0..255 -> xw[r][i] = sum_n c_in[r][n]*x[n][i] (via xT);
//         blocks 256..  -> wbf bf16 conversion of c_in (padded).
__global__ __launch_bounds__(256) void wbfxw_kernel(
    const unsigned short* __restrict__ xT, const int* __restrict__ c_in,
    float* __restrict__ xw, unsigned short* __restrict__ wbf)
{
    const int tid = threadIdx.x;
    if (blockIdx.x < 256) {
        __shared__ float red[3][4];
        const int i = blockIdx.x;
        float a0 = 0.f, a1 = 0.f, a2 = 0.f;
        for (int n = tid * 4; n < NN; n += 1024) {
            ushort4 xv = *(const ushort4*)(xT + (size_t)i * NPAD + n);
            int4 w0 = *(const int4*)(c_in + n);
            int4 w1 = *(const int4*)(c_in + NN + n);
            int4 w2 = *(const int4*)(c_in + 2 * NN + n);
            float f0 = bf2f(xv.x), f1 = bf2f(xv.y), f2 = bf2f(xv.z), f3 = bf2f(xv.w);
            a0 += f0 * w0.x + f1 * w0.y + f2 * w0.z + f3 * w0.w;
            a1 += f0 * w1.x + f1 * w1.y + f2 * w1.z + f3 * w1.w;
            a2 += f0 * w2.x + f1 * w2.y + f2 * w2.z + f3 * w2.w;
        }
#pragma unroll
        for (int off = 32; off; off >>= 1) {
            a0 += __shfl_down(a0, off, 64);
            a1 += __shfl_down(a1, off, 64);
            a2 += __shfl_down(a2, off, 64);
        }
        if ((tid & 63) == 0) {
            red[0][tid >> 6] = a0; red[1][tid >> 6] = a1; red[2][tid >> 6] = a2;
        }
        __syncthreads();
        if (tid < 3)
            xw[tid * 256 + i] = red[tid][0] + red[tid][1] + red[tid][2] + red[tid][3];
    } else {
        int t = (blockIdx.x - 256) * 256 + tid;
        if (t < 3 * NPAD) {
            int r = t / NPAD, n = t % NPAD;
            wbf[t] = f2bf(n < NN ? (float)c_in[r * NN + n] : 0.f);
        }
    }
}

// ---------------------------------------------------------------------------
// G partials: Gp[z][tile][r][128*128] += xT(w-scaled) @ xT^T over node chunk z
__global__ __launch_bounds__(512) void g_kernel(
    const unsigned short* __restrict__ xT, const unsigned short* __restrict__ wbf,
    float* __restrict__ Gp)
{
    __shared__ __align__(16) char ldsA[16384];
    __shared__ __align__(16) char ldsB[16384];
    const int tid = threadIdx.x, lane = tid & 63, wid = tid >> 6;
    const int wr = wid >> 1, wc = wid & 1;
    const int i0 = blockIdx.x * 128, j0 = blockIdx.y * 128;
    const int TPZ = (NPAD / 64 + GS - 1) / GS;
    const int kt0 = blockIdx.z * TPZ;
    const int kt1 = min(NPAD / 64, kt0 + TPZ);

    f32x4 acc[3][2][4];
#pragma unroll
    for (int r = 0; r < 3; r++)
#pragma unroll
        for (int m = 0; m < 2; m++)
#pragma unroll
            for (int n = 0; n < 4; n++) acc[r][m][n] = (f32x4){0.f, 0.f, 0.f, 0.f};

    for (int kt = kt0; kt < kt1; kt++) {
        const int kbyte = kt * 128;
#pragma unroll
        for (int is = 0; is < 2; is++) {
            int lb = is * 8192 + wid * 1024;
            int d = lb + lane * 16;
            int row = d >> 7;
            int sc_ = (d & 127) ^ ((row & 7) << 4);
            gload_lds16((const char*)xT + (size_t)(i0 + row) * (NPAD * 2) + kbyte + sc_, ldsA + lb);
            gload_lds16((const char*)xT + (size_t)(j0 + row) * (NPAD * 2) + kbyte + sc_, ldsB + lb);
        }
        __syncthreads();
#pragma unroll
        for (int kk = 0; kk < 2; kk++) {
            const int cb = kk * 64 + ((lane >> 4) << 4);
            bf16x8 bfr[4];
#pragma unroll
            for (int n = 0; n < 4; n++) {
                int rn = wc * 64 + n * 16 + (lane & 15);
                bfr[n] = *(const bf16x8*)(ldsB + rn * 128 + (cb ^ ((rn & 7) << 4)));
            }
            float au[2][8];
#pragma unroll
            for (int m = 0; m < 2; m++) {
                int row = wr * 32 + m * 16 + (lane & 15);
                bf16x8 ar = *(const bf16x8*)(ldsA + row * 128 + (cb ^ ((row & 7) << 4)));
#pragma unroll
                for (int q = 0; q < 8; q++) au[m][q] = bf2f((unsigned short)ar[q]);
            }
            const int nb = kt * 64 + kk * 32 + ((lane >> 4) << 3);
#pragma unroll
            for (int r = 0; r < 3; r++) {
                bf16x8 wv = *(const bf16x8*)(wbf + (size_t)r * NPAD + nb);
                float wf[8];
#pragma unroll
                for (int q = 0; q < 8; q++) wf[q] = bf2f((unsigned short)wv[q]);
                bf16x8 am[2];
#pragma unroll
                for (int m = 0; m < 2; m++)
#pragma unroll
                    for (int q = 0; q < 8; q++)
                        am[m][q] = (short)f2bf(au[m][q] * wf[q]);
#pragma unroll
                for (int m = 0; m < 2; m++)
#pragma unroll
                    for (int n = 0; n < 4; n++)
                        acc[r][m][n] = __builtin_amdgcn_mfma_f32_16x16x32_bf16(
                            am[m], bfr[n], acc[r][m][n], 0, 0, 0);
            }
        }
        __syncthreads();
    }
    float* base = Gp + ((size_t)blockIdx.z * 4 + blockIdx.x * 2 + blockIdx.y) * 3 * 16384;
#pragma unroll
    for (int r = 0; r < 3; r++)
#pragma unroll
        for (int m = 0; m < 2; m++)
#pragma unroll
            for (int n = 0; n < 4; n++) {
                int col = wc * 64 + n * 16 + (lane & 15);
                int rw0 = wr * 32 + m * 16 + ((lane >> 4) << 2);
#pragma unroll
                for (int reg = 0; reg < 4; reg++)
                    base[r * 16384 + (rw0 + reg) * 128 + col] = acc[r][m][n][reg];
            }
}

// Reduce Gp over z, emit Gb (bf16 [3][256][256])
__global__ __launch_bounds__(256) void greduce_kernel(
    const float* __restrict__ Gp, unsigned short* __restrict__ Gb)
{
    int gid = blockIdx.x * 256 + threadIdx.x;
    int t = gid >> 14, rem = gid & 16383;
    int r = t % 3, tile = t / 3;
    float s = 0.f;
    for (int z = 0; z < GS; z++)
        s += Gp[(size_t)z * 196608 + ((size_t)tile * 3 + r) * 16384 + rem];
    int i = (tile >> 1) * 128 + (rem >> 7);
    int j = (tile & 1) * 128 + (rem & 127);
    Gb[(size_t)r * 65536 + i * 256 + j] = f2bf(s);
}

// y[r][row] = dot(Mat[r] row (bf16,256), v[r] (f32,256))
__global__ __launch_bounds__(256) void matvec_bf(
    const unsigned short* __restrict__ Mat, const float* __restrict__ v,
    float* __restrict__ y)
{
    __shared__ float vs[256];
    const int b = blockIdx.x;
    const int r = b >> 6, rb = (b & 63) * 4;
    const int tid = threadIdx.x;
    vs[tid] = v[r * 256 + tid];
    __syncthreads();
    const int wid = tid >> 6, lane = tid & 63;
    const int row = rb + wid;
    ushort4 m4 = *(const ushort4*)(Mat + (size_t)r * 65536 + row * 256 + lane * 4);
    float s = bf2f(m4.x) * vs[lane * 4] + bf2f(m4.y) * vs[lane * 4 + 1] +
              bf2f(m4.z) * vs[lane * 4 + 2] + bf2f(m4.w) * vs[lane * 4 + 3];
#pragma unroll
    for (int off = 32; off; off >>= 1) s += __shfl_down(s, off, 64);
    if (lane == 0) y[r * 256 + row] = s;
}

// ---------------------------------------------------------------------------
// One wave per node, qs fused: compute qs_t = x[n].tv_t inline, then
// Afull[n][t*256+:]     = (cnt/denom) * x[n]
// Afull[n][768+t*256+:] = (Nr/denom)  * sum_{e in seg(t,n)} x[col]
__global__ __launch_bounds__(256) void gather_kernel(
    const unsigned short* __restrict__ xb, const int* __restrict__ scol,
    const int* __restrict__ off, const float* __restrict__ tv,
    const int* __restrict__ c_out, const int* __restrict__ nr,
    unsigned short* __restrict__ Afull)
{
    __shared__ float ts[768];
    __shared__ float nrs[RR];
    const int tid = threadIdx.x;
    for (int k = tid; k < 768; k += 256) ts[k] = tv[k];
    if (tid < RR) nrs[tid] = (float)nr[tid];
    __syncthreads();
    const int wid = tid >> 6, lane = tid & 63;
    const int n = blockIdx.x * 4 + wid;
    if (n >= NN) return;
    ushort4 xv = *(const ushort4*)(xb + (size_t)n * DD + lane * 4);
    float xf[4] = {bf2f(xv.x), bf2f(xv.y), bf2f(xv.z), bf2f(xv.w)};
    float dots[RR];
#pragma unroll
    for (int t = 0; t < RR; t++) {
        float s = xf[0] * ts[t * 256 + lane * 4] + xf[1] * ts[t * 256 + lane * 4 + 1] +
                  xf[2] * ts[t * 256 + lane * 4 + 2] + xf[3] * ts[t * 256 + lane * 4 + 3];
#pragma unroll
        for (int o = 32; o; o >>= 1) s += __shfl_xor(s, o, 64);
        dots[t] = s;
    }
#pragma unroll
    for (int t = 0; t < RR; t++) {
        float nrf = nrs[t];
        float denom = dots[t] + nrf;
        int cnt = c_out[t * NN + n];
        float s2 = cnt ? (float)cnt / denom : 0.f;
        ushort4 o1;
        o1.x = f2bf(s2 * xf[0]); o1.y = f2bf(s2 * xf[1]);
        o1.z = f2bf(s2 * xf[2]); o1.w = f2bf(s2 * xf[3]);
        *(ushort4*)(Afull + (size_t)n * 1536 + t * 256 + lane * 4) = o1;

        float acc[4] = {0.f, 0.f, 0.f, 0.f};
        int b0 = off[t * NN + n], b1 = off[t * NN + n + 1];
        for (int i = b0; i < b1; i++) {
            int col = scol[i];
            ushort4 v = *(const ushort4*)(xb + (size_t)col * DD + lane * 4);
            acc[0] += bf2f(v.x); acc[1] += bf2f(v.y);
            acc[2] += bf2f(v.z); acc[3] += bf2f(v.w);
        }
        float s1 = nrf / denom;
        ushort4 o2;
        o2.x = f2bf(s1 * acc[0]); o2.y = f2bf(s1 * acc[1]);
        o2.z = f2bf(s1 * acc[2]); o2.w = f2bf(s1 * acc[3]);
        *(ushort4*)(Afull + (size_t)n * 1536 + 768 + t * 256 + lane * 4) = o2;
    }
}

// ---------------------------------------------------------------------------
// MFMA NT GEMM: C[M,N] = A[M,KK] @ B[N,KK]^T (bf16 in, fp32 acc)
// MODE 0: bf16 store; MODE 1: fp32 store. SWZ: bijective XCD remap on blockIdx.x.
template <int MODE, int SWZ>
__global__ __launch_bounds__(256) void gemm_nt(
    const unsigned short* __restrict__ A, int lda,
    const unsigned short* __restrict__ B, int ldb,
    void* __restrict__ Cv, int ldc, int M, int KK,
    size_t sa, size_t sb, size_t sc)
{
    A += (size_t)blockIdx.z * sa;
    B += (size_t)blockIdx.z * sb;
    __shared__ __align__(16) char ldsA[16384];
    __shared__ __align__(16) char ldsB[16384];
    const int tid = threadIdx.x, lane = tid & 63, wid = tid >> 6;
    const int wr = wid >> 1, wc = wid & 1;
    int bx = blockIdx.x;
    if (SWZ) {
        int nwg = gridDim.x, q = nwg >> 3, rem = nwg & 7;
        int xcd = bx & 7, idx = bx >> 3;
        bx = (xcd < rem ? xcd * (q + 1) : rem * (q + 1) + (xcd - rem) * q) + idx;
    }
    const int row0 = bx * 128, col0 = blockIdx.y * 128;

    f32x4 acc[4][4];
#pragma unroll
    for (int m = 0; m < 4; m++)
#pragma unroll
        for (int n = 0; n < 4; n++) acc[m][n] = (f32x4){0.f, 0.f, 0.f, 0.f};

    for (int k0 = 0; k0 < KK; k0 += 64) {
#pragma unroll
        for (int is = 0; is < 4; is++) {
            int lb = is * 4096 + wid * 1024;
            int d = lb + lane * 16;
            int row = d >> 7;
            int sc_ = (d & 127) ^ ((row & 7) << 4);
            int gr = row0 + row; gr = gr < M ? gr : M - 1;
            gload_lds16((const char*)(A + (size_t)gr * lda + k0) + sc_, ldsA + lb);
            int rn = col0 + row;
            gload_lds16((const char*)(B + (size_t)rn * ldb + k0) + sc_, ldsB + lb);
        }
        __syncthreads();
#pragma unroll
        for (int kk = 0; kk < 2; kk++) {
            bf16x8 af[4], bf_[4];
            const int cb = kk * 64 + ((lane >> 4) << 4);
#pragma unroll
            for (int m = 0; m < 4; m++) {
                int row = wr * 64 + m * 16 + (lane & 15);
                af[m] = *(const bf16x8*)(ldsA + row * 128 + (cb ^ ((row & 7) << 4)));
                int rn = wc * 64 + m * 16 + (lane & 15);
                bf_[m] = *(const bf16x8*)(ldsB + rn * 128 + (cb ^ ((rn & 7) << 4)));
            }
#pragma unroll
            for (int m = 0; m < 4; m++)
#pragma unroll
                for (int n = 0; n < 4; n++)
                    acc[m][n] = __builtin_amdgcn_mfma_f32_16x16x32_bf16(
                        af[m], bf_[n], acc[m][n], 0, 0, 0);
        }
        __syncthreads();
    }

#pragma unroll
    for (int m = 0; m < 4; m++) {
#pragma unroll
        for (int reg = 0; reg < 4; reg++) {
            int r = row0 + wr * 64 + m * 16 + ((lane >> 4) << 2) + reg;
            if (r >= M) continue;
#pragma unroll
            for (int n = 0; n < 4; n++) {
                int c = col0 + wc * 64 + n * 16 + (lane & 15);
                float v = acc[m][n][reg];
                if (MODE == 0)
                    ((unsigned short*)Cv)[(size_t)blockIdx.z * sc + (size_t)r * ldc + c] = f2bf(v);
                else
                    ((float*)Cv)[(size_t)blockIdx.z * sc + (size_t)r * ldc + c] = v;
            }
        }
    }
}

// ---------------------------------------------------------------------------
extern "C" void kernel_launch(void* const* d_in, const int* in_sizes, int n_in,
                              void* d_out, int out_size, void* d_ws, size_t ws_size,
                              hipStream_t stream)
{
    const float* x   = (const float*)d_in[0];
    const float* Wq  = (const float*)d_in[1];
    const float* Wk  = (const float*)d_in[2];
    const float* Wv  = (const float*)d_in[3];
    const float* Whp = (const float*)d_in[4];
    const int* eidx  = (const int*)d_in[5];
    const int* etyp  = (const int*)d_in[6];
    const int* erow = eidx;
    const int* ecol = eidx + EE;
    float* out = (float*)d_out;

    char* p = (char*)d_ws;
    unsigned short* xb    = (unsigned short*)p; p += (size_t)NN * DD * 2;        // 25.6 MB
    unsigned short* xT    = (unsigned short*)p; p += (size_t)DD * NPAD * 2;      // 25.6 MB
    char*           regB  = p;                  p += (size_t)NN * 1536 * 2;      // 153.6 MB (Gp then Afull)
    unsigned short* Gb    = (unsigned short*)p; p += (size_t)RR * 65536 * 2;
    unsigned short* M1    = (unsigned short*)p; p += (size_t)RR * 65536 * 2;
    unsigned short* Tm    = (unsigned short*)p; p += (size_t)RR * 65536 * 2;
    unsigned short* Bout  = (unsigned short*)p; p += (size_t)256 * 1536 * 2;
    unsigned short* Wqb   = (unsigned short*)p; p += (size_t)RR * 65536 * 2;
    unsigned short* Wkb   = (unsigned short*)p; p += (size_t)RR * 65536 * 2;
    unsigned short* Wvb   = (unsigned short*)p; p += (size_t)RR * 65536 * 2;
    unsigned short* WhpT  = (unsigned short*)p; p += 65536 * 2;
    unsigned short* wbf   = (unsigned short*)p; p += (size_t)RR * NPAD * 2;
    float*          xw    = (float*)p;          p += 768 * 4;
    float*          tv    = (float*)p;          p += 768 * 4;
    int*            c_in  = (int*)p;            p += (size_t)RR * NN * 4;   // ┐ one
    int*            c_out = (int*)p;            p += (size_t)RR * NN * 4;   // │ memset
    int*            nr    = (int*)p;            p += 4 * 4;                 // ┘ region
    int*            off   = (int*)p;            p += (size_t)(RR * NN + 4) * 4;
    int*            cur   = (int*)p;            p += (size_t)RR * NN * 4;
    int*            scol  = (int*)p;            p += (size_t)EE * 4;
    int*            bsum  = (int*)p;            p += SNB * 4;
    int*            boff  = (int*)p;            p += SNB * 4;
    float*          Gp    = (float*)regB;       // dead before Afull written
    unsigned short* Afull = (unsigned short*)regB;

    prep_tc<<<TBLK + 2560, 256, 0, stream>>>(x, Wq, Wk, Wv, Whp, xb, xT, Wqb, Wkb, Wvb, WhpT);
    hipMemsetAsync(c_in, 0, (size_t)(6 * NN + 4) * sizeof(int), stream);
    count_kernel<<<512, 256, 0, stream>>>(erow, ecol, etyp, c_in, c_out, nr);
    scan_reduce<<<SNB, 256, 0, stream>>>(c_out, bsum);
    scan_top<<<1, 256, 0, stream>>>(bsum, boff, off + SCT);
    scan_bot<<<SNB, 256, 0, stream>>>(c_out, boff, off, cur);
    fill_kernel<<<(EE + 255) / 256, 256, 0, stream>>>(erow, ecol, etyp, cur, scol);
    wbfxw_kernel<<<256 + (3 * NPAD + 255) / 256, 256, 0, stream>>>(xT, c_in, xw, wbf);

    // Pre-G weight products: M1_r = Wq_r @ Wk_r^T ; Bout cols 768+ = Whp^T @ Wv_r^T
    gemm_nt<0, 0><<<dim3(2, 2, 3), 256, 0, stream>>>(Wqb, 256, Wkb, 256, M1, 256, 256, 256,
                                                     65536, 65536, 65536);
    gemm_nt<0, 0><<<dim3(2, 2, 3), 256, 0, stream>>>(WhpT, 256, Wvb, 256, Bout + 768, 1536,
                                                     256, 256, 0, 65536, 256);

    g_kernel<<<dim3(2, 2, GS), 512, 0, stream>>>(xT, wbf, Gp);
    greduce_kernel<<<12 * 64, 256, 0, stream>>>(Gp, Gb);

    // T_r = M1_r @ G_r (G symmetric) ; Bout cols 0..767 = (M2T_r) @ T_r^T
    gemm_nt<0, 0><<<dim3(2, 2, 3), 256, 0, stream>>>(M1, 256, Gb, 256, Tm, 256, 256, 256,
                                                     65536, 65536, 65536);
    gemm_nt<0, 0><<<dim3(2, 2, 3), 256, 0, stream>>>(Bout + 768, 1536, Tm, 256, Bout, 1536,
                                                     256, 256, 256, 65536, 256);
    matvec_bf<<<192, 256, 0, stream>>>(M1, xw, tv);   // tv = M1 @ xw = Wq Wk^T xw

    gather_kernel<<<(NN + 3) / 4, 256, 0, stream>>>(xb, scol, off, tv, c_out, nr, Afull);

    const int MB = (NN + 127) / 128;  // 391
    // out = Afull @ Bout^T   (K=1536, fp32 store, XCD-swizzled)
    gemm_nt<1, 1><<<dim3(MB, 2), 256, 0, stream>>>(Afull, 1536, Bout, 1536, out, 256, NN, 1536,
                                                   0, 0, 0);
}

// Round 9
// 292.129 us; speedup vs baseline: 15.6174x; 1.0960x over previous
//
#include <hip/hip_runtime.h>

#define NN 50000
#define EE 300000
#define DD 256
#define RR 3
#define NPAD 50048            // 782 * 64
#define GS 64                 // split-K slices for G
#define SCT (RR * NN)         // 150000
#define SCB 1024
#define SNB ((SCT + SCB - 1) / SCB)  // 147
#define TBLK 3128             // transpose blocks in prep_tc (782*4)

using bf16x8 = __attribute__((ext_vector_type(8))) short;
using f32x4  = __attribute__((ext_vector_type(4))) float;

__device__ __forceinline__ float bf2f(unsigned short u) {
    return __uint_as_float(((unsigned)u) << 16);
}
__device__ __forceinline__ unsigned short f2bf(float f) {
    unsigned u = __float_as_uint(f);
    return (unsigned short)((u + 0x7fffu + ((u >> 16) & 1u)) >> 16);
}
__device__ __forceinline__ void gload_lds16(const void* g, void* l) {
    __builtin_amdgcn_global_load_lds(
        (const __attribute__((address_space(1))) unsigned int*)g,
        (__attribute__((address_space(3))) unsigned int*)l, 16, 0, 0);
}

// ---------------------------------------------------------------------------
// Merged: x transpose/convert (blocks 0..TBLK-1) + weight bf16 copies.
__global__ __launch_bounds__(256) void prep_tc(
    const float* __restrict__ x, const float* __restrict__ Wq,
    const float* __restrict__ Wk, const float* __restrict__ Wv,
    const float* __restrict__ Whp,
    unsigned short* __restrict__ xb, unsigned short* __restrict__ xT,
    unsigned short* __restrict__ Wqb, unsigned short* __restrict__ Wkb,
    unsigned short* __restrict__ Wvb, unsigned short* __restrict__ WhpT)
{
    const int tid = threadIdx.x;
    if (blockIdx.x < TBLK) {
        __shared__ unsigned short t[64][66];
        const int tb = blockIdx.x;
        const int n0 = (tb % 782) * 64, i0 = (tb / 782) * 64;
        const int nl = tid >> 2, c0 = (tid & 3) * 16;
        unsigned short vb[16];
        int n = n0 + nl;
        if (n < NN) {
            const float* src = x + (size_t)n * DD + i0 + c0;
#pragma unroll
            for (int q = 0; q < 16; q += 4) {
                float4 v = *(const float4*)(src + q);
                vb[q] = f2bf(v.x); vb[q + 1] = f2bf(v.y);
                vb[q + 2] = f2bf(v.z); vb[q + 3] = f2bf(v.w);
            }
#pragma unroll
            for (int q = 0; q < 16; q += 4)
                *(ushort4*)(xb + (size_t)n * DD + i0 + c0 + q) =
                    make_ushort4(vb[q], vb[q + 1], vb[q + 2], vb[q + 3]);
        } else {
#pragma unroll
            for (int q = 0; q < 16; q++) vb[q] = 0;
        }
#pragma unroll
        for (int q = 0; q < 16; q++) t[nl][c0 + q] = vb[q];
        __syncthreads();
        const int il = tid >> 2, nc0 = (tid & 3) * 16;
        unsigned short ob[16];
#pragma unroll
        for (int q = 0; q < 16; q++) ob[q] = t[nc0 + q][il];
#pragma unroll
        for (int q = 0; q < 16; q += 4)
            *(ushort4*)(xT + (size_t)(i0 + il) * NPAD + n0 + nc0 + q) =
                make_ushort4(ob[q], ob[q + 1], ob[q + 2], ob[q + 3]);
    } else {
        int t = (blockIdx.x - TBLK) * 256 + tid;
        int slot = t >> 16, o = t & 65535;
        int a = o >> 8, b = o & 255;
        if (slot < 3)       Wqb[(size_t)slot * 65536 + o] = f2bf(Wq[(size_t)slot * 65536 + o]);
        else if (slot < 6)  Wkb[(size_t)(slot - 3) * 65536 + o] = f2bf(Wk[(size_t)(slot - 3) * 65536 + o]);
        else if (slot < 9)  Wvb[(size_t)(slot - 6) * 65536 + o] = f2bf(Wv[(size_t)(slot - 6) * 65536 + o]);
        else if (slot == 9) WhpT[o] = f2bf(Whp[b * 256 + a]);
    }
}

// ---------------------------------------------------------------------------
// Degree counts; nr via LDS block counters.
__global__ __launch_bounds__(256) void count_kernel(
    const int* __restrict__ erow, const int* __restrict__ ecol,
    const int* __restrict__ etype, int* __restrict__ c_in,
    int* __restrict__ c_out, int* __restrict__ nr)
{
    __shared__ int lnr[RR];
    if (threadIdx.x < RR) lnr[threadIdx.x] = 0;
    __syncthreads();
    int g = blockIdx.x * blockDim.x + threadIdx.x;
    int stride = gridDim.x * blockDim.x;
    for (int e = g; e < EE; e += stride) {
        int t = etype[e];
        atomicAdd(&c_out[t * NN + erow[e]], 1);
        atomicAdd(&c_in[t * NN + ecol[e]], 1);
        atomicAdd(&lnr[t], 1);
    }
    __syncthreads();
    if (threadIdx.x < RR) atomicAdd(&nr[threadIdx.x], lnr[threadIdx.x]);
}

// ---------------------------------------------------------------------------
// Multi-block scan
__global__ __launch_bounds__(256) void scan_reduce(
    const int* __restrict__ cnt, int* __restrict__ bsum)
{
    __shared__ int ws[4];
    const int b = blockIdx.x, tid = threadIdx.x;
    const int i = b * SCB + tid * 4;
    int s = 0;
    if (i < SCT) {
        int4 v = *(const int4*)(cnt + i);
        s = v.x + v.y + v.z + v.w;
    }
#pragma unroll
    for (int off = 32; off; off >>= 1) s += __shfl_down(s, off, 64);
    if ((tid & 63) == 0) ws[tid >> 6] = s;
    __syncthreads();
    if (tid == 0) bsum[b] = ws[0] + ws[1] + ws[2] + ws[3];
}

__global__ __launch_bounds__(256) void scan_top(
    const int* __restrict__ bsum, int* __restrict__ boff, int* __restrict__ offT)
{
    __shared__ int bs[256];
    const int tid = threadIdx.x;
    int v = tid < SNB ? bsum[tid] : 0;
    bs[tid] = v;
    __syncthreads();
    for (int d = 1; d < 256; d <<= 1) {
        int t = (tid >= d) ? bs[tid - d] : 0;
        __syncthreads();
        bs[tid] += t;
        __syncthreads();
    }
    if (tid < SNB) boff[tid] = tid ? bs[tid - 1] : 0;
    if (tid == 255) *offT = bs[255];
}

__global__ __launch_bounds__(256) void scan_bot(
    const int* __restrict__ cnt, const int* __restrict__ boff,
    int* __restrict__ off, int* __restrict__ cur)
{
    __shared__ int bs[256];
    const int b = blockIdx.x, tid = threadIdx.x;
    const int i = b * SCB + tid * 4;
    int4 v = make_int4(0, 0, 0, 0);
    if (i < SCT) v = *(const int4*)(cnt + i);
    int s = v.x + v.y + v.z + v.w;
    bs[tid] = s;
    __syncthreads();
    for (int d = 1; d < 256; d <<= 1) {
        int t = (tid >= d) ? bs[tid - d] : 0;
        __syncthreads();
        bs[tid] += t;
        __syncthreads();
    }
    if (i < SCT) {
        int pre = boff[b] + (tid ? bs[tid - 1] : 0);
        int4 o;
        o.x = pre;
        o.y = pre + v.x;
        o.z = pre + v.x + v.y;
        o.w = pre + v.x + v.y + v.z;
        *(int4*)(off + i) = o;
        *(int4*)(cur + i) = o;
    }
}

// Bucket-fill: sorted_col grouped by key (t*NN+row).
__global__ __launch_bounds__(256) void fill_kernel(
    const int* __restrict__ erow, const int* __restrict__ ecol,
    const int* __restrict__ etype, int* __restrict__ cur,
    int* __restrict__ scol)
{
    int e = blockIdx.x * 256 + threadIdx.x;
    if (e < EE) {
        int key = etype[e] * NN + erow[e];
        int p = atomicAdd(&cur[key], 1);
        scol[p] = ecol[e];
    }
}

// ---------------------------------------------------------------------------
// Merged: blocks 0..255 -> xw; blocks 256.. -> wbf conversion.
__global__ __launch_bounds__(256) void wbfxw_kernel(
    const unsigned short* __restrict__ xT, const int* __restrict__ c_in,
    float* __restrict__ xw, unsigned short* __restrict__ wbf)
{
    const int tid = threadIdx.x;
    if (blockIdx.x < 256) {
        __shared__ float red[3][4];
        const int i = blockIdx.x;
        float a0 = 0.f, a1 = 0.f, a2 = 0.f;
        for (int n = tid * 4; n < NN; n += 1024) {
            ushort4 xv = *(const ushort4*)(xT + (size_t)i * NPAD + n);
            int4 w0 = *(const int4*)(c_in + n);
            int4 w1 = *(const int4*)(c_in + NN + n);
            int4 w2 = *(const int4*)(c_in + 2 * NN + n);
            float f0 = bf2f(xv.x), f1 = bf2f(xv.y), f2 = bf2f(xv.z), f3 = bf2f(xv.w);
            a0 += f0 * w0.x + f1 * w0.y + f2 * w0.z + f3 * w0.w;
            a1 += f0 * w1.x + f1 * w1.y + f2 * w1.z + f3 * w1.w;
            a2 += f0 * w2.x + f1 * w2.y + f2 * w2.z + f3 * w2.w;
        }
#pragma unroll
        for (int off = 32; off; off >>= 1) {
            a0 += __shfl_down(a0, off, 64);
            a1 += __shfl_down(a1, off, 64);
            a2 += __shfl_down(a2, off, 64);
        }
        if ((tid & 63) == 0) {
            red[0][tid >> 6] = a0; red[1][tid >> 6] = a1; red[2][tid >> 6] = a2;
        }
        __syncthreads();
        if (tid < 3)
            xw[tid * 256 + i] = red[tid][0] + red[tid][1] + red[tid][2] + red[tid][3];
    } else {
        int t = (blockIdx.x - 256) * 256 + tid;
        if (t < 3 * NPAD) {
            int r = t / NPAD, n = t % NPAD;
            wbf[t] = f2bf(n < NN ? (float)c_in[r * NN + n] : 0.f);
        }
    }
}

// ---------------------------------------------------------------------------
// G partials: Gp[z][tile][r][128*128] += xT(w-scaled) @ xT^T over node chunk z
__global__ __launch_bounds__(512) void g_kernel(
    const unsigned short* __restrict__ xT, const unsigned short* __restrict__ wbf,
    float* __restrict__ Gp)
{
    __shared__ __align__(16) char ldsA[16384];
    __shared__ __align__(16) char ldsB[16384];
    const int tid = threadIdx.x, lane = tid & 63, wid = tid >> 6;
    const int wr = wid >> 1, wc = wid & 1;
    const int i0 = blockIdx.x * 128, j0 = blockIdx.y * 128;
    const int TPZ = (NPAD / 64 + GS - 1) / GS;
    const int kt0 = blockIdx.z * TPZ;
    const int kt1 = min(NPAD / 64, kt0 + TPZ);

    f32x4 acc[3][2][4];
#pragma unroll
    for (int r = 0; r < 3; r++)
#pragma unroll
        for (int m = 0; m < 2; m++)
#pragma unroll
            for (int n = 0; n < 4; n++) acc[r][m][n] = (f32x4){0.f, 0.f, 0.f, 0.f};

    for (int kt = kt0; kt < kt1; kt++) {
        const int kbyte = kt * 128;
#pragma unroll
        for (int is = 0; is < 2; is++) {
            int lb = is * 8192 + wid * 1024;
            int d = lb + lane * 16;
            int row = d >> 7;
            int sc_ = (d & 127) ^ ((row & 7) << 4);
            gload_lds16((const char*)xT + (size_t)(i0 + row) * (NPAD * 2) + kbyte + sc_, ldsA + lb);
            gload_lds16((const char*)xT + (size_t)(j0 + row) * (NPAD * 2) + kbyte + sc_, ldsB + lb);
        }
        __syncthreads();
#pragma unroll
        for (int kk = 0; kk < 2; kk++) {
            const int cb = kk * 64 + ((lane >> 4) << 4);
            bf16x8 bfr[4];
#pragma unroll
            for (int n = 0; n < 4; n++) {
                int rn = wc * 64 + n * 16 + (lane & 15);
                bfr[n] = *(const bf16x8*)(ldsB + rn * 128 + (cb ^ ((rn & 7) << 4)));
            }
            float au[2][8];
#pragma unroll
            for (int m = 0; m < 2; m++) {
                int row = wr * 32 + m * 16 + (lane & 15);
                bf16x8 ar = *(const bf16x8*)(ldsA + row * 128 + (cb ^ ((row & 7) << 4)));
#pragma unroll
                for (int q = 0; q < 8; q++) au[m][q] = bf2f((unsigned short)ar[q]);
            }
            const int nb = kt * 64 + kk * 32 + ((lane >> 4) << 3);
#pragma unroll
            for (int r = 0; r < 3; r++) {
                bf16x8 wv = *(const bf16x8*)(wbf + (size_t)r * NPAD + nb);
                float wf[8];
#pragma unroll
                for (int q = 0; q < 8; q++) wf[q] = bf2f((unsigned short)wv[q]);
                bf16x8 am[2];
#pragma unroll
                for (int m = 0; m < 2; m++)
#pragma unroll
                    for (int q = 0; q < 8; q++)
                        am[m][q] = (short)f2bf(au[m][q] * wf[q]);
#pragma unroll
                for (int m = 0; m < 2; m++)
#pragma unroll
                    for (int n = 0; n < 4; n++)
                        acc[r][m][n] = __builtin_amdgcn_mfma_f32_16x16x32_bf16(
                            am[m], bfr[n], acc[r][m][n], 0, 0, 0);
            }
        }
        __syncthreads();
    }
    float* base = Gp + ((size_t)blockIdx.z * 4 + blockIdx.x * 2 + blockIdx.y) * 3 * 16384;
#pragma unroll
    for (int r = 0; r < 3; r++)
#pragma unroll
        for (int m = 0; m < 2; m++)
#pragma unroll
            for (int n = 0; n < 4; n++) {
                int col = wc * 64 + n * 16 + (lane & 15);
                int rw0 = wr * 32 + m * 16 + ((lane >> 4) << 2);
#pragma unroll
                for (int reg = 0; reg < 4; reg++)
                    base[r * 16384 + (rw0 + reg) * 128 + col] = acc[r][m][n][reg];
            }
}

// Reduce Gp over z, emit Gb (bf16 [3][256][256])
__global__ __launch_bounds__(256) void greduce_kernel(
    const float* __restrict__ Gp, unsigned short* __restrict__ Gb)
{
    int gid = blockIdx.x * 256 + threadIdx.x;
    int t = gid >> 14, rem = gid & 16383;
    int r = t % 3, tile = t / 3;
    float s = 0.f;
    for (int z = 0; z < GS; z++)
        s += Gp[(size_t)z * 196608 + ((size_t)tile * 3 + r) * 16384 + rem];
    int i = (tile >> 1) * 128 + (rem >> 7);
    int j = (tile & 1) * 128 + (rem & 127);
    Gb[(size_t)r * 65536 + i * 256 + j] = f2bf(s);
}

// y[r][row] = dot(Mat[r] row (bf16,256), v[r] (f32,256))
__global__ __launch_bounds__(256) void matvec_bf(
    const unsigned short* __restrict__ Mat, const float* __restrict__ v,
    float* __restrict__ y)
{
    __shared__ float vs[256];
    const int b = blockIdx.x;
    const int r = b >> 6, rb = (b & 63) * 4;
    const int tid = threadIdx.x;
    vs[tid] = v[r * 256 + tid];
    __syncthreads();
    const int wid = tid >> 6, lane = tid & 63;
    const int row = rb + wid;
    ushort4 m4 = *(const ushort4*)(Mat + (size_t)r * 65536 + row * 256 + lane * 4);
    float s = bf2f(m4.x) * vs[lane * 4] + bf2f(m4.y) * vs[lane * 4 + 1] +
              bf2f(m4.z) * vs[lane * 4 + 2] + bf2f(m4.w) * vs[lane * 4 + 3];
#pragma unroll
    for (int off = 32; off; off >>= 1) s += __shfl_down(s, off, 64);
    if (lane == 0) y[r * 256 + row] = s;
}

// ---------------------------------------------------------------------------
// One wave per node, qs fused.
__global__ __launch_bounds__(256) void gather_kernel(
    const unsigned short* __restrict__ xb, const int* __restrict__ scol,
    const int* __restrict__ off, const float* __restrict__ tv,
    const int* __restrict__ c_out, const int* __restrict__ nr,
    unsigned short* __restrict__ Afull)
{
    __shared__ float ts[768];
    __shared__ float nrs[RR];
    const int tid = threadIdx.x;
    for (int k = tid; k < 768; k += 256) ts[k] = tv[k];
    if (tid < RR) nrs[tid] = (float)nr[tid];
    __syncthreads();
    const int wid = tid >> 6, lane = tid & 63;
    const int n = blockIdx.x * 4 + wid;
    if (n >= NN) return;
    ushort4 xv = *(const ushort4*)(xb + (size_t)n * DD + lane * 4);
    float xf[4] = {bf2f(xv.x), bf2f(xv.y), bf2f(xv.z), bf2f(xv.w)};
    float dots[RR];
#pragma unroll
    for (int t = 0; t < RR; t++) {
        float s = xf[0] * ts[t * 256 + lane * 4] + xf[1] * ts[t * 256 + lane * 4 + 1] +
                  xf[2] * ts[t * 256 + lane * 4 + 2] + xf[3] * ts[t * 256 + lane * 4 + 3];
#pragma unroll
        for (int o = 32; o; o >>= 1) s += __shfl_xor(s, o, 64);
        dots[t] = s;
    }
#pragma unroll
    for (int t = 0; t < RR; t++) {
        float nrf = nrs[t];
        float denom = dots[t] + nrf;
        int cnt = c_out[t * NN + n];
        float s2 = cnt ? (float)cnt / denom : 0.f;
        ushort4 o1;
        o1.x = f2bf(s2 * xf[0]); o1.y = f2bf(s2 * xf[1]);
        o1.z = f2bf(s2 * xf[2]); o1.w = f2bf(s2 * xf[3]);
        *(ushort4*)(Afull + (size_t)n * 1536 + t * 256 + lane * 4) = o1;

        float acc[4] = {0.f, 0.f, 0.f, 0.f};
        int b0 = off[t * NN + n], b1 = off[t * NN + n + 1];
        for (int i = b0; i < b1; i++) {
            int col = scol[i];
            ushort4 v = *(const ushort4*)(xb + (size_t)col * DD + lane * 4);
            acc[0] += bf2f(v.x); acc[1] += bf2f(v.y);
            acc[2] += bf2f(v.z); acc[3] += bf2f(v.w);
        }
        float s1 = nrf / denom;
        ushort4 o2;
        o2.x = f2bf(s1 * acc[0]); o2.y = f2bf(s1 * acc[1]);
        o2.z = f2bf(s1 * acc[2]); o2.w = f2bf(s1 * acc[3]);
        *(ushort4*)(Afull + (size_t)n * 1536 + 768 + t * 256 + lane * 4) = o2;
    }
}

// ---------------------------------------------------------------------------
// Small MFMA NT GEMM (unchanged, for 256x256 weight products)
template <int MODE, int SWZ>
__global__ __launch_bounds__(256) void gemm_nt(
    const unsigned short* __restrict__ A, int lda,
    const unsigned short* __restrict__ B, int ldb,
    void* __restrict__ Cv, int ldc, int M, int KK,
    size_t sa, size_t sb, size_t sc)
{
    A += (size_t)blockIdx.z * sa;
    B += (size_t)blockIdx.z * sb;
    __shared__ __align__(16) char ldsA[16384];
    __shared__ __align__(16) char ldsB[16384];
    const int tid = threadIdx.x, lane = tid & 63, wid = tid >> 6;
    const int wr = wid >> 1, wc = wid & 1;
    int bx = blockIdx.x;
    if (SWZ) {
        int nwg = gridDim.x, q = nwg >> 3, rem = nwg & 7;
        int xcd = bx & 7, idx = bx >> 3;
        bx = (xcd < rem ? xcd * (q + 1) : rem * (q + 1) + (xcd - rem) * q) + idx;
    }
    const int row0 = bx * 128, col0 = blockIdx.y * 128;

    f32x4 acc[4][4];
#pragma unroll
    for (int m = 0; m < 4; m++)
#pragma unroll
        for (int n = 0; n < 4; n++) acc[m][n] = (f32x4){0.f, 0.f, 0.f, 0.f};

    for (int k0 = 0; k0 < KK; k0 += 64) {
#pragma unroll
        for (int is = 0; is < 4; is++) {
            int lb = is * 4096 + wid * 1024;
            int d = lb + lane * 16;
            int row = d >> 7;
            int sc_ = (d & 127) ^ ((row & 7) << 4);
            int gr = row0 + row; gr = gr < M ? gr : M - 1;
            gload_lds16((const char*)(A + (size_t)gr * lda + k0) + sc_, ldsA + lb);
            int rn = col0 + row;
            gload_lds16((const char*)(B + (size_t)rn * ldb + k0) + sc_, ldsB + lb);
        }
        __syncthreads();
#pragma unroll
        for (int kk = 0; kk < 2; kk++) {
            bf16x8 af[4], bf_[4];
            const int cb = kk * 64 + ((lane >> 4) << 4);
#pragma unroll
            for (int m = 0; m < 4; m++) {
                int row = wr * 64 + m * 16 + (lane & 15);
                af[m] = *(const bf16x8*)(ldsA + row * 128 + (cb ^ ((row & 7) << 4)));
                int rn = wc * 64 + m * 16 + (lane & 15);
                bf_[m] = *(const bf16x8*)(ldsB + rn * 128 + (cb ^ ((rn & 7) << 4)));
            }
#pragma unroll
            for (int m = 0; m < 4; m++)
#pragma unroll
                for (int n = 0; n < 4; n++)
                    acc[m][n] = __builtin_amdgcn_mfma_f32_16x16x32_bf16(
                        af[m], bf_[n], acc[m][n], 0, 0, 0);
        }
        __syncthreads();
    }

#pragma unroll
    for (int m = 0; m < 4; m++) {
#pragma unroll
        for (int reg = 0; reg < 4; reg++) {
            int r = row0 + wr * 64 + m * 16 + ((lane >> 4) << 2) + reg;
            if (r >= M) continue;
#pragma unroll
            for (int n = 0; n < 4; n++) {
                int c = col0 + wc * 64 + n * 16 + (lane & 15);
                float v = acc[m][n][reg];
                if (MODE == 0)
                    ((unsigned short*)Cv)[(size_t)blockIdx.z * sc + (size_t)r * ldc + c] = f2bf(v);
                else
                    ((float*)Cv)[(size_t)blockIdx.z * sc + (size_t)r * ldc + c] = v;
            }
        }
    }
}

// ---------------------------------------------------------------------------
// Final GEMM: out[M,256] = A[M,1536] @ B[256,1536]^T, fp32 store.
// 256x256 tile, 1024 threads (16 waves of 64x64), BK=64, double-buffered
// 128 KiB LDS, T3-min 2-phase: stage t+1 before computing t, one barrier/step
// (its implicit vmcnt(0) drain lands after the MFMAs). XCD-swizzled blockIdx.x.
__global__ __launch_bounds__(1024) void gemm_big(
    const unsigned short* __restrict__ A, int lda,
    const unsigned short* __restrict__ B, int ldb,
    float* __restrict__ C, int ldc, int M, int KK)
{
    extern __shared__ __align__(16) char lds[];   // 131072 B
    char* ldsA = lds;             // two 32 KiB A buffers
    char* ldsB = lds + 65536;     // two 32 KiB B buffers
    const int tid = threadIdx.x, lane = tid & 63, wid = tid >> 6;
    const int wr = wid >> 2, wc = wid & 3;        // 4x4 waves of 64x64
    int bx = blockIdx.x;
    {
        int nwg = gridDim.x, q = nwg >> 3, rem = nwg & 7;
        int xcd = bx & 7, idx = bx >> 3;
        bx = (xcd < rem ? xcd * (q + 1) : rem * (q + 1) + (xcd - rem) * q) + idx;
    }
    const int row0 = bx * 256, col0 = blockIdx.y * 256;

    f32x4 acc[4][4];
#pragma unroll
    for (int m = 0; m < 4; m++)
#pragma unroll
        for (int n = 0; n < 4; n++) acc[m][n] = (f32x4){0.f, 0.f, 0.f, 0.f};

    const int NT = KK / 64;   // 24
    int cur = 0;

    // stage tile t into buffer buf (A: 256x64, B: 256x64; 2 passes of 16 KiB)
#define STAGE_TILE(buf, t)                                                     \
    {                                                                          \
        const int k0_ = (t) * 64;                                              \
        _Pragma("unroll")                                                      \
        for (int is = 0; is < 2; is++) {                                       \
            int lb = is * 16384 + wid * 1024;                                  \
            int d = lb + lane * 16;                                            \
            int row = d >> 7;                                                  \
            int sc_ = (d & 127) ^ ((row & 7) << 4);                            \
            int gr = row0 + row; gr = gr < M ? gr : M - 1;                     \
            gload_lds16((const char*)(A + (size_t)gr * lda + k0_) + sc_,       \
                        ldsA + (buf) * 32768 + lb);                            \
            int rn = col0 + row;                                               \
            gload_lds16((const char*)(B + (size_t)rn * ldb + k0_) + sc_,       \
                        ldsB + (buf) * 32768 + lb);                            \
        }                                                                      \
    }

    STAGE_TILE(0, 0);
    __syncthreads();

    for (int t = 0; t < NT; t++) {
        if (t + 1 < NT) STAGE_TILE(cur ^ 1, t + 1);
        const char* bA = ldsA + cur * 32768;
        const char* bB = ldsB + cur * 32768;
#pragma unroll
        for (int kk = 0; kk < 2; kk++) {
            bf16x8 af[4], bf_[4];
            const int cb = kk * 64 + ((lane >> 4) << 4);
#pragma unroll
            for (int m = 0; m < 4; m++) {
                int row = wr * 64 + m * 16 + (lane & 15);
                af[m] = *(const bf16x8*)(bA + row * 128 + (cb ^ ((row & 7) << 4)));
                int rn = wc * 64 + m * 16 + (lane & 15);
                bf_[m] = *(const bf16x8*)(bB + rn * 128 + (cb ^ ((rn & 7) << 4)));
            }
#pragma unroll
            for (int m = 0; m < 4; m++)
#pragma unroll
                for (int n = 0; n < 4; n++)
                    acc[m][n] = __builtin_amdgcn_mfma_f32_16x16x32_bf16(
                        af[m], bf_[n], acc[m][n], 0, 0, 0);
        }
        __syncthreads();   // drains staged loads (vmcnt0) + protects buffer reuse
        cur ^= 1;
    }
#undef STAGE_TILE

#pragma unroll
    for (int m = 0; m < 4; m++) {
#pragma unroll
        for (int reg = 0; reg < 4; reg++) {
            int r = row0 + wr * 64 + m * 16 + ((lane >> 4) << 2) + reg;
            if (r >= M) continue;
#pragma unroll
            for (int n = 0; n < 4; n++) {
                int c = col0 + wc * 64 + n * 16 + (lane & 15);
                C[(size_t)r * ldc + c] = acc[m][n][reg];
            }
        }
    }
}

// ---------------------------------------------------------------------------
extern "C" void kernel_launch(void* const* d_in, const int* in_sizes, int n_in,
                              void* d_out, int out_size, void* d_ws, size_t ws_size,
                              hipStream_t stream)
{
    const float* x   = (const float*)d_in[0];
    const float* Wq  = (const float*)d_in[1];
    const float* Wk  = (const float*)d_in[2];
    const float* Wv  = (const float*)d_in[3];
    const float* Whp = (const float*)d_in[4];
    const int* eidx  = (const int*)d_in[5];
    const int* etyp  = (const int*)d_in[6];
    const int* erow = eidx;
    const int* ecol = eidx + EE;
    float* out = (float*)d_out;

    char* p = (char*)d_ws;
    unsigned short* xb    = (unsigned short*)p; p += (size_t)NN * DD * 2;
    unsigned short* xT    = (unsigned short*)p; p += (size_t)DD * NPAD * 2;
    char*           regB  = p;                  p += (size_t)NN * 1536 * 2;
    unsigned short* Gb    = (unsigned short*)p; p += (size_t)RR * 65536 * 2;
    unsigned short* M1    = (unsigned short*)p; p += (size_t)RR * 65536 * 2;
    unsigned short* Tm    = (unsigned short*)p; p += (size_t)RR * 65536 * 2;
    unsigned short* Bout  = (unsigned short*)p; p += (size_t)256 * 1536 * 2;
    unsigned short* Wqb   = (unsigned short*)p; p += (size_t)RR * 65536 * 2;
    unsigned short* Wkb   = (unsigned short*)p; p += (size_t)RR * 65536 * 2;
    unsigned short* Wvb   = (unsigned short*)p; p += (size_t)RR * 65536 * 2;
    unsigned short* WhpT  = (unsigned short*)p; p += 65536 * 2;
    unsigned short* wbf   = (unsigned short*)p; p += (size_t)RR * NPAD * 2;
    float*          xw    = (float*)p;          p += 768 * 4;
    float*          tv    = (float*)p;          p += 768 * 4;
    int*            c_in  = (int*)p;            p += (size_t)RR * NN * 4;
    int*            c_out = (int*)p;            p += (size_t)RR * NN * 4;
    int*            nr    = (int*)p;            p += 4 * 4;
    int*            off   = (int*)p;            p += (size_t)(RR * NN + 4) * 4;
    int*            cur   = (int*)p;            p += (size_t)RR * NN * 4;
    int*            scol  = (int*)p;            p += (size_t)EE * 4;
    int*            bsum  = (int*)p;            p += SNB * 4;
    int*            boff  = (int*)p;            p += SNB * 4;
    float*          Gp    = (float*)regB;
    unsigned short* Afull = (unsigned short*)regB;

    hipFuncSetAttribute((const void*)gemm_big,
                        hipFuncAttributeMaxDynamicSharedMemorySize, 131072);

    prep_tc<<<TBLK + 2560, 256, 0, stream>>>(x, Wq, Wk, Wv, Whp, xb, xT, Wqb, Wkb, Wvb, WhpT);
    hipMemsetAsync(c_in, 0, (size_t)(6 * NN + 4) * sizeof(int), stream);
    count_kernel<<<512, 256, 0, stream>>>(erow, ecol, etyp, c_in, c_out, nr);
    scan_reduce<<<SNB, 256, 0, stream>>>(c_out, bsum);
    scan_top<<<1, 256, 0, stream>>>(bsum, boff, off + SCT);
    scan_bot<<<SNB, 256, 0, stream>>>(c_out, boff, off, cur);
    fill_kernel<<<(EE + 255) / 256, 256, 0, stream>>>(erow, ecol, etyp, cur, scol);
    wbfxw_kernel<<<256 + (3 * NPAD + 255) / 256, 256, 0, stream>>>(xT, c_in, xw, wbf);

    // Pre-G weight products: M1_r = Wq_r @ Wk_r^T ; Bout cols 768+ = Whp^T @ Wv_r^T
    gemm_nt<0, 0><<<dim3(2, 2, 3), 256, 0, stream>>>(Wqb, 256, Wkb, 256, M1, 256, 256, 256,
                                                     65536, 65536, 65536);
    gemm_nt<0, 0><<<dim3(2, 2, 3), 256, 0, stream>>>(WhpT, 256, Wvb, 256, Bout + 768, 1536,
                                                     256, 256, 0, 65536, 256);

    g_kernel<<<dim3(2, 2, GS), 512, 0, stream>>>(xT, wbf, Gp);
    greduce_kernel<<<12 * 64, 256, 0, stream>>>(Gp, Gb);

    // T_r = M1_r @ G_r (G symmetric) ; Bout cols 0..767 = (M2T_r) @ T_r^T
    gemm_nt<0, 0><<<dim3(2, 2, 3), 256, 0, stream>>>(M1, 256, Gb, 256, Tm, 256, 256, 256,
                                                     65536, 65536, 65536);
    gemm_nt<0, 0><<<dim3(2, 2, 3), 256, 0, stream>>>(Bout + 768, 1536, Tm, 256, Bout, 1536,
                                                     256, 256, 256, 65536, 256);
    matvec_bf<<<192, 256, 0, stream>>>(M1, xw, tv);   // tv = Wq Wk^T xw

    gather_kernel<<<(NN + 3) / 4, 256, 0, stream>>>(xb, scol, off, tv, c_out, nr, Afull);

    // out = Afull @ Bout^T   (K=1536, fp32, 256^2 tile, dbuf prefetch)
    const int MB2 = (NN + 255) / 256;  // 196
    gemm_big<<<dim3(MB2, 1), 1024, 131072, stream>>>(Afull, 1536, Bout, 1536, out, 256, NN, 1536);
}